// Round 3
// baseline (503.907 us; speedup 1.0000x reference)
//
#include <hip/hip_runtime.h>
#include <hip/hip_bf16.h>
#include <math.h>

#define L_SEQ 2048
#define D_MODEL 128
#define N_ROWS 16384  // B*L = 8*2048
#define LOG2E 1.4426950408889634f

typedef __attribute__((ext_vector_type(8))) short bf16x8;
typedef __attribute__((ext_vector_type(4))) short short4v;
typedef __attribute__((ext_vector_type(4))) float f32x4;

__device__ __forceinline__ short f2bf(float x)  // RNE
{
    __hip_bfloat16 b = __float2bfloat16(x);
    return *reinterpret_cast<short*>(&b);
}
__device__ __forceinline__ short f2bf_fast(float x)  // round-half-up, x >= 0
{
    unsigned u = __builtin_bit_cast(unsigned, x);
    return (short)((u + 0x8000u) >> 16);
}
__device__ __forceinline__ float bf2f(short s)
{
    unsigned u = ((unsigned)(unsigned short)s) << 16;
    return __builtin_bit_cast(float, u);
}
__device__ __forceinline__ short f2h(float x)   // v_cvt_f16_f32
{
    _Float16 h = (_Float16)x;
    return (short)__builtin_bit_cast(unsigned short, h);
}
__device__ __forceinline__ float h2f(short s)   // v_cvt_f32_f16
{
    _Float16 h = __builtin_bit_cast(_Float16, (unsigned short)s);
    return (float)h;
}

// ---------------------------------------------------------------------------
// One-shot fp32 -> bf16 conversion of x and all weight matrices.
// ---------------------------------------------------------------------------
__global__ __launch_bounds__(256) void convert_kernel(
    const float* __restrict__ x,    const float* __restrict__ inw,
    const float* __restrict__ ssmi, const float* __restrict__ ssmo,
    const float* __restrict__ qkvw, const float* __restrict__ aow,
    const float* __restrict__ f1w,  const float* __restrict__ f2w,
    short* __restrict__ xb, short* __restrict__ wb)
{
    int it = blockIdx.x * 256 + threadIdx.x;
    const float* src; short* dst; int off;
    if      (it < 131072) { src = x;    dst = xb;          off = it; }
    else if (it < 132096) { src = inw;  dst = wb;          off = it - 131072; }
    else if (it < 140288) { src = ssmi; dst = wb + 8192;   off = it - 132096; }
    else if (it < 144384) { src = ssmo; dst = wb + 73728;  off = it - 140288; }
    else if (it < 156672) { src = qkvw; dst = wb + 106496; off = it - 144384; }
    else if (it < 160768) { src = aow;  dst = wb + 204800; off = it - 156672; }
    else if (it < 177152) { src = f1w;  dst = wb + 237568; off = it - 160768; }
    else                  { src = f2w;  dst = wb + 368640; off = it - 177152; }
    off <<= 3;
    float4 v0 = *(const float4*)(src + off);
    float4 v1 = *(const float4*)(src + off + 4);
    bf16x8 p = {f2bf(v0.x), f2bf(v0.y), f2bf(v0.z), f2bf(v0.w),
                f2bf(v1.x), f2bf(v1.y), f2bf(v1.z), f2bf(v1.w)};
    *(bf16x8*)(dst + off) = p;
}

// ---------------------------------------------------------------------------
// Fused E=128 GEMM + residual + LayerNorm (R10).
// FUSE: 0 = PE+LN, 1 = RES+LN, 2 = RES only (last ff2).
// ---------------------------------------------------------------------------
template <int FUSE>
__global__ __launch_bounds__(256) void gemm_ln(const short* __restrict__ A,
                                               const short* __restrict__ W,
                                               const float* __restrict__ bias,
                                               const float* __restrict__ lnw,
                                               const float* __restrict__ lnb,
                                               float* __restrict__ bh,
                                               short* __restrict__ lnout,
                                               int K)
{
    __shared__ __align__(16) short As[64][72];
    __shared__ __align__(16) short Bs[128][72];

    const int tid  = threadIdx.x;
    const int wave = tid >> 6;
    const int lane = tid & 63;
    const int m    = lane & 15;
    const int quad = lane >> 4;
    const int n0   = blockIdx.x * 64;

    const int arow = tid >> 2, acol = (tid & 3) << 4;
    const int brow = tid >> 1, bcol = (tid & 1) << 5;

    const short* Ap = A + (size_t)(n0 + arow) * K + acol;
    const short* Wp = W + (size_t)brow * K + bcol;

    f32x4 acc[8];
#pragma unroll
    for (int i = 0; i < 8; ++i) acc[i] = (f32x4){0.f, 0.f, 0.f, 0.f};

    bf16x8 a0 = *(const bf16x8*)Ap;
    bf16x8 a1 = *(const bf16x8*)(Ap + 8);
    bf16x8 b0 = *(const bf16x8*)Wp;
    bf16x8 b1 = *(const bf16x8*)(Wp + 8);
    bf16x8 b2 = *(const bf16x8*)(Wp + 16);
    bf16x8 b3 = *(const bf16x8*)(Wp + 24);

    for (int k0 = 0; k0 < K; k0 += 64) {
        *(bf16x8*)&As[arow][acol]      = a0;
        *(bf16x8*)&As[arow][acol + 8]  = a1;
        *(bf16x8*)&Bs[brow][bcol]      = b0;
        *(bf16x8*)&Bs[brow][bcol + 8]  = b1;
        *(bf16x8*)&Bs[brow][bcol + 16] = b2;
        *(bf16x8*)&Bs[brow][bcol + 24] = b3;
        __syncthreads();
        if (k0 + 64 < K) {
            a0 = *(const bf16x8*)(Ap + k0 + 64);
            a1 = *(const bf16x8*)(Ap + k0 + 72);
            b0 = *(const bf16x8*)(Wp + k0 + 64);
            b1 = *(const bf16x8*)(Wp + k0 + 72);
            b2 = *(const bf16x8*)(Wp + k0 + 80);
            b3 = *(const bf16x8*)(Wp + k0 + 88);
        }
#pragma unroll
        for (int ks = 0; ks < 2; ++ks) {
            bf16x8 af = *(const bf16x8*)&As[(wave << 4) + m][(ks << 5) + (quad << 3)];
#pragma unroll
            for (int nt = 0; nt < 8; ++nt) {
                bf16x8 bfr = *(const bf16x8*)&Bs[(nt << 4) + m][(ks << 5) + (quad << 3)];
                acc[nt] = __builtin_amdgcn_mfma_f32_16x16x32_bf16(af, bfr, acc[nt], 0, 0, 0);
            }
        }
        __syncthreads();
    }

    // ---- epilogue: bias (+PE | +res), write fp32 bh, keep v in registers ----
#pragma unroll
    for (int nt = 0; nt < 8; ++nt) {
        int col = (nt << 4) + m;
        float bv = bias[col];
        float fr = 0.f;
        if (FUSE == 0)
            fr = __expf((float)(col & ~1) * (-0.07195578415606394f)); // -ln(1e4)/128
#pragma unroll
        for (int r = 0; r < 4; ++r) {
            int row = n0 + (wave << 4) + (quad << 2) + r;
            float t = acc[nt][r] + bv;
            if (FUSE == 0) {
                float ang = (float)(row & (L_SEQ - 1)) * fr;
                t += (col & 1) ? cosf(ang) : sinf(ang);
            } else {
                t += bh[(size_t)row * 128 + col];
            }
            acc[nt][r] = t;
            bh[(size_t)row * 128 + col] = t;
        }
    }

    if (FUSE < 2) {
        // ---- in-register LayerNorm over the 128 cols of each row ----
        float wv[8], bvn[8];
#pragma unroll
        for (int nt = 0; nt < 8; ++nt) {
            wv[nt]  = lnw[(nt << 4) + m];
            bvn[nt] = lnb[(nt << 4) + m];
        }
#pragma unroll
        for (int r = 0; r < 4; ++r) {
            float s = 0.f;
#pragma unroll
            for (int nt = 0; nt < 8; ++nt) s += acc[nt][r];
            s += __shfl_xor(s, 1);
            s += __shfl_xor(s, 2);
            s += __shfl_xor(s, 4);
            s += __shfl_xor(s, 8);
            float mean = s * (1.f / 128.f);
            float q = 0.f;
#pragma unroll
            for (int nt = 0; nt < 8; ++nt) {
                float d = acc[nt][r] - mean;
                q = fmaf(d, d, q);
            }
            q += __shfl_xor(q, 1);
            q += __shfl_xor(q, 2);
            q += __shfl_xor(q, 4);
            q += __shfl_xor(q, 8);
            float inv = rsqrtf(q * (1.f / 128.f) + 1e-5f);
            int row = n0 + (wave << 4) + (quad << 2) + r;
#pragma unroll
            for (int nt = 0; nt < 8; ++nt) {
                int col = (nt << 4) + m;
                lnout[(size_t)row * 128 + col] =
                    f2bf((acc[nt][r] - mean) * inv * wv[nt] + bvn[nt]);
            }
        }
    }
}

// ---------------------------------------------------------------------------
// bf16-native MFMA GEMM (validated R3-R7). 64x64 tile, BK=64, reg prefetch.
// Remaining epilogues: BF_RELU (ff1), QKV, SCAN_T.
// ---------------------------------------------------------------------------
enum { EPI_BF_RELU = 0, EPI_QKV = 1, EPI_SCAN_T = 2 };

template <int EPI>
__global__ __launch_bounds__(256) void gemm_bf(const short* __restrict__ A,
                                               const short* __restrict__ W,
                                               const float* __restrict__ bias,
                                               short* __restrict__ outb,  // QKV: qs (ks = +2097152); SCAN_T: pt
                                               short* __restrict__ outv,  // QKV: vt
                                               int K, int E)
{
    __shared__ __align__(16) short As[64][72];
    __shared__ __align__(16) short Bs[64][72];

    const int tid  = threadIdx.x;
    const int wave = tid >> 6;
    const int lane = tid & 63;
    const int m    = lane & 15;
    const int quad = lane >> 4;

    const int n0 = blockIdx.y * 64;
    const int e0 = blockIdx.x * 64;

    const int srow = tid >> 2;
    const int scol = (tid & 3) << 4;

    const short* Ap = A + (size_t)(n0 + srow) * K + scol;
    const short* Wp = W + (size_t)(e0 + srow) * K + scol;

    f32x4 acc[4];
#pragma unroll
    for (int i = 0; i < 4; ++i) acc[i] = (f32x4){0.f, 0.f, 0.f, 0.f};

    bf16x8 a0 = *(const bf16x8*)Ap;
    bf16x8 a1 = *(const bf16x8*)(Ap + 8);
    bf16x8 w0 = *(const bf16x8*)Wp;
    bf16x8 w1 = *(const bf16x8*)(Wp + 8);

    for (int k0 = 0; k0 < K; k0 += 64) {
        *(bf16x8*)&As[srow][scol]     = a0;
        *(bf16x8*)&As[srow][scol + 8] = a1;
        *(bf16x8*)&Bs[srow][scol]     = w0;
        *(bf16x8*)&Bs[srow][scol + 8] = w1;
        __syncthreads();
        if (k0 + 64 < K) {  // prefetch next chunk while MFMAs run
            a0 = *(const bf16x8*)(Ap + k0 + 64);
            a1 = *(const bf16x8*)(Ap + k0 + 72);
            w0 = *(const bf16x8*)(Wp + k0 + 64);
            w1 = *(const bf16x8*)(Wp + k0 + 72);
        }
#pragma unroll
        for (int ks = 0; ks < 2; ++ks) {
            bf16x8 af = *(const bf16x8*)&As[(wave << 4) + m][(ks << 5) + (quad << 3)];
#pragma unroll
            for (int nt = 0; nt < 4; ++nt) {
                bf16x8 bfr = *(const bf16x8*)&Bs[(nt << 4) + m][(ks << 5) + (quad << 3)];
                acc[nt] = __builtin_amdgcn_mfma_f32_16x16x32_bf16(af, bfr, acc[nt], 0, 0, 0);
            }
        }
        __syncthreads();
    }

    if (EPI == EPI_QKV) {
        const float QSC = 0.17677669529663687f * LOG2E;  // 1/sqrt(32) * log2e
        if (e0 < 256) {
            short* dst = (e0 < 128) ? outb : (outb + 2097152);
            int cbase = (e0 < 128) ? e0 : (e0 - 128);
#pragma unroll
            for (int nt = 0; nt < 4; ++nt) {
                int col = cbase + (nt << 4) + m;
                float bv = bias[e0 + (nt << 4) + m];
#pragma unroll
                for (int r = 0; r < 4; ++r) {
                    int row = n0 + (wave << 4) + (quad << 2) + r;
                    float v = acc[nt][r] + bv;
                    if (e0 < 128) v *= QSC;
                    dst[(size_t)row * 128 + col] = f2bf(v);
                }
            }
        } else {
            int bb_ = n0 >> 11;
            int l0  = (n0 & (L_SEQ - 1)) + (wave << 4) + (quad << 2);
#pragma unroll
            for (int nt = 0; nt < 4; ++nt) {
                int c  = (e0 - 256) + (nt << 4) + m;
                int hh = c >> 5, dd = c & 31;
                float bv = bias[e0 + (nt << 4) + m];
                short4v pk;
#pragma unroll
                for (int r = 0; r < 4; ++r) pk[r] = f2bf(acc[nt][r] + bv);
                *(short4v*)&outv[(size_t)((bb_ * 4 + hh) * 32 + dd) * L_SEQ + l0] = pk;
            }
        }
    } else if (EPI == EPI_SCAN_T) {
        // transposed write pt[b][e][l] (fp16): u2 for e<128, sigmoid(g) for e>=128
        int bb_ = n0 >> 11;
        int l0  = (n0 & (L_SEQ - 1)) + (wave << 4) + (quad << 2);
#pragma unroll
        for (int nt = 0; nt < 4; ++nt) {
            int col = e0 + (nt << 4) + m;
            float bv = bias[col];
            short4v pk;
            if (e0 < 128) {
#pragma unroll
                for (int r = 0; r < 4; ++r)
                    pk[r] = f2h((acc[nt][r] + bv) * (2.f * LOG2E));
            } else {
#pragma unroll
                for (int r = 0; r < 4; ++r) {
                    float gr = acc[nt][r] + bv;
                    float g = __builtin_amdgcn_rcpf(
                        1.f + __builtin_amdgcn_exp2f(-gr * LOG2E));
                    pk[r] = f2h(g);
                }
            }
            *(short4v*)&outb[(((size_t)(bb_ * 256 + col)) << 11) + l0] = pk;
        }
    } else {  // EPI_BF_RELU
#pragma unroll
        for (int nt = 0; nt < 4; ++nt) {
            int col = e0 + (nt << 4) + m;
            float bv = bias[col];
#pragma unroll
            for (int r = 0; r < 4; ++r) {
                int row = n0 + (wave << 4) + (quad << 2) + r;
                float v = fmaxf(acc[nt][r] + bv, 0.f);
                outb[(size_t)row * E + col] = f2bf(v);
            }
        }
    }
}

// ---------------------------------------------------------------------------
// SSM gated scan — R13 chunked-parallel version (validated R1: 68 -> ~10 us).
// Recurrence is contractive; 16 chunks of 128 steps each with 128-step
// burn-in from h=0. Sequential depth 2048 -> 256.
// ---------------------------------------------------------------------------
#define SCAN_WARM 128   // burn-in steps (contraction margin)

__device__ __forceinline__ void scan8(float& h, bf16x8 u8, bf16x8 g8,
                                      float a2, short* __restrict__ ob, int l0)
{
#pragma unroll
    for (int i = 0; i < 8; ++i) {
        float u2 = h2f(u8[i]);
        float g  = h2f(g8[i]);
        float omg = 1.f - g;
        float m2  = -2.f * omg;
        float c0 = fmaf(g, h, omg);                          // parallel to exp path
        float e2 = __builtin_amdgcn_exp2f(fmaf(a2, h, u2));  // exp(2x)
        float r  = __builtin_amdgcn_rcpf(1.f + e2);
        h = fmaf(m2, r, c0);
        ob[(l0 + i) * D_MODEL] = f2bf(h);
    }
}

__device__ __forceinline__ void scan8_ns(float& h, bf16x8 u8, bf16x8 g8,
                                         float a2)
{
#pragma unroll
    for (int i = 0; i < 8; ++i) {
        float u2 = h2f(u8[i]);
        float g  = h2f(g8[i]);
        float omg = 1.f - g;
        float m2  = -2.f * omg;
        float c0 = fmaf(g, h, omg);
        float e2 = __builtin_amdgcn_exp2f(fmaf(a2, h, u2));
        float r  = __builtin_amdgcn_rcpf(1.f + e2);
        h = fmaf(m2, r, c0);
    }
}

__global__ __launch_bounds__(64) void scan_kernel(const short* __restrict__ pt,
                                                  const float* __restrict__ A,
                                                  short* __restrict__ hs)
{
    int blk = blockIdx.x;             // 256 blocks = 16 (b,dhalf) x 16 chunks
    int c   = blk & 15;               // chunk index: writes l in [c*128, c*128+128)
    int bd  = blk >> 4;
    int b   = bd >> 1;
    int d   = ((bd & 1) << 6) + threadIdx.x;
    float a2 = 2.f * A[d] * LOG2E;
    const short* up = pt + (((size_t)(b * 256 + d)) << 11);
    const short* gp = up + (((size_t)128) << 11);
    short* ob = hs + ((size_t)(b << 11)) * D_MODEL + d;

    const int lw = c << 7;            // first stored step
    float h = 0.f;

    bf16x8 uA0, uA1, gA0, gA1;

    if (c > 0) {
        // ---- burn-in: SCAN_WARM steps ending at lw, no stores ----
        int l0 = lw - SCAN_WARM;
        uA0 = *(const bf16x8*)(up + l0);
        uA1 = *(const bf16x8*)(up + l0 + 8);
        gA0 = *(const bf16x8*)(gp + l0);
        gA1 = *(const bf16x8*)(gp + l0 + 8);
        for (int l = l0; l < lw; l += 32) {
            bf16x8 uB0 = *(const bf16x8*)(up + l + 16);
            bf16x8 uB1 = *(const bf16x8*)(up + l + 24);
            bf16x8 gB0 = *(const bf16x8*)(gp + l + 16);
            bf16x8 gB1 = *(const bf16x8*)(gp + l + 24);
            scan8_ns(h, uA0, gA0, a2);
            scan8_ns(h, uA1, gA1, a2);
            uA0 = *(const bf16x8*)(up + l + 32);
            uA1 = *(const bf16x8*)(up + l + 40);
            gA0 = *(const bf16x8*)(gp + l + 32);
            gA1 = *(const bf16x8*)(gp + l + 40);
            scan8_ns(h, uB0, gB0, a2);
            scan8_ns(h, uB1, gB1, a2);
        }
    } else {
        uA0 = *(const bf16x8*)(up);
        uA1 = *(const bf16x8*)(up + 8);
        gA0 = *(const bf16x8*)(gp);
        gA1 = *(const bf16x8*)(gp + 8);
    }

    // ---- live phase: 128 steps with stores ----
    for (int l = lw; l < lw + 128; l += 32) {
        bf16x8 uB0 = *(const bf16x8*)(up + l + 16);
        bf16x8 uB1 = *(const bf16x8*)(up + l + 24);
        bf16x8 gB0 = *(const bf16x8*)(gp + l + 16);
        bf16x8 gB1 = *(const bf16x8*)(gp + l + 24);
        scan8(h, uA0, gA0, a2, ob, l);
        scan8(h, uA1, gA1, a2, ob, l + 8);
        if (l + 32 < lw + 128) {      // guard: l+32 would be OOB at chunk end
            uA0 = *(const bf16x8*)(up + l + 32);
            uA1 = *(const bf16x8*)(up + l + 40);
            gA0 = *(const bf16x8*)(gp + l + 32);
            gA1 = *(const bf16x8*)(gp + l + 40);
        }
        scan8(h, uB0, gB0, a2, ob, l + 16);
        scan8(h, uB1, gB1, a2, ob, l + 24);
    }
}

// ---------------------------------------------------------------------------
// Flash attention v4 (R14): barrier-free, LDS-minimal.
// R1 counters: MfmaUtil 13 / VALUBusy 42 / bank-conflict 6.3M -> LDS-BW bound
// (1.87 GB through LDS @69TB/s ~ 27us of the 52). KV per (b,h) is 256KB =
// L2-resident, so K/V staging was pure overhead (m169 lesson). v4:
//  - K and V MFMA fragments loaded DIRECTLY from global (L1/L2), register
//    double-buffered; no K/V LDS, no __syncthreads at all.
//  - QK^T computed swapped (mfma(K,Q) -> S^T): lane holds P[q=m][k=..+quad*4+r],
//    r contiguous -> P spills as 4x ds_write_b64 (2-way = free) instead of
//    16x 4-way-conflicted ds_write_b16. Row-sum: 1 reg + shfl_xor(16,32).
//  - XCD swizzle: each XCD works 4 consecutive (b,h) pairs -> 1MB KV in its L2.
// LDS traffic 1.87GB -> 0.52GB (P round-trip only, conflict-free).
// ---------------------------------------------------------------------------
__global__ __launch_bounds__(256) void attn_kernel(const short* __restrict__ Qs,
                                                   const short* __restrict__ Ks,
                                                   const short* __restrict__ Vtg,
                                                   short* __restrict__ outb)
{
    __shared__ __align__(16) short Plds[4][16][72];

    const int tid  = threadIdx.x;
    const int wave = tid >> 6;
    const int lane = tid & 63;
    const int m    = lane & 15;
    const int quad = lane >> 4;

    // XCD-aware swizzle (grid 1024, 8 XCDs round-robin on dispatch id):
    // XCD x gets logical blocks [x*128, x*128+128) = 4 (b,h) pairs.
    const int raw = blockIdx.x;
    const int bid = (raw & 7) * 128 + (raw >> 3);
    const int b  = bid >> 7;
    const int h  = (bid >> 5) & 3;
    const int q0 = (bid & 31) << 6;

    bf16x8 qfrag = *(const bf16x8*)&Qs[((size_t)((b << 11) + q0 + (wave << 4) + m)) * 128
                                       + (h << 5) + (quad << 3)];

    f32x4 O[2];
    O[0] = (f32x4){0.f, 0.f, 0.f, 0.f};
    O[1] = (f32x4){0.f, 0.f, 0.f, 0.f};
    float rs = 0.f;

    // per-lane fragment bases: kf lane (m,quad) -> K[kpos=kt*16+m][d=quad*8..]
    //                          vf lane (m,quad) -> V^T[d=dt*16+m][k=..quad*8..]
    const short* kbase = Ks + ((size_t)((b << 11) + m)) * 128 + (h << 5) + (quad << 3);
    const short* vbase = Vtg + ((size_t)((b << 2) + h) * 32 + m) * L_SEQ + (quad << 3);

    bf16x8 kA[4], vA[4], kB[4], vB[4];
#pragma unroll
    for (int kt = 0; kt < 4; ++kt)
        kA[kt] = *(const bf16x8*)(kbase + (size_t)(kt << 4) * 128);
    vA[0] = *(const bf16x8*)(vbase);
    vA[1] = *(const bf16x8*)(vbase + 32);
    vA[2] = *(const bf16x8*)(vbase + 16 * L_SEQ);
    vA[3] = *(const bf16x8*)(vbase + 16 * L_SEQ + 32);

#define ATTN_STEP(kc, CK, CV, NK, NV, DO_PF)                                    \
    {                                                                           \
        if (DO_PF) {                                                            \
            const short* kn = kbase + (size_t)(((kc) + 1) << 6) * 128;          \
            const short* vn = vbase + (((kc) + 1) << 6);                        \
            _Pragma("unroll")                                                   \
            for (int kt = 0; kt < 4; ++kt)                                      \
                NK[kt] = *(const bf16x8*)(kn + (size_t)(kt << 4) * 128);        \
            NV[0] = *(const bf16x8*)(vn);                                       \
            NV[1] = *(const bf16x8*)(vn + 32);                                  \
            NV[2] = *(const bf16x8*)(vn + 16 * L_SEQ);                          \
            NV[3] = *(const bf16x8*)(vn + 16 * L_SEQ + 32);                     \
        }                                                                       \
        _Pragma("unroll")                                                       \
        for (int kt = 0; kt < 4; ++kt) {                                        \
            f32x4 S = __builtin_amdgcn_mfma_f32_16x16x32_bf16(                  \
                CK[kt], qfrag, (f32x4){0.f, 0.f, 0.f, 0.f}, 0, 0, 0);           \
            short4v pk;                                                         \
            _Pragma("unroll")                                                   \
            for (int r = 0; r < 4; ++r) {                                       \
                float p = __builtin_amdgcn_exp2f(S[r]);                         \
                rs += p;                                                        \
                pk[r] = f2bf_fast(p);                                           \
            }                                                                   \
            *(short4v*)&Plds[wave][m][(kt << 4) + (quad << 2)] = pk;            \
        }                                                                       \
        _Pragma("unroll")                                                       \
        for (int kt2 = 0; kt2 < 2; ++kt2) {                                     \
            bf16x8 pf = *(const bf16x8*)&Plds[wave][m][(kt2 << 5) + (quad << 3)];\
            _Pragma("unroll")                                                   \
            for (int dt = 0; dt < 2; ++dt)                                      \
                O[dt] = __builtin_amdgcn_mfma_f32_16x16x32_bf16(                \
                    pf, CV[(dt << 1) | kt2], O[dt], 0, 0, 0);                   \
        }                                                                       \
    }

    for (int kc = 0; kc < 32; kc += 2) {
        ATTN_STEP(kc, kA, vA, kB, vB, 1);
        ATTN_STEP(kc + 1, kB, vB, kA, vA, (kc + 2 < 32));
    }
#undef ATTN_STEP

    // rs per lane = sum over its (quad-slice of k) for q = m; finish across quads
    rs += __shfl_xor(rs, 16);
    rs += __shfl_xor(rs, 32);

#pragma unroll
    for (int r = 0; r < 4; ++r) {
        float sv  = __shfl(rs, (quad << 2) + r);   // rs(q=quad*4+r) lives at lane q
        float inv = 1.f / sv;
        int row = (b << 11) + q0 + (wave << 4) + (quad << 2) + r;
        short* op = outb + (size_t)row * D_MODEL + (h << 5) + m;
        op[0]  = f2bf(O[0][r] * inv);
        op[16] = f2bf(O[1][r] * inv);
    }
}

// ---------------------------------------------------------------------------
// Fused pool + head (R12): one 1024-thread block per batch element.
// ---------------------------------------------------------------------------
__global__ __launch_bounds__(1024) void pool_head_kernel(
    const float* __restrict__ h,
    const float* __restrict__ hlnw, const float* __restrict__ hlnb,
    const float* __restrict__ h1w, const float* __restrict__ h1b,
    const float* __restrict__ h2w, const float* __restrict__ h2b,
    float* __restrict__ out)
{
    __shared__ float part[8][128];
    __shared__ float sd[128];
    __shared__ float sq[128];

    int b   = blockIdx.x;
    int t   = threadIdx.x;
    int d   = t & 127;
    int seg = t >> 7;    // 0..7
    const float* hb = h + (size_t)b * L_SEQ * D_MODEL;

    // ---- phase 1: pool ----
    float acc = 0.f;
    int l0 = seg << 8;
    for (int l = l0; l < l0 + 256; l += 4) {
        acc += hb[(l + 0) * D_MODEL + d] + hb[(l + 1) * D_MODEL + d]
             + hb[(l + 2) * D_MODEL + d] + hb[(l + 3) * D_MODEL + d];
    }
    part[seg][d] = acc;
    __syncthreads();

    // ---- phase 2: head (threads 0..127 compute; all hit barriers) ----
    float v = 0.f;
    if (t < 128) {
        float s = 0.f;
#pragma unroll
        for (int i = 0; i < 8; ++i) s += part[i][t];
        v = 0.5f * hb[(L_SEQ - 1) * D_MODEL + t] + 0.5f * (s * (1.f / (float)L_SEQ));
        sd[t] = v;
    }
    __syncthreads();
    for (int s = 64; s > 0; s >>= 1) {
        if (t < s) sd[t] += sd[t + s];
        __syncthreads();
    }
    float mu = sd[0] * (1.f / 128.f);
    __syncthreads();
    float dv = v - mu;
    if (t < 128) sd[t] = dv * dv;
    __syncthreads();
    for (int s = 64; s > 0; s >>= 1) {
        if (t < s) sd[t] += sd[t + s];
        __syncthreads();
    }
    float var = sd[0] * (1.f / 128.f);
    __syncthreads();
    if (t < 128) sq[t] = dv * rsqrtf(var + 1e-5f) * hlnw[t] + hlnb[t];
    __syncthreads();
    if (t < 128) {
        float dot = h1b[t];
        for (int d2 = 0; d2 < 128; ++d2) dot = fmaf(sq[d2], h1w[t * 128 + d2], dot);
        float ge = 0.5f * dot * (1.f + erff(dot * 0.7071067811865475f));
        sd[t] = ge * h2w[t];
    }
    __syncthreads();
    for (int s = 64; s > 0; s >>= 1) {
        if (t < s) sd[t] += sd[t + s];
        __syncthreads();
    }
    if (t == 0) out[b] = sd[0] + h2b[0];
}

// ---------------------------------------------------------------------------
extern "C" void kernel_launch(void* const* d_in, const int* in_sizes, int n_in,
                              void* d_out, int out_size, void* d_ws, size_t ws_size,
                              hipStream_t stream)
{
    (void)in_sizes; (void)n_in; (void)out_size; (void)ws_size;
    const float* x      = (const float*)d_in[0];
    const float* in_w   = (const float*)d_in[1];
    const float* in_b   = (const float*)d_in[2];
    const float* ssm_nw = (const float*)d_in[3];
    const float* ssm_nb = (const float*)d_in[4];
    const float* ssm_A  = (const float*)d_in[5];
    const float* ssm_iw = (const float*)d_in[6];
    const float* ssm_ib = (const float*)d_in[7];
    const float* ssm_ow = (const float*)d_in[8];
    const float* ssm_ob = (const float*)d_in[9];
    const float* ln1w   = (const float*)d_in[10];
    const float* ln1b   = (const float*)d_in[11];
    const float* ln2w   = (const float*)d_in[12];
    const float* ln2b   = (const float*)d_in[13];
    const float* qkvw   = (const float*)d_in[14];
    const float* qkvb   = (const float*)d_in[15];
    const float* aow    = (const float*)d_in[16];
    const float* aob    = (const float*)d_in[17];
    const float* f1w    = (const float*)d_in[18];
    const float* f1b    = (const float*)d_in[19];
    const float* f2w    = (const float*)d_in[20];
    const float* f2b    = (const float*)d_in[21];
    const float* hlnw   = (const float*)d_in[22];
    const float* hlnb   = (const float*)d_in[23];
    const float* h1w    = (const float*)d_in[24];
    const float* h1b    = (const float*)d_in[25];
    const float* h2w    = (const float*)d_in[26];
    const float* h2b    = (const float*)d_in[27];
    float* out = (float*)d_out;

    char* wsb = (char*)d_ws;
    float* bh     = (float*)(wsb);               // [N,128] fp32 residual stream (8 MB)
    short* abuf   = (short*)(wsb + 8388608);     // [N,512] bf16 wide scratch / scan pt (16 MB)
    short* bbuf   = (short*)(wsb + 25165824);    // [N,128] bf16 ln/hs/attn-out (4 MB)
    short* qs     = (short*)(wsb + 29360128);    // [N,128] bf16 Q prescaled; ks = +2097152
    short* vt     = (short*)(wsb + 37748736);    // [B,4,32,2048] bf16 V^T (4 MB)
    short* xb     = (short*)(wsb + 41943040);    // [N,64] bf16 input (2 MB)
    short* wb     = (short*)(wsb + 44040192);    // bf16 weights (~1 MB)
    short* ks     = qs + 2097152;

    dim3 blk(256);

    convert_kernel<<<756, blk, 0, stream>>>(x, in_w, ssm_iw, ssm_ow, qkvw, aow, f1w, f2w, xb, wb);

    // input projection + PE + LN(ssm_norm0): writes bh (fp32) and bbuf (bf16 LN)
    gemm_ln<0><<<256, blk, 0, stream>>>(
        xb, wb, in_b, ssm_nw, ssm_nb, bh, bbuf, 64);

    // SSM block 0
    gemm_bf<EPI_SCAN_T><<<dim3(4, 256), blk, 0, stream>>>(
        bbuf, wb + 8192, ssm_ib, abuf, nullptr, 128, 256);
    scan_kernel<<<256, 64, 0, stream>>>(abuf, ssm_A, bbuf);
    gemm_ln<1><<<256, blk, 0, stream>>>(                       // +res, LN(ssm_norm1)
        bbuf, wb + 73728, ssm_ob, ssm_nw + 128, ssm_nb + 128, bh, bbuf, 128);

    // SSM block 1
    gemm_bf<EPI_SCAN_T><<<dim3(4, 256), blk, 0, stream>>>(
        bbuf, wb + 8192 + 32768, ssm_ib + 256, abuf, nullptr, 128, 256);
    scan_kernel<<<256, 64, 0, stream>>>(abuf, ssm_A + 128, bbuf);
    gemm_ln<1><<<256, blk, 0, stream>>>(                       // +res, LN(ln1[0])
        bbuf, wb + 73728 + 16384, ssm_ob + 128, ln1w, ln1b, bh, bbuf, 128);

    // Encoder layer 0
    gemm_bf<EPI_QKV><<<dim3(6, 256), blk, 0, stream>>>(
        bbuf, wb + 106496, qkvb, qs, vt, 128, 384);
    attn_kernel<<<1024, blk, 0, stream>>>(qs, ks, vt, bbuf);
    gemm_ln<1><<<256, blk, 0, stream>>>(                       // +res, LN(ln2[0])
        bbuf, wb + 204800, aob, ln2w, ln2b, bh, bbuf, 128);
    gemm_bf<EPI_BF_RELU><<<dim3(8, 256), blk, 0, stream>>>(
        bbuf, wb + 237568, f1b, abuf, nullptr, 128, 512);
    gemm_ln<1><<<256, blk, 0, stream>>>(                       // ff2[0] +res, LN(ln1[1])
        abuf, wb + 368640, f2b, ln1w + 128, ln1b + 128, bh, bbuf, 512);

    // Encoder layer 1
    gemm_bf<EPI_QKV><<<dim3(6, 256), blk, 0, stream>>>(
        bbuf, wb + 106496 + 49152, qkvb + 384, qs, vt, 128, 384);
    attn_kernel<<<1024, blk, 0, stream>>>(qs, ks, vt, bbuf);
    gemm_ln<1><<<256, blk, 0, stream>>>(                       // +res, LN(ln2[1])
        bbuf, wb + 204800 + 16384, aob + 128, ln2w + 128, ln2b + 128, bh, bbuf, 128);
    gemm_bf<EPI_BF_RELU><<<dim3(8, 256), blk, 0, stream>>>(
        bbuf, wb + 237568 + 65536, f1b + 512, abuf, nullptr, 128, 512);
    gemm_ln<2><<<256, blk, 0, stream>>>(                       // ff2[1] +res only
        abuf, wb + 368640 + 65536, f2b + 128, nullptr, nullptr, bh, nullptr, 512);

    pool_head_kernel<<<8, 1024, 0, stream>>>(bh, hlnw, hlnb, h1w, h1b, h2w, h2b, out);
}

// Round 4
// 356.331 us; speedup vs baseline: 1.4142x; 1.4142x over previous
//
#include <hip/hip_runtime.h>
#include <hip/hip_bf16.h>
#include <math.h>

#define L_SEQ 2048
#define D_MODEL 128
#define N_ROWS 16384  // B*L = 8*2048
#define LOG2E 1.4426950408889634f

typedef __attribute__((ext_vector_type(8))) short bf16x8;
typedef __attribute__((ext_vector_type(4))) short short4v;
typedef __attribute__((ext_vector_type(4))) float f32x4;

__device__ __forceinline__ short f2bf(float x)  // RNE
{
    __hip_bfloat16 b = __float2bfloat16(x);
    return *reinterpret_cast<short*>(&b);
}
__device__ __forceinline__ short f2bf_fast(float x)  // round-half-up, x >= 0
{
    unsigned u = __builtin_bit_cast(unsigned, x);
    return (short)((u + 0x8000u) >> 16);
}
__device__ __forceinline__ float bf2f(short s)
{
    unsigned u = ((unsigned)(unsigned short)s) << 16;
    return __builtin_bit_cast(float, u);
}
__device__ __forceinline__ short f2h(float x)   // v_cvt_f16_f32
{
    _Float16 h = (_Float16)x;
    return (short)__builtin_bit_cast(unsigned short, h);
}
__device__ __forceinline__ float h2f(short s)   // v_cvt_f32_f16
{
    _Float16 h = __builtin_bit_cast(_Float16, (unsigned short)s);
    return (float)h;
}

// ---------------------------------------------------------------------------
// One-shot fp32 -> bf16 conversion of x and all weight matrices.
// ---------------------------------------------------------------------------
__global__ __launch_bounds__(256) void convert_kernel(
    const float* __restrict__ x,    const float* __restrict__ inw,
    const float* __restrict__ ssmi, const float* __restrict__ ssmo,
    const float* __restrict__ qkvw, const float* __restrict__ aow,
    const float* __restrict__ f1w,  const float* __restrict__ f2w,
    short* __restrict__ xb, short* __restrict__ wb)
{
    int it = blockIdx.x * 256 + threadIdx.x;
    const float* src; short* dst; int off;
    if      (it < 131072) { src = x;    dst = xb;          off = it; }
    else if (it < 132096) { src = inw;  dst = wb;          off = it - 131072; }
    else if (it < 140288) { src = ssmi; dst = wb + 8192;   off = it - 132096; }
    else if (it < 144384) { src = ssmo; dst = wb + 73728;  off = it - 140288; }
    else if (it < 156672) { src = qkvw; dst = wb + 106496; off = it - 144384; }
    else if (it < 160768) { src = aow;  dst = wb + 204800; off = it - 156672; }
    else if (it < 177152) { src = f1w;  dst = wb + 237568; off = it - 160768; }
    else                  { src = f2w;  dst = wb + 368640; off = it - 177152; }
    off <<= 3;
    float4 v0 = *(const float4*)(src + off);
    float4 v1 = *(const float4*)(src + off + 4);
    bf16x8 p = {f2bf(v0.x), f2bf(v0.y), f2bf(v0.z), f2bf(v0.w),
                f2bf(v1.x), f2bf(v1.y), f2bf(v1.z), f2bf(v1.w)};
    *(bf16x8*)(dst + off) = p;
}

// ---------------------------------------------------------------------------
// Fused E=128 GEMM + residual + LayerNorm (R10).
// FUSE: 0 = PE+LN, 1 = RES+LN, 2 = RES only (last ff2).
// ---------------------------------------------------------------------------
template <int FUSE>
__global__ __launch_bounds__(256) void gemm_ln(const short* __restrict__ A,
                                               const short* __restrict__ W,
                                               const float* __restrict__ bias,
                                               const float* __restrict__ lnw,
                                               const float* __restrict__ lnb,
                                               float* __restrict__ bh,
                                               short* __restrict__ lnout,
                                               int K)
{
    __shared__ __align__(16) short As[64][72];
    __shared__ __align__(16) short Bs[128][72];

    const int tid  = threadIdx.x;
    const int wave = tid >> 6;
    const int lane = tid & 63;
    const int m    = lane & 15;
    const int quad = lane >> 4;
    const int n0   = blockIdx.x * 64;

    const int arow = tid >> 2, acol = (tid & 3) << 4;
    const int brow = tid >> 1, bcol = (tid & 1) << 5;

    const short* Ap = A + (size_t)(n0 + arow) * K + acol;
    const short* Wp = W + (size_t)brow * K + bcol;

    f32x4 acc[8];
#pragma unroll
    for (int i = 0; i < 8; ++i) acc[i] = (f32x4){0.f, 0.f, 0.f, 0.f};

    bf16x8 a0 = *(const bf16x8*)Ap;
    bf16x8 a1 = *(const bf16x8*)(Ap + 8);
    bf16x8 b0 = *(const bf16x8*)Wp;
    bf16x8 b1 = *(const bf16x8*)(Wp + 8);
    bf16x8 b2 = *(const bf16x8*)(Wp + 16);
    bf16x8 b3 = *(const bf16x8*)(Wp + 24);

    for (int k0 = 0; k0 < K; k0 += 64) {
        *(bf16x8*)&As[arow][acol]      = a0;
        *(bf16x8*)&As[arow][acol + 8]  = a1;
        *(bf16x8*)&Bs[brow][bcol]      = b0;
        *(bf16x8*)&Bs[brow][bcol + 8]  = b1;
        *(bf16x8*)&Bs[brow][bcol + 16] = b2;
        *(bf16x8*)&Bs[brow][bcol + 24] = b3;
        __syncthreads();
        if (k0 + 64 < K) {
            a0 = *(const bf16x8*)(Ap + k0 + 64);
            a1 = *(const bf16x8*)(Ap + k0 + 72);
            b0 = *(const bf16x8*)(Wp + k0 + 64);
            b1 = *(const bf16x8*)(Wp + k0 + 72);
            b2 = *(const bf16x8*)(Wp + k0 + 80);
            b3 = *(const bf16x8*)(Wp + k0 + 88);
        }
#pragma unroll
        for (int ks = 0; ks < 2; ++ks) {
            bf16x8 af = *(const bf16x8*)&As[(wave << 4) + m][(ks << 5) + (quad << 3)];
#pragma unroll
            for (int nt = 0; nt < 8; ++nt) {
                bf16x8 bfr = *(const bf16x8*)&Bs[(nt << 4) + m][(ks << 5) + (quad << 3)];
                acc[nt] = __builtin_amdgcn_mfma_f32_16x16x32_bf16(af, bfr, acc[nt], 0, 0, 0);
            }
        }
        __syncthreads();
    }

    // ---- epilogue: bias (+PE | +res), write fp32 bh, keep v in registers ----
#pragma unroll
    for (int nt = 0; nt < 8; ++nt) {
        int col = (nt << 4) + m;
        float bv = bias[col];
        float fr = 0.f;
        if (FUSE == 0)
            fr = __expf((float)(col & ~1) * (-0.07195578415606394f)); // -ln(1e4)/128
#pragma unroll
        for (int r = 0; r < 4; ++r) {
            int row = n0 + (wave << 4) + (quad << 2) + r;
            float t = acc[nt][r] + bv;
            if (FUSE == 0) {
                float ang = (float)(row & (L_SEQ - 1)) * fr;
                t += (col & 1) ? cosf(ang) : sinf(ang);
            } else {
                t += bh[(size_t)row * 128 + col];
            }
            acc[nt][r] = t;
            bh[(size_t)row * 128 + col] = t;
        }
    }

    if (FUSE < 2) {
        // ---- in-register LayerNorm over the 128 cols of each row ----
        float wv[8], bvn[8];
#pragma unroll
        for (int nt = 0; nt < 8; ++nt) {
            wv[nt]  = lnw[(nt << 4) + m];
            bvn[nt] = lnb[(nt << 4) + m];
        }
#pragma unroll
        for (int r = 0; r < 4; ++r) {
            float s = 0.f;
#pragma unroll
            for (int nt = 0; nt < 8; ++nt) s += acc[nt][r];
            s += __shfl_xor(s, 1);
            s += __shfl_xor(s, 2);
            s += __shfl_xor(s, 4);
            s += __shfl_xor(s, 8);
            float mean = s * (1.f / 128.f);
            float q = 0.f;
#pragma unroll
            for (int nt = 0; nt < 8; ++nt) {
                float d = acc[nt][r] - mean;
                q = fmaf(d, d, q);
            }
            q += __shfl_xor(q, 1);
            q += __shfl_xor(q, 2);
            q += __shfl_xor(q, 4);
            q += __shfl_xor(q, 8);
            float inv = rsqrtf(q * (1.f / 128.f) + 1e-5f);
            int row = n0 + (wave << 4) + (quad << 2) + r;
#pragma unroll
            for (int nt = 0; nt < 8; ++nt) {
                int col = (nt << 4) + m;
                lnout[(size_t)row * 128 + col] =
                    f2bf((acc[nt][r] - mean) * inv * wv[nt] + bvn[nt]);
            }
        }
    }
}

// ---------------------------------------------------------------------------
// bf16-native MFMA GEMM (validated R3-R7). 64x64 tile, BK=64, reg prefetch.
// Remaining epilogues: BF_RELU (ff1), QKV, SCAN_T.
// ---------------------------------------------------------------------------
enum { EPI_BF_RELU = 0, EPI_QKV = 1, EPI_SCAN_T = 2 };

template <int EPI>
__global__ __launch_bounds__(256) void gemm_bf(const short* __restrict__ A,
                                               const short* __restrict__ W,
                                               const float* __restrict__ bias,
                                               short* __restrict__ outb,  // QKV: qs (ks = +2097152); SCAN_T: pt
                                               short* __restrict__ outv,  // QKV: vt
                                               int K, int E)
{
    __shared__ __align__(16) short As[64][72];
    __shared__ __align__(16) short Bs[64][72];

    const int tid  = threadIdx.x;
    const int wave = tid >> 6;
    const int lane = tid & 63;
    const int m    = lane & 15;
    const int quad = lane >> 4;

    const int n0 = blockIdx.y * 64;
    const int e0 = blockIdx.x * 64;

    const int srow = tid >> 2;
    const int scol = (tid & 3) << 4;

    const short* Ap = A + (size_t)(n0 + srow) * K + scol;
    const short* Wp = W + (size_t)(e0 + srow) * K + scol;

    f32x4 acc[4];
#pragma unroll
    for (int i = 0; i < 4; ++i) acc[i] = (f32x4){0.f, 0.f, 0.f, 0.f};

    bf16x8 a0 = *(const bf16x8*)Ap;
    bf16x8 a1 = *(const bf16x8*)(Ap + 8);
    bf16x8 w0 = *(const bf16x8*)Wp;
    bf16x8 w1 = *(const bf16x8*)(Wp + 8);

    for (int k0 = 0; k0 < K; k0 += 64) {
        *(bf16x8*)&As[srow][scol]     = a0;
        *(bf16x8*)&As[srow][scol + 8] = a1;
        *(bf16x8*)&Bs[srow][scol]     = w0;
        *(bf16x8*)&Bs[srow][scol + 8] = w1;
        __syncthreads();
        if (k0 + 64 < K) {  // prefetch next chunk while MFMAs run
            a0 = *(const bf16x8*)(Ap + k0 + 64);
            a1 = *(const bf16x8*)(Ap + k0 + 72);
            w0 = *(const bf16x8*)(Wp + k0 + 64);
            w1 = *(const bf16x8*)(Wp + k0 + 72);
        }
#pragma unroll
        for (int ks = 0; ks < 2; ++ks) {
            bf16x8 af = *(const bf16x8*)&As[(wave << 4) + m][(ks << 5) + (quad << 3)];
#pragma unroll
            for (int nt = 0; nt < 4; ++nt) {
                bf16x8 bfr = *(const bf16x8*)&Bs[(nt << 4) + m][(ks << 5) + (quad << 3)];
                acc[nt] = __builtin_amdgcn_mfma_f32_16x16x32_bf16(af, bfr, acc[nt], 0, 0, 0);
            }
        }
        __syncthreads();
    }

    if (EPI == EPI_QKV) {
        const float QSC = 0.17677669529663687f * LOG2E;  // 1/sqrt(32) * log2e
        if (e0 < 256) {
            short* dst = (e0 < 128) ? outb : (outb + 2097152);
            int cbase = (e0 < 128) ? e0 : (e0 - 128);
#pragma unroll
            for (int nt = 0; nt < 4; ++nt) {
                int col = cbase + (nt << 4) + m;
                float bv = bias[e0 + (nt << 4) + m];
#pragma unroll
                for (int r = 0; r < 4; ++r) {
                    int row = n0 + (wave << 4) + (quad << 2) + r;
                    float v = acc[nt][r] + bv;
                    if (e0 < 128) v *= QSC;
                    dst[(size_t)row * 128 + col] = f2bf(v);
                }
            }
        } else {
            int bb_ = n0 >> 11;
            int l0  = (n0 & (L_SEQ - 1)) + (wave << 4) + (quad << 2);
#pragma unroll
            for (int nt = 0; nt < 4; ++nt) {
                int c  = (e0 - 256) + (nt << 4) + m;
                int hh = c >> 5, dd = c & 31;
                float bv = bias[e0 + (nt << 4) + m];
                short4v pk;
#pragma unroll
                for (int r = 0; r < 4; ++r) pk[r] = f2bf(acc[nt][r] + bv);
                *(short4v*)&outv[(size_t)((bb_ * 4 + hh) * 32 + dd) * L_SEQ + l0] = pk;
            }
        }
    } else if (EPI == EPI_SCAN_T) {
        // transposed write pt[b][e][l] (fp16): u2 for e<128, sigmoid(g) for e>=128
        int bb_ = n0 >> 11;
        int l0  = (n0 & (L_SEQ - 1)) + (wave << 4) + (quad << 2);
#pragma unroll
        for (int nt = 0; nt < 4; ++nt) {
            int col = e0 + (nt << 4) + m;
            float bv = bias[col];
            short4v pk;
            if (e0 < 128) {
#pragma unroll
                for (int r = 0; r < 4; ++r)
                    pk[r] = f2h((acc[nt][r] + bv) * (2.f * LOG2E));
            } else {
#pragma unroll
                for (int r = 0; r < 4; ++r) {
                    float gr = acc[nt][r] + bv;
                    float g = __builtin_amdgcn_rcpf(
                        1.f + __builtin_amdgcn_exp2f(-gr * LOG2E));
                    pk[r] = f2h(g);
                }
            }
            *(short4v*)&outb[(((size_t)(bb_ * 256 + col)) << 11) + l0] = pk;
        }
    } else {  // EPI_BF_RELU
#pragma unroll
        for (int nt = 0; nt < 4; ++nt) {
            int col = e0 + (nt << 4) + m;
            float bv = bias[col];
#pragma unroll
            for (int r = 0; r < 4; ++r) {
                int row = n0 + (wave << 4) + (quad << 2) + r;
                float v = fmaxf(acc[nt][r] + bv, 0.f);
                outb[(size_t)row * E + col] = f2bf(v);
            }
        }
    }
}

// ---------------------------------------------------------------------------
// SSM gated scan — R13 chunked-parallel version (validated R1: 68 -> ~10 us).
// Recurrence is contractive; 16 chunks of 128 steps each with 128-step
// burn-in from h=0. Sequential depth 2048 -> 256.
// ---------------------------------------------------------------------------
#define SCAN_WARM 128   // burn-in steps (contraction margin)

__device__ __forceinline__ void scan8(float& h, bf16x8 u8, bf16x8 g8,
                                      float a2, short* __restrict__ ob, int l0)
{
#pragma unroll
    for (int i = 0; i < 8; ++i) {
        float u2 = h2f(u8[i]);
        float g  = h2f(g8[i]);
        float omg = 1.f - g;
        float m2  = -2.f * omg;
        float c0 = fmaf(g, h, omg);                          // parallel to exp path
        float e2 = __builtin_amdgcn_exp2f(fmaf(a2, h, u2));  // exp(2x)
        float r  = __builtin_amdgcn_rcpf(1.f + e2);
        h = fmaf(m2, r, c0);
        ob[(l0 + i) * D_MODEL] = f2bf(h);
    }
}

__device__ __forceinline__ void scan8_ns(float& h, bf16x8 u8, bf16x8 g8,
                                         float a2)
{
#pragma unroll
    for (int i = 0; i < 8; ++i) {
        float u2 = h2f(u8[i]);
        float g  = h2f(g8[i]);
        float omg = 1.f - g;
        float m2  = -2.f * omg;
        float c0 = fmaf(g, h, omg);
        float e2 = __builtin_amdgcn_exp2f(fmaf(a2, h, u2));
        float r  = __builtin_amdgcn_rcpf(1.f + e2);
        h = fmaf(m2, r, c0);
    }
}

__global__ __launch_bounds__(64) void scan_kernel(const short* __restrict__ pt,
                                                  const float* __restrict__ A,
                                                  short* __restrict__ hs)
{
    int blk = blockIdx.x;             // 256 blocks = 16 (b,dhalf) x 16 chunks
    int c   = blk & 15;               // chunk index: writes l in [c*128, c*128+128)
    int bd  = blk >> 4;
    int b   = bd >> 1;
    int d   = ((bd & 1) << 6) + threadIdx.x;
    float a2 = 2.f * A[d] * LOG2E;
    const short* up = pt + (((size_t)(b * 256 + d)) << 11);
    const short* gp = up + (((size_t)128) << 11);
    short* ob = hs + ((size_t)(b << 11)) * D_MODEL + d;

    const int lw = c << 7;            // first stored step
    float h = 0.f;

    bf16x8 uA0, uA1, gA0, gA1;

    if (c > 0) {
        // ---- burn-in: SCAN_WARM steps ending at lw, no stores ----
        int l0 = lw - SCAN_WARM;
        uA0 = *(const bf16x8*)(up + l0);
        uA1 = *(const bf16x8*)(up + l0 + 8);
        gA0 = *(const bf16x8*)(gp + l0);
        gA1 = *(const bf16x8*)(gp + l0 + 8);
        for (int l = l0; l < lw; l += 32) {
            bf16x8 uB0 = *(const bf16x8*)(up + l + 16);
            bf16x8 uB1 = *(const bf16x8*)(up + l + 24);
            bf16x8 gB0 = *(const bf16x8*)(gp + l + 16);
            bf16x8 gB1 = *(const bf16x8*)(gp + l + 24);
            scan8_ns(h, uA0, gA0, a2);
            scan8_ns(h, uA1, gA1, a2);
            uA0 = *(const bf16x8*)(up + l + 32);
            uA1 = *(const bf16x8*)(up + l + 40);
            gA0 = *(const bf16x8*)(gp + l + 32);
            gA1 = *(const bf16x8*)(gp + l + 40);
            scan8_ns(h, uB0, gB0, a2);
            scan8_ns(h, uB1, gB1, a2);
        }
    } else {
        uA0 = *(const bf16x8*)(up);
        uA1 = *(const bf16x8*)(up + 8);
        gA0 = *(const bf16x8*)(gp);
        gA1 = *(const bf16x8*)(gp + 8);
    }

    // ---- live phase: 128 steps with stores ----
    for (int l = lw; l < lw + 128; l += 32) {
        bf16x8 uB0 = *(const bf16x8*)(up + l + 16);
        bf16x8 uB1 = *(const bf16x8*)(up + l + 24);
        bf16x8 gB0 = *(const bf16x8*)(gp + l + 16);
        bf16x8 gB1 = *(const bf16x8*)(gp + l + 24);
        scan8(h, uA0, gA0, a2, ob, l);
        scan8(h, uA1, gA1, a2, ob, l + 8);
        if (l + 32 < lw + 128) {      // guard: l+32 would be OOB at chunk end
            uA0 = *(const bf16x8*)(up + l + 32);
            uA1 = *(const bf16x8*)(up + l + 40);
            gA0 = *(const bf16x8*)(gp + l + 32);
            gA1 = *(const bf16x8*)(gp + l + 40);
        }
        scan8(h, uB0, gB0, a2, ob, l + 16);
        scan8(h, uB1, gB1, a2, ob, l + 24);
    }
}

// ---------------------------------------------------------------------------
// Flash attention v5 (R15): v3's staged/double-buffered K/V LDS pipeline
// (validated: coalesced bulk staging hides global latency; 1 barrier/chunk)
// + v4's validated swapped-QK^T compute path (mfma(K,Q) -> lane holds
// P[q=m][k=kt*16+quad*4+r]; P spill = 4x ds_write_b64 2-way (free) instead
// of 16x 4-way ds_write_b16; scalar row-sum + shfl epilogue) + v4's XCD
// swizzle (validated: FETCH 34.8 -> 6.2 MB).
// R3 post-mortem: v4's register double-buffer was rematerialized by the
// allocator (VGPR 60 < the 64 the buffers need) -> every chunk serially ate
// L2 latency on a 16-line gather; MfmaUtil 5.4, dur 122us. Structural LDS
// staging is the latency-hiding mechanism; keep it.
// ---------------------------------------------------------------------------
__global__ __launch_bounds__(256) void attn_kernel(const short* __restrict__ Qs,
                                                   const short* __restrict__ Ks,
                                                   const short* __restrict__ Vtg,
                                                   short* __restrict__ outb)
{
    __shared__ __align__(16) short Klds[2][64][40];
    __shared__ __align__(16) short Vlds[2][32][72];
    __shared__ __align__(16) short Plds[4][16][72];

    const int tid  = threadIdx.x;
    const int wave = tid >> 6;
    const int lane = tid & 63;
    const int m    = lane & 15;
    const int quad = lane >> 4;

    // XCD-aware swizzle (grid 1024, 8 XCDs round-robin on dispatch id):
    // XCD x gets logical blocks [x*128, x*128+128) = 4 (b,h) pairs = 1MB KV.
    const int raw = blockIdx.x;
    const int bid = (raw & 7) * 128 + (raw >> 3);
    const int b  = bid >> 7;
    const int h  = (bid >> 5) & 3;
    const int q0 = (bid & 31) << 6;

    bf16x8 qfrag = *(const bf16x8*)&Qs[((size_t)((b << 11) + q0 + (wave << 4) + m)) * 128
                                       + (h << 5) + (quad << 3)];

    f32x4 O[2];
    O[0] = (f32x4){0.f, 0.f, 0.f, 0.f};
    O[1] = (f32x4){0.f, 0.f, 0.f, 0.f};
    float rs = 0.f;

    const int krow = tid >> 2, dg = (tid & 3) << 3;
    const int vrow = tid >> 3, kg = (tid & 7) << 3;
    const short* kbase = Ks + ((size_t)(b << 11) + krow) * 128 + (h << 5) + dg;
    const short* vbase = Vtg + ((size_t)((b << 2) + h) * 32 + vrow) * L_SEQ + kg;

    // stage chunk 0
    bf16x8 kreg = *(const bf16x8*)kbase;
    bf16x8 vreg = *(const bf16x8*)vbase;
    *(bf16x8*)&Klds[0][krow][dg] = kreg;
    *(bf16x8*)&Vlds[0][vrow][kg] = vreg;
    __syncthreads();

    for (int kc = 0; kc < 32; ++kc) {
        const int cur = kc & 1;
        if (kc < 31) {  // prefetch next chunk into registers (coalesced bulk)
            kreg = *(const bf16x8*)(kbase + (size_t)((kc + 1) << 6) * 128);
            vreg = *(const bf16x8*)(vbase + ((kc + 1) << 6));
        }

        // ---- swapped QK^T: S^T = mfma(K, Q); lane (m,quad) r holds
        //      P[q=m][k=kt*16+quad*4+r] -> contiguous-in-k b64 P spill ----
#pragma unroll
        for (int kt = 0; kt < 4; ++kt) {
            bf16x8 kf = *(const bf16x8*)&Klds[cur][(kt << 4) + m][quad << 3];
            f32x4 S = __builtin_amdgcn_mfma_f32_16x16x32_bf16(
                kf, qfrag, (f32x4){0.f, 0.f, 0.f, 0.f}, 0, 0, 0);
            short4v pk;
#pragma unroll
            for (int r = 0; r < 4; ++r) {
                float p = __builtin_amdgcn_exp2f(S[r]);
                rs += p;
                pk[r] = f2bf_fast(p);
            }
            *(short4v*)&Plds[wave][m][(kt << 4) + (quad << 2)] = pk;
        }

        // ---- PV (Plds per-wave: intra-wave lgkmcnt only, no barrier) ----
#pragma unroll
        for (int kt2 = 0; kt2 < 2; ++kt2) {
            bf16x8 pf = *(const bf16x8*)&Plds[wave][m][(kt2 << 5) + (quad << 3)];
#pragma unroll
            for (int dt = 0; dt < 2; ++dt) {
                bf16x8 vf = *(const bf16x8*)&Vlds[cur][(dt << 4) + m][(kt2 << 5) + (quad << 3)];
                O[dt] = __builtin_amdgcn_mfma_f32_16x16x32_bf16(pf, vf, O[dt], 0, 0, 0);
            }
        }

        // ---- write next K/V buffer; single barrier per chunk ----
        if (kc < 31) {
            *(bf16x8*)&Klds[cur ^ 1][krow][dg] = kreg;
            *(bf16x8*)&Vlds[cur ^ 1][vrow][kg] = vreg;
        }
        __syncthreads();
    }

    // rs per lane = sum over its quad-slice of k for q = m; finish across quads
    rs += __shfl_xor(rs, 16);
    rs += __shfl_xor(rs, 32);

#pragma unroll
    for (int r = 0; r < 4; ++r) {
        float sv  = __shfl(rs, (quad << 2) + r);   // rs(q=quad*4+r) lives at lane q
        float inv = 1.f / sv;
        int row = (b << 11) + q0 + (wave << 4) + (quad << 2) + r;
        short* op = outb + (size_t)row * D_MODEL + (h << 5) + m;
        op[0]  = f2bf(O[0][r] * inv);
        op[16] = f2bf(O[1][r] * inv);
    }
}

// ---------------------------------------------------------------------------
// Fused pool + head (R12): one 1024-thread block per batch element.
// ---------------------------------------------------------------------------
__global__ __launch_bounds__(1024) void pool_head_kernel(
    const float* __restrict__ h,
    const float* __restrict__ hlnw, const float* __restrict__ hlnb,
    const float* __restrict__ h1w, const float* __restrict__ h1b,
    const float* __restrict__ h2w, const float* __restrict__ h2b,
    float* __restrict__ out)
{
    __shared__ float part[8][128];
    __shared__ float sd[128];
    __shared__ float sq[128];

    int b   = blockIdx.x;
    int t   = threadIdx.x;
    int d   = t & 127;
    int seg = t >> 7;    // 0..7
    const float* hb = h + (size_t)b * L_SEQ * D_MODEL;

    // ---- phase 1: pool ----
    float acc = 0.f;
    int l0 = seg << 8;
    for (int l = l0; l < l0 + 256; l += 4) {
        acc += hb[(l + 0) * D_MODEL + d] + hb[(l + 1) * D_MODEL + d]
             + hb[(l + 2) * D_MODEL + d] + hb[(l + 3) * D_MODEL + d];
    }
    part[seg][d] = acc;
    __syncthreads();

    // ---- phase 2: head (threads 0..127 compute; all hit barriers) ----
    float v = 0.f;
    if (t < 128) {
        float s = 0.f;
#pragma unroll
        for (int i = 0; i < 8; ++i) s += part[i][t];
        v = 0.5f * hb[(L_SEQ - 1) * D_MODEL + t] + 0.5f * (s * (1.f / (float)L_SEQ));
        sd[t] = v;
    }
    __syncthreads();
    for (int s = 64; s > 0; s >>= 1) {
        if (t < s) sd[t] += sd[t + s];
        __syncthreads();
    }
    float mu = sd[0] * (1.f / 128.f);
    __syncthreads();
    float dv = v - mu;
    if (t < 128) sd[t] = dv * dv;
    __syncthreads();
    for (int s = 64; s > 0; s >>= 1) {
        if (t < s) sd[t] += sd[t + s];
        __syncthreads();
    }
    float var = sd[0] * (1.f / 128.f);
    __syncthreads();
    if (t < 128) sq[t] = dv * rsqrtf(var + 1e-5f) * hlnw[t] + hlnb[t];
    __syncthreads();
    if (t < 128) {
        float dot = h1b[t];
        for (int d2 = 0; d2 < 128; ++d2) dot = fmaf(sq[d2], h1w[t * 128 + d2], dot);
        float ge = 0.5f * dot * (1.f + erff(dot * 0.7071067811865475f));
        sd[t] = ge * h2w[t];
    }
    __syncthreads();
    for (int s = 64; s > 0; s >>= 1) {
        if (t < s) sd[t] += sd[t + s];
        __syncthreads();
    }
    if (t == 0) out[b] = sd[0] + h2b[0];
}

// ---------------------------------------------------------------------------
extern "C" void kernel_launch(void* const* d_in, const int* in_sizes, int n_in,
                              void* d_out, int out_size, void* d_ws, size_t ws_size,
                              hipStream_t stream)
{
    (void)in_sizes; (void)n_in; (void)out_size; (void)ws_size;
    const float* x      = (const float*)d_in[0];
    const float* in_w   = (const float*)d_in[1];
    const float* in_b   = (const float*)d_in[2];
    const float* ssm_nw = (const float*)d_in[3];
    const float* ssm_nb = (const float*)d_in[4];
    const float* ssm_A  = (const float*)d_in[5];
    const float* ssm_iw = (const float*)d_in[6];
    const float* ssm_ib = (const float*)d_in[7];
    const float* ssm_ow = (const float*)d_in[8];
    const float* ssm_ob = (const float*)d_in[9];
    const float* ln1w   = (const float*)d_in[10];
    const float* ln1b   = (const float*)d_in[11];
    const float* ln2w   = (const float*)d_in[12];
    const float* ln2b   = (const float*)d_in[13];
    const float* qkvw   = (const float*)d_in[14];
    const float* qkvb   = (const float*)d_in[15];
    const float* aow    = (const float*)d_in[16];
    const float* aob    = (const float*)d_in[17];
    const float* f1w    = (const float*)d_in[18];
    const float* f1b    = (const float*)d_in[19];
    const float* f2w    = (const float*)d_in[20];
    const float* f2b    = (const float*)d_in[21];
    const float* hlnw   = (const float*)d_in[22];
    const float* hlnb   = (const float*)d_in[23];
    const float* h1w    = (const float*)d_in[24];
    const float* h1b    = (const float*)d_in[25];
    const float* h2w    = (const float*)d_in[26];
    const float* h2b    = (const float*)d_in[27];
    float* out = (float*)d_out;

    char* wsb = (char*)d_ws;
    float* bh     = (float*)(wsb);               // [N,128] fp32 residual stream (8 MB)
    short* abuf   = (short*)(wsb + 8388608);     // [N,512] bf16 wide scratch / scan pt (16 MB)
    short* bbuf   = (short*)(wsb + 25165824);    // [N,128] bf16 ln/hs/attn-out (4 MB)
    short* qs     = (short*)(wsb + 29360128);    // [N,128] bf16 Q prescaled; ks = +2097152
    short* vt     = (short*)(wsb + 37748736);    // [B,4,32,2048] bf16 V^T (4 MB)
    short* xb     = (short*)(wsb + 41943040);    // [N,64] bf16 input (2 MB)
    short* wb     = (short*)(wsb + 44040192);    // bf16 weights (~1 MB)
    short* ks     = qs + 2097152;

    dim3 blk(256);

    convert_kernel<<<756, blk, 0, stream>>>(x, in_w, ssm_iw, ssm_ow, qkvw, aow, f1w, f2w, xb, wb);

    // input projection + PE + LN(ssm_norm0): writes bh (fp32) and bbuf (bf16 LN)
    gemm_ln<0><<<256, blk, 0, stream>>>(
        xb, wb, in_b, ssm_nw, ssm_nb, bh, bbuf, 64);

    // SSM block 0
    gemm_bf<EPI_SCAN_T><<<dim3(4, 256), blk, 0, stream>>>(
        bbuf, wb + 8192, ssm_ib, abuf, nullptr, 128, 256);
    scan_kernel<<<256, 64, 0, stream>>>(abuf, ssm_A, bbuf);
    gemm_ln<1><<<256, blk, 0, stream>>>(                       // +res, LN(ssm_norm1)
        bbuf, wb + 73728, ssm_ob, ssm_nw + 128, ssm_nb + 128, bh, bbuf, 128);

    // SSM block 1
    gemm_bf<EPI_SCAN_T><<<dim3(4, 256), blk, 0, stream>>>(
        bbuf, wb + 8192 + 32768, ssm_ib + 256, abuf, nullptr, 128, 256);
    scan_kernel<<<256, 64, 0, stream>>>(abuf, ssm_A + 128, bbuf);
    gemm_ln<1><<<256, blk, 0, stream>>>(                       // +res, LN(ln1[0])
        bbuf, wb + 73728 + 16384, ssm_ob + 128, ln1w, ln1b, bh, bbuf, 128);

    // Encoder layer 0
    gemm_bf<EPI_QKV><<<dim3(6, 256), blk, 0, stream>>>(
        bbuf, wb + 106496, qkvb, qs, vt, 128, 384);
    attn_kernel<<<1024, blk, 0, stream>>>(qs, ks, vt, bbuf);
    gemm_ln<1><<<256, blk, 0, stream>>>(                       // +res, LN(ln2[0])
        bbuf, wb + 204800, aob, ln2w, ln2b, bh, bbuf, 128);
    gemm_bf<EPI_BF_RELU><<<dim3(8, 256), blk, 0, stream>>>(
        bbuf, wb + 237568, f1b, abuf, nullptr, 128, 512);
    gemm_ln<1><<<256, blk, 0, stream>>>(                       // ff2[0] +res, LN(ln1[1])
        abuf, wb + 368640, f2b, ln1w + 128, ln1b + 128, bh, bbuf, 512);

    // Encoder layer 1
    gemm_bf<EPI_QKV><<<dim3(6, 256), blk, 0, stream>>>(
        bbuf, wb + 106496 + 49152, qkvb + 384, qs, vt, 128, 384);
    attn_kernel<<<1024, blk, 0, stream>>>(qs, ks, vt, bbuf);
    gemm_ln<1><<<256, blk, 0, stream>>>(                       // +res, LN(ln2[1])
        bbuf, wb + 204800 + 16384, aob + 128, ln2w + 128, ln2b + 128, bh, bbuf, 128);
    gemm_bf<EPI_BF_RELU><<<dim3(8, 256), blk, 0, stream>>>(
        bbuf, wb + 237568 + 65536, f1b + 512, abuf, nullptr, 128, 512);
    gemm_ln<2><<<256, blk, 0, stream>>>(                       // ff2[1] +res only
        abuf, wb + 368640 + 65536, f2b + 128, nullptr, nullptr, bh, nullptr, 512);

    pool_head_kernel<<<8, 1024, 0, stream>>>(bh, hlnw, hlnb, h1w, h1b, h2w, h2b, out);
}

// Round 5
// 347.351 us; speedup vs baseline: 1.4507x; 1.0259x over previous
//
#include <hip/hip_runtime.h>
#include <hip/hip_bf16.h>
#include <math.h>

#define L_SEQ 2048
#define D_MODEL 128
#define N_ROWS 16384  // B*L = 8*2048
#define LOG2E 1.4426950408889634f

typedef __attribute__((ext_vector_type(8))) short bf16x8;
typedef __attribute__((ext_vector_type(4))) short short4v;
typedef __attribute__((ext_vector_type(4))) float f32x4;

__device__ __forceinline__ short f2bf(float x)  // RNE
{
    __hip_bfloat16 b = __float2bfloat16(x);
    return *reinterpret_cast<short*>(&b);
}
__device__ __forceinline__ short f2bf_fast(float x)  // round-half-up, x >= 0
{
    unsigned u = __builtin_bit_cast(unsigned, x);
    return (short)((u + 0x8000u) >> 16);
}
__device__ __forceinline__ unsigned cvt_pk_bf16(float lo, float hi)  // 2xbf16 in 1 instr
{
    unsigned r;
    asm("v_cvt_pk_bf16_f32 %0, %1, %2" : "=v"(r) : "v"(lo), "v"(hi));
    return r;
}
__device__ __forceinline__ float bf2f(short s)
{
    unsigned u = ((unsigned)(unsigned short)s) << 16;
    return __builtin_bit_cast(float, u);
}
__device__ __forceinline__ short f2h(float x)   // v_cvt_f16_f32
{
    _Float16 h = (_Float16)x;
    return (short)__builtin_bit_cast(unsigned short, h);
}
__device__ __forceinline__ float h2f(short s)   // v_cvt_f32_f16
{
    _Float16 h = __builtin_bit_cast(_Float16, (unsigned short)s);
    return (float)h;
}

// ---------------------------------------------------------------------------
// One-shot fp32 -> bf16 conversion of x and all weight matrices.
// ---------------------------------------------------------------------------
__global__ __launch_bounds__(256) void convert_kernel(
    const float* __restrict__ x,    const float* __restrict__ inw,
    const float* __restrict__ ssmi, const float* __restrict__ ssmo,
    const float* __restrict__ qkvw, const float* __restrict__ aow,
    const float* __restrict__ f1w,  const float* __restrict__ f2w,
    short* __restrict__ xb, short* __restrict__ wb)
{
    int it = blockIdx.x * 256 + threadIdx.x;
    const float* src; short* dst; int off;
    if      (it < 131072) { src = x;    dst = xb;          off = it; }
    else if (it < 132096) { src = inw;  dst = wb;          off = it - 131072; }
    else if (it < 140288) { src = ssmi; dst = wb + 8192;   off = it - 132096; }
    else if (it < 144384) { src = ssmo; dst = wb + 73728;  off = it - 140288; }
    else if (it < 156672) { src = qkvw; dst = wb + 106496; off = it - 144384; }
    else if (it < 160768) { src = aow;  dst = wb + 204800; off = it - 156672; }
    else if (it < 177152) { src = f1w;  dst = wb + 237568; off = it - 160768; }
    else                  { src = f2w;  dst = wb + 368640; off = it - 177152; }
    off <<= 3;
    float4 v0 = *(const float4*)(src + off);
    float4 v1 = *(const float4*)(src + off + 4);
    bf16x8 p = {f2bf(v0.x), f2bf(v0.y), f2bf(v0.z), f2bf(v0.w),
                f2bf(v1.x), f2bf(v1.y), f2bf(v1.z), f2bf(v1.w)};
    *(bf16x8*)(dst + off) = p;
}

// ---------------------------------------------------------------------------
// Fused E=128 GEMM + residual + LayerNorm (R16 occupancy rework).
// R4 analysis: old 64-row/256-block version ran 1 block/CU = 1 wave/SIMD;
// every staging drain + barrier idled the CU. New: 32-row x 128-col blocks,
// grid 512 -> 2 blocks/CU = 2 waves/SIMD. 4 waves = (row-half rh) x
// (col-half ch); each wave: 16 rows x 64 cols (4 col-tiles). LN now needs a
// cross-wave combine: one-pass sum/sumsq partials via 256B LDS + 1 barrier
// (var = E[x^2] - mu^2).
// FUSE: 0 = PE+LN, 1 = RES+LN, 2 = RES only (last ff2).
// ---------------------------------------------------------------------------
template <int FUSE>
__global__ __launch_bounds__(256) void gemm_ln(const short* __restrict__ A,
                                               const short* __restrict__ W,
                                               const float* __restrict__ bias,
                                               const float* __restrict__ lnw,
                                               const float* __restrict__ lnb,
                                               float* __restrict__ bh,
                                               short* __restrict__ lnout,
                                               int K)
{
    __shared__ __align__(16) short As[32][72];
    __shared__ __align__(16) short Bs[128][72];
    __shared__ float2 red[2][32];

    const int tid  = threadIdx.x;
    const int wave = tid >> 6;
    const int lane = tid & 63;
    const int m    = lane & 15;
    const int quad = lane >> 4;
    const int rh   = wave & 1;     // row half (16 rows)
    const int ch   = wave >> 1;    // col half (64 cols)
    const int n0   = blockIdx.x * 32;

    const int arow = tid >> 3, acol = (tid & 7) << 3;
    const int brow = tid >> 1, bcol = (tid & 1) << 5;

    const short* Ap = A + (size_t)(n0 + arow) * K + acol;
    const short* Wp = W + (size_t)brow * K + bcol;

    f32x4 acc[4];
#pragma unroll
    for (int i = 0; i < 4; ++i) acc[i] = (f32x4){0.f, 0.f, 0.f, 0.f};

    bf16x8 a0 = *(const bf16x8*)Ap;
    bf16x8 b0 = *(const bf16x8*)Wp;
    bf16x8 b1 = *(const bf16x8*)(Wp + 8);
    bf16x8 b2 = *(const bf16x8*)(Wp + 16);
    bf16x8 b3 = *(const bf16x8*)(Wp + 24);

    for (int k0 = 0; k0 < K; k0 += 64) {
        *(bf16x8*)&As[arow][acol]      = a0;
        *(bf16x8*)&Bs[brow][bcol]      = b0;
        *(bf16x8*)&Bs[brow][bcol + 8]  = b1;
        *(bf16x8*)&Bs[brow][bcol + 16] = b2;
        *(bf16x8*)&Bs[brow][bcol + 24] = b3;
        __syncthreads();
        if (k0 + 64 < K) {
            a0 = *(const bf16x8*)(Ap + k0 + 64);
            b0 = *(const bf16x8*)(Wp + k0 + 64);
            b1 = *(const bf16x8*)(Wp + k0 + 72);
            b2 = *(const bf16x8*)(Wp + k0 + 80);
            b3 = *(const bf16x8*)(Wp + k0 + 88);
        }
#pragma unroll
        for (int ks = 0; ks < 2; ++ks) {
            bf16x8 af = *(const bf16x8*)&As[(rh << 4) + m][(ks << 5) + (quad << 3)];
#pragma unroll
            for (int nt = 0; nt < 4; ++nt) {
                bf16x8 bfr = *(const bf16x8*)&Bs[(ch << 6) + (nt << 4) + m][(ks << 5) + (quad << 3)];
                acc[nt] = __builtin_amdgcn_mfma_f32_16x16x32_bf16(af, bfr, acc[nt], 0, 0, 0);
            }
        }
        __syncthreads();
    }

    // ---- epilogue: bias (+PE | +res), write fp32 bh, keep v in registers ----
#pragma unroll
    for (int nt = 0; nt < 4; ++nt) {
        int col = (ch << 6) + (nt << 4) + m;
        float bv = bias[col];
        float fr = 0.f;
        if (FUSE == 0)
            fr = __expf((float)(col & ~1) * (-0.07195578415606394f)); // -ln(1e4)/128
#pragma unroll
        for (int r = 0; r < 4; ++r) {
            int row = n0 + (rh << 4) + (quad << 2) + r;
            float t = acc[nt][r] + bv;
            if (FUSE == 0) {
                float ang = (float)(row & (L_SEQ - 1)) * fr;
                t += (col & 1) ? cosf(ang) : sinf(ang);
            } else {
                t += bh[(size_t)row * 128 + col];
            }
            acc[nt][r] = t;
            bh[(size_t)row * 128 + col] = t;
        }
    }

    if (FUSE < 2) {
        // ---- LN: one-pass sum/sumsq; 64-col partials cross-wave via LDS ----
        float wv[4], bvn[4];
#pragma unroll
        for (int nt = 0; nt < 4; ++nt) {
            wv[nt]  = lnw[(ch << 6) + (nt << 4) + m];
            bvn[nt] = lnb[(ch << 6) + (nt << 4) + m];
        }
        float s1[4], s2[4];
#pragma unroll
        for (int r = 0; r < 4; ++r) {
            float s = 0.f, q = 0.f;
#pragma unroll
            for (int nt = 0; nt < 4; ++nt) {
                float t = acc[nt][r];
                s += t;
                q = fmaf(t, t, q);
            }
            s += __shfl_xor(s, 1);  q += __shfl_xor(q, 1);
            s += __shfl_xor(s, 2);  q += __shfl_xor(q, 2);
            s += __shfl_xor(s, 4);  q += __shfl_xor(q, 4);
            s += __shfl_xor(s, 8);  q += __shfl_xor(q, 8);
            s1[r] = s; s2[r] = q;
            if (m == 0) red[ch][(rh << 4) + (quad << 2) + r] = make_float2(s, q);
        }
        __syncthreads();
#pragma unroll
        for (int r = 0; r < 4; ++r) {
            float2 o = red[ch ^ 1][(rh << 4) + (quad << 2) + r];
            float ts = s1[r] + o.x;
            float tq = s2[r] + o.y;
            float mean = ts * (1.f / 128.f);
            float var  = tq * (1.f / 128.f) - mean * mean;
            float inv  = rsqrtf(var + 1e-5f);
            int row = n0 + (rh << 4) + (quad << 2) + r;
#pragma unroll
            for (int nt = 0; nt < 4; ++nt) {
                int col = (ch << 6) + (nt << 4) + m;
                lnout[(size_t)row * 128 + col] =
                    f2bf((acc[nt][r] - mean) * inv * wv[nt] + bvn[nt]);
            }
        }
    }
}

// ---------------------------------------------------------------------------
// bf16-native MFMA GEMM (validated R3-R7). 64x64 tile, BK=64, reg prefetch.
// Remaining epilogues: BF_RELU (ff1), QKV, SCAN_T.
// ---------------------------------------------------------------------------
enum { EPI_BF_RELU = 0, EPI_QKV = 1, EPI_SCAN_T = 2 };

template <int EPI>
__global__ __launch_bounds__(256) void gemm_bf(const short* __restrict__ A,
                                               const short* __restrict__ W,
                                               const float* __restrict__ bias,
                                               short* __restrict__ outb,  // QKV: qs (ks = +2097152); SCAN_T: pt
                                               short* __restrict__ outv,  // QKV: vt
                                               int K, int E)
{
    __shared__ __align__(16) short As[64][72];
    __shared__ __align__(16) short Bs[64][72];

    const int tid  = threadIdx.x;
    const int wave = tid >> 6;
    const int lane = tid & 63;
    const int m    = lane & 15;
    const int quad = lane >> 4;

    const int n0 = blockIdx.y * 64;
    const int e0 = blockIdx.x * 64;

    const int srow = tid >> 2;
    const int scol = (tid & 3) << 4;

    const short* Ap = A + (size_t)(n0 + srow) * K + scol;
    const short* Wp = W + (size_t)(e0 + srow) * K + scol;

    f32x4 acc[4];
#pragma unroll
    for (int i = 0; i < 4; ++i) acc[i] = (f32x4){0.f, 0.f, 0.f, 0.f};

    bf16x8 a0 = *(const bf16x8*)Ap;
    bf16x8 a1 = *(const bf16x8*)(Ap + 8);
    bf16x8 w0 = *(const bf16x8*)Wp;
    bf16x8 w1 = *(const bf16x8*)(Wp + 8);

    for (int k0 = 0; k0 < K; k0 += 64) {
        *(bf16x8*)&As[srow][scol]     = a0;
        *(bf16x8*)&As[srow][scol + 8] = a1;
        *(bf16x8*)&Bs[srow][scol]     = w0;
        *(bf16x8*)&Bs[srow][scol + 8] = w1;
        __syncthreads();
        if (k0 + 64 < K) {  // prefetch next chunk while MFMAs run
            a0 = *(const bf16x8*)(Ap + k0 + 64);
            a1 = *(const bf16x8*)(Ap + k0 + 72);
            w0 = *(const bf16x8*)(Wp + k0 + 64);
            w1 = *(const bf16x8*)(Wp + k0 + 72);
        }
#pragma unroll
        for (int ks = 0; ks < 2; ++ks) {
            bf16x8 af = *(const bf16x8*)&As[(wave << 4) + m][(ks << 5) + (quad << 3)];
#pragma unroll
            for (int nt = 0; nt < 4; ++nt) {
                bf16x8 bfr = *(const bf16x8*)&Bs[(nt << 4) + m][(ks << 5) + (quad << 3)];
                acc[nt] = __builtin_amdgcn_mfma_f32_16x16x32_bf16(af, bfr, acc[nt], 0, 0, 0);
            }
        }
        __syncthreads();
    }

    if (EPI == EPI_QKV) {
        const float QSC = 0.17677669529663687f * LOG2E;  // 1/sqrt(32) * log2e
        if (e0 < 256) {
            short* dst = (e0 < 128) ? outb : (outb + 2097152);
            int cbase = (e0 < 128) ? e0 : (e0 - 128);
#pragma unroll
            for (int nt = 0; nt < 4; ++nt) {
                int col = cbase + (nt << 4) + m;
                float bv = bias[e0 + (nt << 4) + m];
#pragma unroll
                for (int r = 0; r < 4; ++r) {
                    int row = n0 + (wave << 4) + (quad << 2) + r;
                    float v = acc[nt][r] + bv;
                    if (e0 < 128) v *= QSC;
                    dst[(size_t)row * 128 + col] = f2bf(v);
                }
            }
        } else {
            int bb_ = n0 >> 11;
            int l0  = (n0 & (L_SEQ - 1)) + (wave << 4) + (quad << 2);
#pragma unroll
            for (int nt = 0; nt < 4; ++nt) {
                int c  = (e0 - 256) + (nt << 4) + m;
                int hh = c >> 5, dd = c & 31;
                float bv = bias[e0 + (nt << 4) + m];
                short4v pk;
#pragma unroll
                for (int r = 0; r < 4; ++r) pk[r] = f2bf(acc[nt][r] + bv);
                *(short4v*)&outv[(size_t)((bb_ * 4 + hh) * 32 + dd) * L_SEQ + l0] = pk;
            }
        }
    } else if (EPI == EPI_SCAN_T) {
        // transposed write pt[b][e][l] (fp16): u2 for e<128, sigmoid(g) for e>=128
        int bb_ = n0 >> 11;
        int l0  = (n0 & (L_SEQ - 1)) + (wave << 4) + (quad << 2);
#pragma unroll
        for (int nt = 0; nt < 4; ++nt) {
            int col = e0 + (nt << 4) + m;
            float bv = bias[col];
            short4v pk;
            if (e0 < 128) {
#pragma unroll
                for (int r = 0; r < 4; ++r)
                    pk[r] = f2h((acc[nt][r] + bv) * (2.f * LOG2E));
            } else {
#pragma unroll
                for (int r = 0; r < 4; ++r) {
                    float gr = acc[nt][r] + bv;
                    float g = __builtin_amdgcn_rcpf(
                        1.f + __builtin_amdgcn_exp2f(-gr * LOG2E));
                    pk[r] = f2h(g);
                }
            }
            *(short4v*)&outb[(((size_t)(bb_ * 256 + col)) << 11) + l0] = pk;
        }
    } else {  // EPI_BF_RELU
#pragma unroll
        for (int nt = 0; nt < 4; ++nt) {
            int col = e0 + (nt << 4) + m;
            float bv = bias[col];
#pragma unroll
            for (int r = 0; r < 4; ++r) {
                int row = n0 + (wave << 4) + (quad << 2) + r;
                float v = fmaxf(acc[nt][r] + bv, 0.f);
                outb[(size_t)row * E + col] = f2bf(v);
            }
        }
    }
}

// ---------------------------------------------------------------------------
// SSM gated scan — R13 chunked-parallel version (validated R1: 68 -> ~10 us).
// Recurrence is contractive; 16 chunks of 128 steps each with 128-step
// burn-in from h=0. Sequential depth 2048 -> 256.
// ---------------------------------------------------------------------------
#define SCAN_WARM 128   // burn-in steps (contraction margin)

__device__ __forceinline__ void scan8(float& h, bf16x8 u8, bf16x8 g8,
                                      float a2, short* __restrict__ ob, int l0)
{
#pragma unroll
    for (int i = 0; i < 8; ++i) {
        float u2 = h2f(u8[i]);
        float g  = h2f(g8[i]);
        float omg = 1.f - g;
        float m2  = -2.f * omg;
        float c0 = fmaf(g, h, omg);                          // parallel to exp path
        float e2 = __builtin_amdgcn_exp2f(fmaf(a2, h, u2));  // exp(2x)
        float r  = __builtin_amdgcn_rcpf(1.f + e2);
        h = fmaf(m2, r, c0);
        ob[(l0 + i) * D_MODEL] = f2bf(h);
    }
}

__device__ __forceinline__ void scan8_ns(float& h, bf16x8 u8, bf16x8 g8,
                                         float a2)
{
#pragma unroll
    for (int i = 0; i < 8; ++i) {
        float u2 = h2f(u8[i]);
        float g  = h2f(g8[i]);
        float omg = 1.f - g;
        float m2  = -2.f * omg;
        float c0 = fmaf(g, h, omg);
        float e2 = __builtin_amdgcn_exp2f(fmaf(a2, h, u2));
        float r  = __builtin_amdgcn_rcpf(1.f + e2);
        h = fmaf(m2, r, c0);
    }
}

__global__ __launch_bounds__(64) void scan_kernel(const short* __restrict__ pt,
                                                  const float* __restrict__ A,
                                                  short* __restrict__ hs)
{
    int blk = blockIdx.x;             // 256 blocks = 16 (b,dhalf) x 16 chunks
    int c   = blk & 15;               // chunk index: writes l in [c*128, c*128+128)
    int bd  = blk >> 4;
    int b   = bd >> 1;
    int d   = ((bd & 1) << 6) + threadIdx.x;
    float a2 = 2.f * A[d] * LOG2E;
    const short* up = pt + (((size_t)(b * 256 + d)) << 11);
    const short* gp = up + (((size_t)128) << 11);
    short* ob = hs + ((size_t)(b << 11)) * D_MODEL + d;

    const int lw = c << 7;            // first stored step
    float h = 0.f;

    bf16x8 uA0, uA1, gA0, gA1;

    if (c > 0) {
        // ---- burn-in: SCAN_WARM steps ending at lw, no stores ----
        int l0 = lw - SCAN_WARM;
        uA0 = *(const bf16x8*)(up + l0);
        uA1 = *(const bf16x8*)(up + l0 + 8);
        gA0 = *(const bf16x8*)(gp + l0);
        gA1 = *(const bf16x8*)(gp + l0 + 8);
        for (int l = l0; l < lw; l += 32) {
            bf16x8 uB0 = *(const bf16x8*)(up + l + 16);
            bf16x8 uB1 = *(const bf16x8*)(up + l + 24);
            bf16x8 gB0 = *(const bf16x8*)(gp + l + 16);
            bf16x8 gB1 = *(const bf16x8*)(gp + l + 24);
            scan8_ns(h, uA0, gA0, a2);
            scan8_ns(h, uA1, gA1, a2);
            uA0 = *(const bf16x8*)(up + l + 32);
            uA1 = *(const bf16x8*)(up + l + 40);
            gA0 = *(const bf16x8*)(gp + l + 32);
            gA1 = *(const bf16x8*)(gp + l + 40);
            scan8_ns(h, uB0, gB0, a2);
            scan8_ns(h, uB1, gB1, a2);
        }
    } else {
        uA0 = *(const bf16x8*)(up);
        uA1 = *(const bf16x8*)(up + 8);
        gA0 = *(const bf16x8*)(gp);
        gA1 = *(const bf16x8*)(gp + 8);
    }

    // ---- live phase: 128 steps with stores ----
    for (int l = lw; l < lw + 128; l += 32) {
        bf16x8 uB0 = *(const bf16x8*)(up + l + 16);
        bf16x8 uB1 = *(const bf16x8*)(up + l + 24);
        bf16x8 gB0 = *(const bf16x8*)(gp + l + 16);
        bf16x8 gB1 = *(const bf16x8*)(gp + l + 24);
        scan8(h, uA0, gA0, a2, ob, l);
        scan8(h, uA1, gA1, a2, ob, l + 8);
        if (l + 32 < lw + 128) {      // guard: l+32 would be OOB at chunk end
            uA0 = *(const bf16x8*)(up + l + 32);
            uA1 = *(const bf16x8*)(up + l + 40);
            gA0 = *(const bf16x8*)(gp + l + 32);
            gA1 = *(const bf16x8*)(gp + l + 40);
        }
        scan8(h, uB0, gB0, a2, ob, l + 16);
        scan8(h, uB1, gB1, a2, ob, l + 24);
    }
}

// ---------------------------------------------------------------------------
// Flash attention v6 (R16): v5 staged pipeline + bank-minimal Plds + cvt_pk.
// R4 post-mortem: b64 P write at stride 72 (36 dw) banks = (4m+8kt+2quad)%32
// -> 16 even banks x 8 accesses (2x the minimum); conflicts went UP (8.4M).
// Fix: stride 68 shorts (34 dw, ≡2 mod 32) -> write banks (2m+8kt+2quad)%32
// = 4/bank = wave64-b64 minimum. pf read (rows now 8B-aligned only) becomes
// 2x b64 (also minimum-banked). P pack: v_cvt_pk_bf16_f32 (2 floats/instr)
// replaces 16x f2bf_fast = -24 VALU/chunk/lane.
// ---------------------------------------------------------------------------
__global__ __launch_bounds__(256) void attn_kernel(const short* __restrict__ Qs,
                                                   const short* __restrict__ Ks,
                                                   const short* __restrict__ Vtg,
                                                   short* __restrict__ outb)
{
    __shared__ __align__(16) short Klds[2][64][40];
    __shared__ __align__(16) short Vlds[2][32][72];
    __shared__ __align__(16) short Plds[4][16][68];   // 34-dword rows: bank-minimal

    const int tid  = threadIdx.x;
    const int wave = tid >> 6;
    const int lane = tid & 63;
    const int m    = lane & 15;
    const int quad = lane >> 4;

    // XCD-aware swizzle (validated R4: FETCH 34.8 -> 6.2 MB)
    const int raw = blockIdx.x;
    const int bid = (raw & 7) * 128 + (raw >> 3);
    const int b  = bid >> 7;
    const int h  = (bid >> 5) & 3;
    const int q0 = (bid & 31) << 6;

    bf16x8 qfrag = *(const bf16x8*)&Qs[((size_t)((b << 11) + q0 + (wave << 4) + m)) * 128
                                       + (h << 5) + (quad << 3)];

    f32x4 O[2];
    O[0] = (f32x4){0.f, 0.f, 0.f, 0.f};
    O[1] = (f32x4){0.f, 0.f, 0.f, 0.f};
    float rs = 0.f;

    const int krow = tid >> 2, dg = (tid & 3) << 3;
    const int vrow = tid >> 3, kg = (tid & 7) << 3;
    const short* kbase = Ks + ((size_t)(b << 11) + krow) * 128 + (h << 5) + dg;
    const short* vbase = Vtg + ((size_t)((b << 2) + h) * 32 + vrow) * L_SEQ + kg;

    // stage chunk 0
    bf16x8 kreg = *(const bf16x8*)kbase;
    bf16x8 vreg = *(const bf16x8*)vbase;
    *(bf16x8*)&Klds[0][krow][dg] = kreg;
    *(bf16x8*)&Vlds[0][vrow][kg] = vreg;
    __syncthreads();

    for (int kc = 0; kc < 32; ++kc) {
        const int cur = kc & 1;
        if (kc < 31) {  // prefetch next chunk into registers (coalesced bulk)
            kreg = *(const bf16x8*)(kbase + (size_t)((kc + 1) << 6) * 128);
            vreg = *(const bf16x8*)(vbase + ((kc + 1) << 6));
        }

        // ---- swapped QK^T: S^T = mfma(K, Q); lane (m,quad) r holds
        //      P[q=m][k=kt*16+quad*4+r] -> b64 P spill via cvt_pk ----
#pragma unroll
        for (int kt = 0; kt < 4; ++kt) {
            bf16x8 kf = *(const bf16x8*)&Klds[cur][(kt << 4) + m][quad << 3];
            f32x4 S = __builtin_amdgcn_mfma_f32_16x16x32_bf16(
                kf, qfrag, (f32x4){0.f, 0.f, 0.f, 0.f}, 0, 0, 0);
            float p0 = __builtin_amdgcn_exp2f(S[0]);
            float p1 = __builtin_amdgcn_exp2f(S[1]);
            float p2 = __builtin_amdgcn_exp2f(S[2]);
            float p3 = __builtin_amdgcn_exp2f(S[3]);
            rs += p0 + p1 + p2 + p3;
            uint2 pk;
            pk.x = cvt_pk_bf16(p0, p1);
            pk.y = cvt_pk_bf16(p2, p3);
            *(uint2*)&Plds[wave][m][(kt << 4) + (quad << 2)] = pk;
        }

        // ---- PV (Plds per-wave: intra-wave lgkmcnt only, no barrier) ----
#pragma unroll
        for (int kt2 = 0; kt2 < 2; ++kt2) {
            short4v plo = *(const short4v*)&Plds[wave][m][(kt2 << 5) + (quad << 3)];
            short4v phi = *(const short4v*)&Plds[wave][m][(kt2 << 5) + (quad << 3) + 4];
            bf16x8 pf = {plo[0], plo[1], plo[2], plo[3],
                         phi[0], phi[1], phi[2], phi[3]};
#pragma unroll
            for (int dt = 0; dt < 2; ++dt) {
                bf16x8 vf = *(const bf16x8*)&Vlds[cur][(dt << 4) + m][(kt2 << 5) + (quad << 3)];
                O[dt] = __builtin_amdgcn_mfma_f32_16x16x32_bf16(pf, vf, O[dt], 0, 0, 0);
            }
        }

        // ---- write next K/V buffer; single barrier per chunk ----
        if (kc < 31) {
            *(bf16x8*)&Klds[cur ^ 1][krow][dg] = kreg;
            *(bf16x8*)&Vlds[cur ^ 1][vrow][kg] = vreg;
        }
        __syncthreads();
    }

    // rs per lane = sum over its quad-slice of k for q = m; finish across quads
    rs += __shfl_xor(rs, 16);
    rs += __shfl_xor(rs, 32);

#pragma unroll
    for (int r = 0; r < 4; ++r) {
        float sv  = __shfl(rs, (quad << 2) + r);   // rs(q=quad*4+r) lives at lane q
        float inv = 1.f / sv;
        int row = (b << 11) + q0 + (wave << 4) + (quad << 2) + r;
        short* op = outb + (size_t)row * D_MODEL + (h << 5) + m;
        op[0]  = f2bf(O[0][r] * inv);
        op[16] = f2bf(O[1][r] * inv);
    }
}

// ---------------------------------------------------------------------------
// Fused pool + head (R12): one 1024-thread block per batch element.
// ---------------------------------------------------------------------------
__global__ __launch_bounds__(1024) void pool_head_kernel(
    const float* __restrict__ h,
    const float* __restrict__ hlnw, const float* __restrict__ hlnb,
    const float* __restrict__ h1w, const float* __restrict__ h1b,
    const float* __restrict__ h2w, const float* __restrict__ h2b,
    float* __restrict__ out)
{
    __shared__ float part[8][128];
    __shared__ float sd[128];
    __shared__ float sq[128];

    int b   = blockIdx.x;
    int t   = threadIdx.x;
    int d   = t & 127;
    int seg = t >> 7;    // 0..7
    const float* hb = h + (size_t)b * L_SEQ * D_MODEL;

    // ---- phase 1: pool ----
    float acc = 0.f;
    int l0 = seg << 8;
    for (int l = l0; l < l0 + 256; l += 4) {
        acc += hb[(l + 0) * D_MODEL + d] + hb[(l + 1) * D_MODEL + d]
             + hb[(l + 2) * D_MODEL + d] + hb[(l + 3) * D_MODEL + d];
    }
    part[seg][d] = acc;
    __syncthreads();

    // ---- phase 2: head (threads 0..127 compute; all hit barriers) ----
    float v = 0.f;
    if (t < 128) {
        float s = 0.f;
#pragma unroll
        for (int i = 0; i < 8; ++i) s += part[i][t];
        v = 0.5f * hb[(L_SEQ - 1) * D_MODEL + t] + 0.5f * (s * (1.f / (float)L_SEQ));
        sd[t] = v;
    }
    __syncthreads();
    for (int s = 64; s > 0; s >>= 1) {
        if (t < s) sd[t] += sd[t + s];
        __syncthreads();
    }
    float mu = sd[0] * (1.f / 128.f);
    __syncthreads();
    float dv = v - mu;
    if (t < 128) sd[t] = dv * dv;
    __syncthreads();
    for (int s = 64; s > 0; s >>= 1) {
        if (t < s) sd[t] += sd[t + s];
        __syncthreads();
    }
    float var = sd[0] * (1.f / 128.f);
    __syncthreads();
    if (t < 128) sq[t] = dv * rsqrtf(var + 1e-5f) * hlnw[t] + hlnb[t];
    __syncthreads();
    if (t < 128) {
        float dot = h1b[t];
        for (int d2 = 0; d2 < 128; ++d2) dot = fmaf(sq[d2], h1w[t * 128 + d2], dot);
        float ge = 0.5f * dot * (1.f + erff(dot * 0.7071067811865475f));
        sd[t] = ge * h2w[t];
    }
    __syncthreads();
    for (int s = 64; s > 0; s >>= 1) {
        if (t < s) sd[t] += sd[t + s];
        __syncthreads();
    }
    if (t == 0) out[b] = sd[0] + h2b[0];
}

// ---------------------------------------------------------------------------
extern "C" void kernel_launch(void* const* d_in, const int* in_sizes, int n_in,
                              void* d_out, int out_size, void* d_ws, size_t ws_size,
                              hipStream_t stream)
{
    (void)in_sizes; (void)n_in; (void)out_size; (void)ws_size;
    const float* x      = (const float*)d_in[0];
    const float* in_w   = (const float*)d_in[1];
    const float* in_b   = (const float*)d_in[2];
    const float* ssm_nw = (const float*)d_in[3];
    const float* ssm_nb = (const float*)d_in[4];
    const float* ssm_A  = (const float*)d_in[5];
    const float* ssm_iw = (const float*)d_in[6];
    const float* ssm_ib = (const float*)d_in[7];
    const float* ssm_ow = (const float*)d_in[8];
    const float* ssm_ob = (const float*)d_in[9];
    const float* ln1w   = (const float*)d_in[10];
    const float* ln1b   = (const float*)d_in[11];
    const float* ln2w   = (const float*)d_in[12];
    const float* ln2b   = (const float*)d_in[13];
    const float* qkvw   = (const float*)d_in[14];
    const float* qkvb   = (const float*)d_in[15];
    const float* aow    = (const float*)d_in[16];
    const float* aob    = (const float*)d_in[17];
    const float* f1w    = (const float*)d_in[18];
    const float* f1b    = (const float*)d_in[19];
    const float* f2w    = (const float*)d_in[20];
    const float* f2b    = (const float*)d_in[21];
    const float* hlnw   = (const float*)d_in[22];
    const float* hlnb   = (const float*)d_in[23];
    const float* h1w    = (const float*)d_in[24];
    const float* h1b    = (const float*)d_in[25];
    const float* h2w    = (const float*)d_in[26];
    const float* h2b    = (const float*)d_in[27];
    float* out = (float*)d_out;

    char* wsb = (char*)d_ws;
    float* bh     = (float*)(wsb);               // [N,128] fp32 residual stream (8 MB)
    short* abuf   = (short*)(wsb + 8388608);     // [N,512] bf16 wide scratch / scan pt (16 MB)
    short* bbuf   = (short*)(wsb + 25165824);    // [N,128] bf16 ln/hs/attn-out (4 MB)
    short* qs     = (short*)(wsb + 29360128);    // [N,128] bf16 Q prescaled; ks = +2097152
    short* vt     = (short*)(wsb + 37748736);    // [B,4,32,2048] bf16 V^T (4 MB)
    short* xb     = (short*)(wsb + 41943040);    // [N,64] bf16 input (2 MB)
    short* wb     = (short*)(wsb + 44040192);    // bf16 weights (~1 MB)
    short* ks     = qs + 2097152;

    dim3 blk(256);

    convert_kernel<<<756, blk, 0, stream>>>(x, in_w, ssm_iw, ssm_ow, qkvw, aow, f1w, f2w, xb, wb);

    // input projection + PE + LN(ssm_norm0): writes bh (fp32) and bbuf (bf16 LN)
    gemm_ln<0><<<512, blk, 0, stream>>>(
        xb, wb, in_b, ssm_nw, ssm_nb, bh, bbuf, 64);

    // SSM block 0
    gemm_bf<EPI_SCAN_T><<<dim3(4, 256), blk, 0, stream>>>(
        bbuf, wb + 8192, ssm_ib, abuf, nullptr, 128, 256);
    scan_kernel<<<256, 64, 0, stream>>>(abuf, ssm_A, bbuf);
    gemm_ln<1><<<512, blk, 0, stream>>>(                       // +res, LN(ssm_norm1)
        bbuf, wb + 73728, ssm_ob, ssm_nw + 128, ssm_nb + 128, bh, bbuf, 128);

    // SSM block 1
    gemm_bf<EPI_SCAN_T><<<dim3(4, 256), blk, 0, stream>>>(
        bbuf, wb + 8192 + 32768, ssm_ib + 256, abuf, nullptr, 128, 256);
    scan_kernel<<<256, 64, 0, stream>>>(abuf, ssm_A + 128, bbuf);
    gemm_ln<1><<<512, blk, 0, stream>>>(                       // +res, LN(ln1[0])
        bbuf, wb + 73728 + 16384, ssm_ob + 128, ln1w, ln1b, bh, bbuf, 128);

    // Encoder layer 0
    gemm_bf<EPI_QKV><<<dim3(6, 256), blk, 0, stream>>>(
        bbuf, wb + 106496, qkvb, qs, vt, 128, 384);
    attn_kernel<<<1024, blk, 0, stream>>>(qs, ks, vt, bbuf);
    gemm_ln<1><<<512, blk, 0, stream>>>(                       // +res, LN(ln2[0])
        bbuf, wb + 204800, aob, ln2w, ln2b, bh, bbuf, 128);
    gemm_bf<EPI_BF_RELU><<<dim3(8, 256), blk, 0, stream>>>(
        bbuf, wb + 237568, f1b, abuf, nullptr, 128, 512);
    gemm_ln<1><<<512, blk, 0, stream>>>(                       // ff2[0] +res, LN(ln1[1])
        abuf, wb + 368640, f2b, ln1w + 128, ln1b + 128, bh, bbuf, 512);

    // Encoder layer 1
    gemm_bf<EPI_QKV><<<dim3(6, 256), blk, 0, stream>>>(
        bbuf, wb + 106496 + 49152, qkvb + 384, qs, vt, 128, 384);
    attn_kernel<<<1024, blk, 0, stream>>>(qs, ks, vt, bbuf);
    gemm_ln<1><<<512, blk, 0, stream>>>(                       // +res, LN(ln2[1])
        bbuf, wb + 204800 + 16384, aob + 128, ln2w + 128, ln2b + 128, bh, bbuf, 128);
    gemm_bf<EPI_BF_RELU><<<dim3(8, 256), blk, 0, stream>>>(
        bbuf, wb + 237568 + 65536, f1b + 512, abuf, nullptr, 128, 512);
    gemm_ln<2><<<512, blk, 0, stream>>>(                       // ff2[1] +res only
        abuf, wb + 368640 + 65536, f2b + 128, nullptr, nullptr, bh, nullptr, 512);

    pool_head_kernel<<<8, 1024, 0, stream>>>(bh, hlnw, hlnb, h1w, h1b, h2w, h2b, out);
}

// Round 7
// 343.361 us; speedup vs baseline: 1.4676x; 1.0116x over previous
//
#include <hip/hip_runtime.h>
#include <hip/hip_bf16.h>
#include <math.h>

#define L_SEQ 2048
#define D_MODEL 128
#define N_ROWS 16384  // B*L = 8*2048
#define LOG2E 1.4426950408889634f

typedef __attribute__((ext_vector_type(8))) short bf16x8;
typedef __attribute__((ext_vector_type(4))) short short4v;
typedef __attribute__((ext_vector_type(4))) float f32x4;

__device__ __forceinline__ short f2bf(float x)  // RNE
{
    __hip_bfloat16 b = __float2bfloat16(x);
    return *reinterpret_cast<short*>(&b);
}
__device__ __forceinline__ short f2bf_fast(float x)  // round-half-up, x >= 0
{
    unsigned u = __builtin_bit_cast(unsigned, x);
    return (short)((u + 0x8000u) >> 16);
}
__device__ __forceinline__ unsigned cvt_pk_bf16(float lo, float hi)  // 2xbf16 in 1 instr
{
    unsigned r;
    asm("v_cvt_pk_bf16_f32 %0, %1, %2" : "=v"(r) : "v"(lo), "v"(hi));
    return r;
}
__device__ __forceinline__ float bf2f(short s)
{
    unsigned u = ((unsigned)(unsigned short)s) << 16;
    return __builtin_bit_cast(float, u);
}
__device__ __forceinline__ short f2h(float x)   // v_cvt_f16_f32
{
    _Float16 h = (_Float16)x;
    return (short)__builtin_bit_cast(unsigned short, h);
}
__device__ __forceinline__ float h2f(short s)   // v_cvt_f32_f16
{
    _Float16 h = __builtin_bit_cast(_Float16, (unsigned short)s);
    return (float)h;
}

// ---------------------------------------------------------------------------
// One-shot fp32 -> bf16 conversion of x and all weight matrices.
// ---------------------------------------------------------------------------
__global__ __launch_bounds__(256) void convert_kernel(
    const float* __restrict__ x,    const float* __restrict__ inw,
    const float* __restrict__ ssmi, const float* __restrict__ ssmo,
    const float* __restrict__ qkvw, const float* __restrict__ aow,
    const float* __restrict__ f1w,  const float* __restrict__ f2w,
    short* __restrict__ xb, short* __restrict__ wb)
{
    int it = blockIdx.x * 256 + threadIdx.x;
    const float* src; short* dst; int off;
    if      (it < 131072) { src = x;    dst = xb;          off = it; }
    else if (it < 132096) { src = inw;  dst = wb;          off = it - 131072; }
    else if (it < 140288) { src = ssmi; dst = wb + 8192;   off = it - 132096; }
    else if (it < 144384) { src = ssmo; dst = wb + 73728;  off = it - 140288; }
    else if (it < 156672) { src = qkvw; dst = wb + 106496; off = it - 144384; }
    else if (it < 160768) { src = aow;  dst = wb + 204800; off = it - 156672; }
    else if (it < 177152) { src = f1w;  dst = wb + 237568; off = it - 160768; }
    else                  { src = f2w;  dst = wb + 368640; off = it - 177152; }
    off <<= 3;
    float4 v0 = *(const float4*)(src + off);
    float4 v1 = *(const float4*)(src + off + 4);
    bf16x8 p = {f2bf(v0.x), f2bf(v0.y), f2bf(v0.z), f2bf(v0.w),
                f2bf(v1.x), f2bf(v1.y), f2bf(v1.z), f2bf(v1.w)};
    *(bf16x8*)(dst + off) = p;
}

// ---------------------------------------------------------------------------
// Fused E=128 GEMM + residual + LayerNorm (R16 occupancy rework, validated R5).
// 32-row x 128-col blocks, grid 512 -> 2 blocks/CU. 4 waves = rh x ch; LN via
// one-pass sum/sumsq partials + 256B LDS cross-wave combine.
// FUSE: 0 = PE+LN, 1 = RES+LN, 2 = RES only (last ff2).
// ---------------------------------------------------------------------------
template <int FUSE>
__global__ __launch_bounds__(256) void gemm_ln(const short* __restrict__ A,
                                               const short* __restrict__ W,
                                               const float* __restrict__ bias,
                                               const float* __restrict__ lnw,
                                               const float* __restrict__ lnb,
                                               float* __restrict__ bh,
                                               short* __restrict__ lnout,
                                               int K)
{
    __shared__ __align__(16) short As[32][72];
    __shared__ __align__(16) short Bs[128][72];
    __shared__ float2 red[2][32];

    const int tid  = threadIdx.x;
    const int wave = tid >> 6;
    const int lane = tid & 63;
    const int m    = lane & 15;
    const int quad = lane >> 4;
    const int rh   = wave & 1;     // row half (16 rows)
    const int ch   = wave >> 1;    // col half (64 cols)
    const int n0   = blockIdx.x * 32;

    const int arow = tid >> 3, acol = (tid & 7) << 3;
    const int brow = tid >> 1, bcol = (tid & 1) << 5;

    const short* Ap = A + (size_t)(n0 + arow) * K + acol;
    const short* Wp = W + (size_t)brow * K + bcol;

    f32x4 acc[4];
#pragma unroll
    for (int i = 0; i < 4; ++i) acc[i] = (f32x4){0.f, 0.f, 0.f, 0.f};

    bf16x8 a0 = *(const bf16x8*)Ap;
    bf16x8 b0 = *(const bf16x8*)Wp;
    bf16x8 b1 = *(const bf16x8*)(Wp + 8);
    bf16x8 b2 = *(const bf16x8*)(Wp + 16);
    bf16x8 b3 = *(const bf16x8*)(Wp + 24);

    for (int k0 = 0; k0 < K; k0 += 64) {
        *(bf16x8*)&As[arow][acol]      = a0;
        *(bf16x8*)&Bs[brow][bcol]      = b0;
        *(bf16x8*)&Bs[brow][bcol + 8]  = b1;
        *(bf16x8*)&Bs[brow][bcol + 16] = b2;
        *(bf16x8*)&Bs[brow][bcol + 24] = b3;
        __syncthreads();
        if (k0 + 64 < K) {
            a0 = *(const bf16x8*)(Ap + k0 + 64);
            b0 = *(const bf16x8*)(Wp + k0 + 64);
            b1 = *(const bf16x8*)(Wp + k0 + 72);
            b2 = *(const bf16x8*)(Wp + k0 + 80);
            b3 = *(const bf16x8*)(Wp + k0 + 88);
        }
#pragma unroll
        for (int ks = 0; ks < 2; ++ks) {
            bf16x8 af = *(const bf16x8*)&As[(rh << 4) + m][(ks << 5) + (quad << 3)];
#pragma unroll
            for (int nt = 0; nt < 4; ++nt) {
                bf16x8 bfr = *(const bf16x8*)&Bs[(ch << 6) + (nt << 4) + m][(ks << 5) + (quad << 3)];
                acc[nt] = __builtin_amdgcn_mfma_f32_16x16x32_bf16(af, bfr, acc[nt], 0, 0, 0);
            }
        }
        __syncthreads();
    }

    // ---- epilogue: bias (+PE | +res), write fp32 bh, keep v in registers ----
#pragma unroll
    for (int nt = 0; nt < 4; ++nt) {
        int col = (ch << 6) + (nt << 4) + m;
        float bv = bias[col];
        float fr = 0.f;
        if (FUSE == 0)
            fr = __expf((float)(col & ~1) * (-0.07195578415606394f)); // -ln(1e4)/128
#pragma unroll
        for (int r = 0; r < 4; ++r) {
            int row = n0 + (rh << 4) + (quad << 2) + r;
            float t = acc[nt][r] + bv;
            if (FUSE == 0) {
                float ang = (float)(row & (L_SEQ - 1)) * fr;
                t += (col & 1) ? cosf(ang) : sinf(ang);
            } else {
                t += bh[(size_t)row * 128 + col];
            }
            acc[nt][r] = t;
            bh[(size_t)row * 128 + col] = t;
        }
    }

    if (FUSE < 2) {
        // ---- LN: one-pass sum/sumsq; 64-col partials cross-wave via LDS ----
        float wv[4], bvn[4];
#pragma unroll
        for (int nt = 0; nt < 4; ++nt) {
            wv[nt]  = lnw[(ch << 6) + (nt << 4) + m];
            bvn[nt] = lnb[(ch << 6) + (nt << 4) + m];
        }
        float s1[4], s2[4];
#pragma unroll
        for (int r = 0; r < 4; ++r) {
            float s = 0.f, q = 0.f;
#pragma unroll
            for (int nt = 0; nt < 4; ++nt) {
                float t = acc[nt][r];
                s += t;
                q = fmaf(t, t, q);
            }
            s += __shfl_xor(s, 1);  q += __shfl_xor(q, 1);
            s += __shfl_xor(s, 2);  q += __shfl_xor(q, 2);
            s += __shfl_xor(s, 4);  q += __shfl_xor(q, 4);
            s += __shfl_xor(s, 8);  q += __shfl_xor(q, 8);
            s1[r] = s; s2[r] = q;
            if (m == 0) red[ch][(rh << 4) + (quad << 2) + r] = make_float2(s, q);
        }
        __syncthreads();
#pragma unroll
        for (int r = 0; r < 4; ++r) {
            float2 o = red[ch ^ 1][(rh << 4) + (quad << 2) + r];
            float ts = s1[r] + o.x;
            float tq = s2[r] + o.y;
            float mean = ts * (1.f / 128.f);
            float var  = tq * (1.f / 128.f) - mean * mean;
            float inv  = rsqrtf(var + 1e-5f);
            int row = n0 + (rh << 4) + (quad << 2) + r;
#pragma unroll
            for (int nt = 0; nt < 4; ++nt) {
                int col = (ch << 6) + (nt << 4) + m;
                lnout[(size_t)row * 128 + col] =
                    f2bf((acc[nt][r] - mean) * inv * wv[nt] + bvn[nt]);
            }
        }
    }
}

// ---------------------------------------------------------------------------
// bf16-native MFMA GEMM (validated R3-R7). 64x64 tile, BK=64, reg prefetch.
// Remaining epilogues: BF_RELU (ff1), QKV, SCAN_T.
// ---------------------------------------------------------------------------
enum { EPI_BF_RELU = 0, EPI_QKV = 1, EPI_SCAN_T = 2 };

template <int EPI>
__global__ __launch_bounds__(256) void gemm_bf(const short* __restrict__ A,
                                               const short* __restrict__ W,
                                               const float* __restrict__ bias,
                                               short* __restrict__ outb,  // QKV: qs (ks = +2097152); SCAN_T: pt
                                               short* __restrict__ outv,  // QKV: vt
                                               int K, int E)
{
    __shared__ __align__(16) short As[64][72];
    __shared__ __align__(16) short Bs[64][72];

    const int tid  = threadIdx.x;
    const int wave = tid >> 6;
    const int lane = tid & 63;
    const int m    = lane & 15;
    const int quad = lane >> 4;

    const int n0 = blockIdx.y * 64;
    const int e0 = blockIdx.x * 64;

    const int srow = tid >> 2;
    const int scol = (tid & 3) << 4;

    const short* Ap = A + (size_t)(n0 + srow) * K + scol;
    const short* Wp = W + (size_t)(e0 + srow) * K + scol;

    f32x4 acc[4];
#pragma unroll
    for (int i = 0; i < 4; ++i) acc[i] = (f32x4){0.f, 0.f, 0.f, 0.f};

    bf16x8 a0 = *(const bf16x8*)Ap;
    bf16x8 a1 = *(const bf16x8*)(Ap + 8);
    bf16x8 w0 = *(const bf16x8*)Wp;
    bf16x8 w1 = *(const bf16x8*)(Wp + 8);

    for (int k0 = 0; k0 < K; k0 += 64) {
        *(bf16x8*)&As[srow][scol]     = a0;
        *(bf16x8*)&As[srow][scol + 8] = a1;
        *(bf16x8*)&Bs[srow][scol]     = w0;
        *(bf16x8*)&Bs[srow][scol + 8] = w1;
        __syncthreads();
        if (k0 + 64 < K) {  // prefetch next chunk while MFMAs run
            a0 = *(const bf16x8*)(Ap + k0 + 64);
            a1 = *(const bf16x8*)(Ap + k0 + 72);
            w0 = *(const bf16x8*)(Wp + k0 + 64);
            w1 = *(const bf16x8*)(Wp + k0 + 72);
        }
#pragma unroll
        for (int ks = 0; ks < 2; ++ks) {
            bf16x8 af = *(const bf16x8*)&As[(wave << 4) + m][(ks << 5) + (quad << 3)];
#pragma unroll
            for (int nt = 0; nt < 4; ++nt) {
                bf16x8 bfr = *(const bf16x8*)&Bs[(nt << 4) + m][(ks << 5) + (quad << 3)];
                acc[nt] = __builtin_amdgcn_mfma_f32_16x16x32_bf16(af, bfr, acc[nt], 0, 0, 0);
            }
        }
        __syncthreads();
    }

    if (EPI == EPI_QKV) {
        const float QSC = 0.17677669529663687f * LOG2E;  // 1/sqrt(32) * log2e
        if (e0 < 256) {
            short* dst = (e0 < 128) ? outb : (outb + 2097152);
            int cbase = (e0 < 128) ? e0 : (e0 - 128);
#pragma unroll
            for (int nt = 0; nt < 4; ++nt) {
                int col = cbase + (nt << 4) + m;
                float bv = bias[e0 + (nt << 4) + m];
#pragma unroll
                for (int r = 0; r < 4; ++r) {
                    int row = n0 + (wave << 4) + (quad << 2) + r;
                    float v = acc[nt][r] + bv;
                    if (e0 < 128) v *= QSC;
                    dst[(size_t)row * 128 + col] = f2bf(v);
                }
            }
        } else {
            int bb_ = n0 >> 11;
            int l0  = (n0 & (L_SEQ - 1)) + (wave << 4) + (quad << 2);
#pragma unroll
            for (int nt = 0; nt < 4; ++nt) {
                int c  = (e0 - 256) + (nt << 4) + m;
                int hh = c >> 5, dd = c & 31;
                float bv = bias[e0 + (nt << 4) + m];
                short4v pk;
#pragma unroll
                for (int r = 0; r < 4; ++r) pk[r] = f2bf(acc[nt][r] + bv);
                *(short4v*)&outv[(size_t)((bb_ * 4 + hh) * 32 + dd) * L_SEQ + l0] = pk;
            }
        }
    } else if (EPI == EPI_SCAN_T) {
        // transposed write pt[b][e][l] (fp16): u2 for e<128, sigmoid(g) for e>=128
        int bb_ = n0 >> 11;
        int l0  = (n0 & (L_SEQ - 1)) + (wave << 4) + (quad << 2);
#pragma unroll
        for (int nt = 0; nt < 4; ++nt) {
            int col = e0 + (nt << 4) + m;
            float bv = bias[col];
            short4v pk;
            if (e0 < 128) {
#pragma unroll
                for (int r = 0; r < 4; ++r)
                    pk[r] = f2h((acc[nt][r] + bv) * (2.f * LOG2E));
            } else {
#pragma unroll
                for (int r = 0; r < 4; ++r) {
                    float gr = acc[nt][r] + bv;
                    float g = __builtin_amdgcn_rcpf(
                        1.f + __builtin_amdgcn_exp2f(-gr * LOG2E));
                    pk[r] = f2h(g);
                }
            }
            *(short4v*)&outb[(((size_t)(bb_ * 256 + col)) << 11) + l0] = pk;
        }
    } else {  // EPI_BF_RELU
#pragma unroll
        for (int nt = 0; nt < 4; ++nt) {
            int col = e0 + (nt << 4) + m;
            float bv = bias[col];
#pragma unroll
            for (int r = 0; r < 4; ++r) {
                int row = n0 + (wave << 4) + (quad << 2) + r;
                float v = fmaxf(acc[nt][r] + bv, 0.f);
                outb[(size_t)row * E + col] = f2bf(v);
            }
        }
    }
}

// ---------------------------------------------------------------------------
// SSM gated scan — R13 chunked-parallel version (validated R1: 68 -> ~10 us).
// Recurrence is contractive; 16 chunks of 128 steps each with 128-step
// burn-in from h=0. Sequential depth 2048 -> 256.
// ---------------------------------------------------------------------------
#define SCAN_WARM 128   // burn-in steps (contraction margin)

__device__ __forceinline__ void scan8(float& h, bf16x8 u8, bf16x8 g8,
                                      float a2, short* __restrict__ ob, int l0)
{
#pragma unroll
    for (int i = 0; i < 8; ++i) {
        float u2 = h2f(u8[i]);
        float g  = h2f(g8[i]);
        float omg = 1.f - g;
        float m2  = -2.f * omg;
        float c0 = fmaf(g, h, omg);                          // parallel to exp path
        float e2 = __builtin_amdgcn_exp2f(fmaf(a2, h, u2));  // exp(2x)
        float r  = __builtin_amdgcn_rcpf(1.f + e2);
        h = fmaf(m2, r, c0);
        ob[(l0 + i) * D_MODEL] = f2bf(h);
    }
}

__device__ __forceinline__ void scan8_ns(float& h, bf16x8 u8, bf16x8 g8,
                                         float a2)
{
#pragma unroll
    for (int i = 0; i < 8; ++i) {
        float u2 = h2f(u8[i]);
        float g  = h2f(g8[i]);
        float omg = 1.f - g;
        float m2  = -2.f * omg;
        float c0 = fmaf(g, h, omg);
        float e2 = __builtin_amdgcn_exp2f(fmaf(a2, h, u2));
        float r  = __builtin_amdgcn_rcpf(1.f + e2);
        h = fmaf(m2, r, c0);
    }
}

__global__ __launch_bounds__(64) void scan_kernel(const short* __restrict__ pt,
                                                  const float* __restrict__ A,
                                                  short* __restrict__ hs)
{
    int blk = blockIdx.x;             // 256 blocks = 16 (b,dhalf) x 16 chunks
    int c   = blk & 15;               // chunk index: writes l in [c*128, c*128+128)
    int bd  = blk >> 4;
    int b   = bd >> 1;
    int d   = ((bd & 1) << 6) + threadIdx.x;
    float a2 = 2.f * A[d] * LOG2E;
    const short* up = pt + (((size_t)(b * 256 + d)) << 11);
    const short* gp = up + (((size_t)128) << 11);
    short* ob = hs + ((size_t)(b << 11)) * D_MODEL + d;

    const int lw = c << 7;            // first stored step
    float h = 0.f;

    bf16x8 uA0, uA1, gA0, gA1;

    if (c > 0) {
        // ---- burn-in: SCAN_WARM steps ending at lw, no stores ----
        int l0 = lw - SCAN_WARM;
        uA0 = *(const bf16x8*)(up + l0);
        uA1 = *(const bf16x8*)(up + l0 + 8);
        gA0 = *(const bf16x8*)(gp + l0);
        gA1 = *(const bf16x8*)(gp + l0 + 8);
        for (int l = l0; l < lw; l += 32) {
            bf16x8 uB0 = *(const bf16x8*)(up + l + 16);
            bf16x8 uB1 = *(const bf16x8*)(up + l + 24);
            bf16x8 gB0 = *(const bf16x8*)(gp + l + 16);
            bf16x8 gB1 = *(const bf16x8*)(gp + l + 24);
            scan8_ns(h, uA0, gA0, a2);
            scan8_ns(h, uA1, gA1, a2);
            uA0 = *(const bf16x8*)(up + l + 32);
            uA1 = *(const bf16x8*)(up + l + 40);
            gA0 = *(const bf16x8*)(gp + l + 32);
            gA1 = *(const bf16x8*)(gp + l + 40);
            scan8_ns(h, uB0, gB0, a2);
            scan8_ns(h, uB1, gB1, a2);
        }
    } else {
        uA0 = *(const bf16x8*)(up);
        uA1 = *(const bf16x8*)(up + 8);
        gA0 = *(const bf16x8*)(gp);
        gA1 = *(const bf16x8*)(gp + 8);
    }

    // ---- live phase: 128 steps with stores ----
    for (int l = lw; l < lw + 128; l += 32) {
        bf16x8 uB0 = *(const bf16x8*)(up + l + 16);
        bf16x8 uB1 = *(const bf16x8*)(up + l + 24);
        bf16x8 gB0 = *(const bf16x8*)(gp + l + 16);
        bf16x8 gB1 = *(const bf16x8*)(gp + l + 24);
        scan8(h, uA0, gA0, a2, ob, l);
        scan8(h, uA1, gA1, a2, ob, l + 8);
        if (l + 32 < lw + 128) {      // guard: l+32 would be OOB at chunk end
            uA0 = *(const bf16x8*)(up + l + 32);
            uA1 = *(const bf16x8*)(up + l + 40);
            gA0 = *(const bf16x8*)(gp + l + 32);
            gA1 = *(const bf16x8*)(gp + l + 40);
        }
        scan8(h, uB0, gB0, a2, ob, l + 16);
        scan8(h, uB1, gB1, a2, ob, l + 24);
    }
}

// ---------------------------------------------------------------------------
// Flash attention v7 (R17): 2 q-tiles per wave (128 q-rows per block).
// R5 counters: conflicts dropped (8.4->5.2M) but time flat -> LDS raw BW is
// the floor: 56KB LDS traffic per chunk per block, of which kf+vf (32KB) is
// 4-wave-redundant reads of the same 8KB K/V chunk. Amortize: each wave
// computes 2 q-fragments -> kf/vf reads serve 2x MFMAs. Per-work LDS traffic
// 56 -> 36KB (-36%); staging + addressing VALU also halve per work.
// exp2/cvt_pk unchanged (1 per P element, irreducible). Grid 1024 -> 512
// (2 blocks/CU); XCD swizzle: 64 logical blocks = one batch element per XCD.
// ---------------------------------------------------------------------------
__global__ __launch_bounds__(256) void attn_kernel(const short* __restrict__ Qs,
                                                   const short* __restrict__ Ks,
                                                   const short* __restrict__ Vtg,
                                                   short* __restrict__ outb)
{
    __shared__ __align__(16) short Klds[2][64][40];
    __shared__ __align__(16) short Vlds[2][32][72];
    __shared__ __align__(16) short Plds[4][32][68];   // [wave][qt*16+m][k] 34-dw rows

    const int tid  = threadIdx.x;
    const int wave = tid >> 6;
    const int lane = tid & 63;
    const int m    = lane & 15;
    const int quad = lane >> 4;

    // XCD-aware swizzle for grid 512: XCD x gets logical [x*64, x*64+64)
    // = all 64 blocks of batch element x (1MB KV in its L2).
    const int raw = blockIdx.x;
    const int bid = (raw & 7) * 64 + (raw >> 3);
    const int b  = bid >> 6;
    const int h  = (bid >> 4) & 3;
    const int q0 = (bid & 15) << 7;       // 128 q-rows per block

    const size_t qrow = (size_t)((b << 11) + q0 + (wave << 5) + m);
    bf16x8 qfA = *(const bf16x8*)&Qs[qrow * 128 + (h << 5) + (quad << 3)];
    bf16x8 qfB = *(const bf16x8*)&Qs[(qrow + 16) * 128 + (h << 5) + (quad << 3)];

    f32x4 O00 = {0.f,0.f,0.f,0.f}, O01 = {0.f,0.f,0.f,0.f};   // qt0: dt0, dt1
    f32x4 O10 = {0.f,0.f,0.f,0.f}, O11 = {0.f,0.f,0.f,0.f};   // qt1: dt0, dt1
    float rs0 = 0.f, rs1 = 0.f;

    const int krow = tid >> 2, dg = (tid & 3) << 3;
    const int vrow = tid >> 3, kg = (tid & 7) << 3;
    const short* kbase = Ks + ((size_t)(b << 11) + krow) * 128 + (h << 5) + dg;
    const short* vbase = Vtg + ((size_t)((b << 2) + h) * 32 + vrow) * L_SEQ + kg;

    // stage chunk 0
    bf16x8 kreg = *(const bf16x8*)kbase;
    bf16x8 vreg = *(const bf16x8*)vbase;
    *(bf16x8*)&Klds[0][krow][dg] = kreg;
    *(bf16x8*)&Vlds[0][vrow][kg] = vreg;
    __syncthreads();

    for (int kc = 0; kc < 32; ++kc) {
        const int cur = kc & 1;
        if (kc < 31) {  // prefetch next chunk into registers (coalesced bulk)
            kreg = *(const bf16x8*)(kbase + (size_t)((kc + 1) << 6) * 128);
            vreg = *(const bf16x8*)(vbase + ((kc + 1) << 6));
        }

        // ---- swapped QK^T: each kf read feeds both q-tiles ----
#pragma unroll
        for (int kt = 0; kt < 4; ++kt) {
            bf16x8 kf = *(const bf16x8*)&Klds[cur][(kt << 4) + m][quad << 3];
            f32x4 S0 = __builtin_amdgcn_mfma_f32_16x16x32_bf16(
                kf, qfA, (f32x4){0.f, 0.f, 0.f, 0.f}, 0, 0, 0);
            f32x4 S1 = __builtin_amdgcn_mfma_f32_16x16x32_bf16(
                kf, qfB, (f32x4){0.f, 0.f, 0.f, 0.f}, 0, 0, 0);
            float a0 = __builtin_amdgcn_exp2f(S0[0]);
            float a1 = __builtin_amdgcn_exp2f(S0[1]);
            float a2 = __builtin_amdgcn_exp2f(S0[2]);
            float a3 = __builtin_amdgcn_exp2f(S0[3]);
            rs0 += a0 + a1 + a2 + a3;
            uint2 pkA;
            pkA.x = cvt_pk_bf16(a0, a1);
            pkA.y = cvt_pk_bf16(a2, a3);
            *(uint2*)&Plds[wave][m][(kt << 4) + (quad << 2)] = pkA;
            float b0 = __builtin_amdgcn_exp2f(S1[0]);
            float b1 = __builtin_amdgcn_exp2f(S1[1]);
            float b2 = __builtin_amdgcn_exp2f(S1[2]);
            float b3 = __builtin_amdgcn_exp2f(S1[3]);
            rs1 += b0 + b1 + b2 + b3;
            uint2 pkB;
            pkB.x = cvt_pk_bf16(b0, b1);
            pkB.y = cvt_pk_bf16(b2, b3);
            *(uint2*)&Plds[wave][16 + m][(kt << 4) + (quad << 2)] = pkB;
        }

        // ---- PV: each vf read feeds both q-tiles ----
#pragma unroll
        for (int kt2 = 0; kt2 < 2; ++kt2) {
            short4v aLo = *(const short4v*)&Plds[wave][m][(kt2 << 5) + (quad << 3)];
            short4v aHi = *(const short4v*)&Plds[wave][m][(kt2 << 5) + (quad << 3) + 4];
            bf16x8 pfA = {aLo[0], aLo[1], aLo[2], aLo[3],
                          aHi[0], aHi[1], aHi[2], aHi[3]};
            short4v bLo = *(const short4v*)&Plds[wave][16 + m][(kt2 << 5) + (quad << 3)];
            short4v bHi = *(const short4v*)&Plds[wave][16 + m][(kt2 << 5) + (quad << 3) + 4];
            bf16x8 pfB = {bLo[0], bLo[1], bLo[2], bLo[3],
                          bHi[0], bHi[1], bHi[2], bHi[3]};
            bf16x8 vf0 = *(const bf16x8*)&Vlds[cur][m][(kt2 << 5) + (quad << 3)];
            bf16x8 vf1 = *(const bf16x8*)&Vlds[cur][16 + m][(kt2 << 5) + (quad << 3)];
            O00 = __builtin_amdgcn_mfma_f32_16x16x32_bf16(pfA, vf0, O00, 0, 0, 0);
            O01 = __builtin_amdgcn_mfma_f32_16x16x32_bf16(pfA, vf1, O01, 0, 0, 0);
            O10 = __builtin_amdgcn_mfma_f32_16x16x32_bf16(pfB, vf0, O10, 0, 0, 0);
            O11 = __builtin_amdgcn_mfma_f32_16x16x32_bf16(pfB, vf1, O11, 0, 0, 0);
        }

        // ---- write next K/V buffer; single barrier per chunk ----
        if (kc < 31) {
            *(bf16x8*)&Klds[cur ^ 1][krow][dg] = kreg;
            *(bf16x8*)&Vlds[cur ^ 1][vrow][kg] = vreg;
        }
        __syncthreads();
    }

    // rs per lane = sum over its quad-slice of k for q = m; finish across quads
    rs0 += __shfl_xor(rs0, 16);
    rs0 += __shfl_xor(rs0, 32);
    rs1 += __shfl_xor(rs1, 16);
    rs1 += __shfl_xor(rs1, 32);

#pragma unroll
    for (int r = 0; r < 4; ++r) {
        float svA = __shfl(rs0, (quad << 2) + r);   // rs(q=quad*4+r) lives at lane q
        float svB = __shfl(rs1, (quad << 2) + r);
        float invA = 1.f / svA;
        float invB = 1.f / svB;
        int rowA = (b << 11) + q0 + (wave << 5) + (quad << 2) + r;
        short* opA = outb + (size_t)rowA * D_MODEL + (h << 5) + m;
        opA[0]  = f2bf(O00[r] * invA);
        opA[16] = f2bf(O01[r] * invA);
        short* opB = opA + (size_t)16 * D_MODEL;
        opB[0]  = f2bf(O10[r] * invB);
        opB[16] = f2bf(O11[r] * invB);
    }
}

// ---------------------------------------------------------------------------
// Fused pool + head (R12): one 1024-thread block per batch element.
// ---------------------------------------------------------------------------
__global__ __launch_bounds__(1024) void pool_head_kernel(
    const float* __restrict__ h,
    const float* __restrict__ hlnw, const float* __restrict__ hlnb,
    const float* __restrict__ h1w, const float* __restrict__ h1b,
    const float* __restrict__ h2w, const float* __restrict__ h2b,
    float* __restrict__ out)
{
    __shared__ float part[8][128];
    __shared__ float sd[128];
    __shared__ float sq[128];

    int b   = blockIdx.x;
    int t   = threadIdx.x;
    int d   = t & 127;
    int seg = t >> 7;    // 0..7
    const float* hb = h + (size_t)b * L_SEQ * D_MODEL;

    // ---- phase 1: pool ----
    float acc = 0.f;
    int l0 = seg << 8;
    for (int l = l0; l < l0 + 256; l += 4) {
        acc += hb[(l + 0) * D_MODEL + d] + hb[(l + 1) * D_MODEL + d]
             + hb[(l + 2) * D_MODEL + d] + hb[(l + 3) * D_MODEL + d];
    }
    part[seg][d] = acc;
    __syncthreads();

    // ---- phase 2: head (threads 0..127 compute; all hit barriers) ----
    float v = 0.f;
    if (t < 128) {
        float s = 0.f;
#pragma unroll
        for (int i = 0; i < 8; ++i) s += part[i][t];
        v = 0.5f * hb[(L_SEQ - 1) * D_MODEL + t] + 0.5f * (s * (1.f / (float)L_SEQ));
        sd[t] = v;
    }
    __syncthreads();
    for (int s = 64; s > 0; s >>= 1) {
        if (t < s) sd[t] += sd[t + s];
        __syncthreads();
    }
    float mu = sd[0] * (1.f / 128.f);
    __syncthreads();
    float dv = v - mu;
    if (t < 128) sd[t] = dv * dv;
    __syncthreads();
    for (int s = 64; s > 0; s >>= 1) {
        if (t < s) sd[t] += sd[t + s];
        __syncthreads();
    }
    float var = sd[0] * (1.f / 128.f);
    __syncthreads();
    if (t < 128) sq[t] = dv * rsqrtf(var + 1e-5f) * hlnw[t] + hlnb[t];
    __syncthreads();
    if (t < 128) {
        float dot = h1b[t];
        for (int d2 = 0; d2 < 128; ++d2) dot = fmaf(sq[d2], h1w[t * 128 + d2], dot);
        float ge = 0.5f * dot * (1.f + erff(dot * 0.7071067811865475f));
        sd[t] = ge * h2w[t];
    }
    __syncthreads();
    for (int s = 64; s > 0; s >>= 1) {
        if (t < s) sd[t] += sd[t + s];
        __syncthreads();
    }
    if (t == 0) out[b] = sd[0] + h2b[0];
}

// ---------------------------------------------------------------------------
extern "C" void kernel_launch(void* const* d_in, const int* in_sizes, int n_in,
                              void* d_out, int out_size, void* d_ws, size_t ws_size,
                              hipStream_t stream)
{
    (void)in_sizes; (void)n_in; (void)out_size; (void)ws_size;
    const float* x      = (const float*)d_in[0];
    const float* in_w   = (const float*)d_in[1];
    const float* in_b   = (const float*)d_in[2];
    const float* ssm_nw = (const float*)d_in[3];
    const float* ssm_nb = (const float*)d_in[4];
    const float* ssm_A  = (const float*)d_in[5];
    const float* ssm_iw = (const float*)d_in[6];
    const float* ssm_ib = (const float*)d_in[7];
    const float* ssm_ow = (const float*)d_in[8];
    const float* ssm_ob = (const float*)d_in[9];
    const float* ln1w   = (const float*)d_in[10];
    const float* ln1b   = (const float*)d_in[11];
    const float* ln2w   = (const float*)d_in[12];
    const float* ln2b   = (const float*)d_in[13];
    const float* qkvw   = (const float*)d_in[14];
    const float* qkvb   = (const float*)d_in[15];
    const float* aow    = (const float*)d_in[16];
    const float* aob    = (const float*)d_in[17];
    const float* f1w    = (const float*)d_in[18];
    const float* f1b    = (const float*)d_in[19];
    const float* f2w    = (const float*)d_in[20];
    const float* f2b    = (const float*)d_in[21];
    const float* hlnw   = (const float*)d_in[22];
    const float* hlnb   = (const float*)d_in[23];
    const float* h1w    = (const float*)d_in[24];
    const float* h1b    = (const float*)d_in[25];
    const float* h2w    = (const float*)d_in[26];
    const float* h2b    = (const float*)d_in[27];
    float* out = (float*)d_out;

    char* wsb = (char*)d_ws;
    float* bh     = (float*)(wsb);               // [N,128] fp32 residual stream (8 MB)
    short* abuf   = (short*)(wsb + 8388608);     // [N,512] bf16 wide scratch / scan pt (16 MB)
    short* bbuf   = (short*)(wsb + 25165824);    // [N,128] bf16 ln/hs/attn-out (4 MB)
    short* qs     = (short*)(wsb + 29360128);    // [N,128] bf16 Q prescaled; ks = +2097152
    short* vt     = (short*)(wsb + 37748736);    // [B,4,32,2048] bf16 V^T (4 MB)
    short* xb     = (short*)(wsb + 41943040);    // [N,64] bf16 input (2 MB)
    short* wb     = (short*)(wsb + 44040192);    // bf16 weights (~1 MB)
    short* ks     = qs + 2097152;

    dim3 blk(256);

    convert_kernel<<<756, blk, 0, stream>>>(x, in_w, ssm_iw, ssm_ow, qkvw, aow, f1w, f2w, xb, wb);

    // input projection + PE + LN(ssm_norm0): writes bh (fp32) and bbuf (bf16 LN)
    gemm_ln<0><<<512, blk, 0, stream>>>(
        xb, wb, in_b, ssm_nw, ssm_nb, bh, bbuf, 64);

    // SSM block 0
    gemm_bf<EPI_SCAN_T><<<dim3(4, 256), blk, 0, stream>>>(
        bbuf, wb + 8192, ssm_ib, abuf, nullptr, 128, 256);
    scan_kernel<<<256, 64, 0, stream>>>(abuf, ssm_A, bbuf);
    gemm_ln<1><<<512, blk, 0, stream>>>(                       // +res, LN(ssm_norm1)
        bbuf, wb + 73728, ssm_ob, ssm_nw + 128, ssm_nb + 128, bh, bbuf, 128);

    // SSM block 1
    gemm_bf<EPI_SCAN_T><<<dim3(4, 256), blk, 0, stream>>>(
        bbuf, wb + 8192 + 32768, ssm_ib + 256, abuf, nullptr, 128, 256);
    scan_kernel<<<256, 64, 0, stream>>>(abuf, ssm_A + 128, bbuf);
    gemm_ln<1><<<512, blk, 0, stream>>>(                       // +res, LN(ln1[0])
        bbuf, wb + 73728 + 16384, ssm_ob + 128, ln1w, ln1b, bh, bbuf, 128);

    // Encoder layer 0
    gemm_bf<EPI_QKV><<<dim3(6, 256), blk, 0, stream>>>(
        bbuf, wb + 106496, qkvb, qs, vt, 128, 384);
    attn_kernel<<<512, blk, 0, stream>>>(qs, ks, vt, bbuf);
    gemm_ln<1><<<512, blk, 0, stream>>>(                       // +res, LN(ln2[0])
        bbuf, wb + 204800, aob, ln2w, ln2b, bh, bbuf, 128);
    gemm_bf<EPI_BF_RELU><<<dim3(8, 256), blk, 0, stream>>>(
        bbuf, wb + 237568, f1b, abuf, nullptr, 128, 512);
    gemm_ln<1><<<512, blk, 0, stream>>>(                       // ff2[0] +res, LN(ln1[1])
        abuf, wb + 368640, f2b, ln1w + 128, ln1b + 128, bh, bbuf, 512);

    // Encoder layer 1
    gemm_bf<EPI_QKV><<<dim3(6, 256), blk, 0, stream>>>(
        bbuf, wb + 106496 + 49152, qkvb + 384, qs, vt, 128, 384);
    attn_kernel<<<512, blk, 0, stream>>>(qs, ks, vt, bbuf);
    gemm_ln<1><<<512, blk, 0, stream>>>(                       // +res, LN(ln2[1])
        bbuf, wb + 204800 + 16384, aob + 128, ln2w + 128, ln2b + 128, bh, bbuf, 128);
    gemm_bf<EPI_BF_RELU><<<dim3(8, 256), blk, 0, stream>>>(
        bbuf, wb + 237568 + 65536, f1b + 512, abuf, nullptr, 128, 512);
    gemm_ln<2><<<512, blk, 0, stream>>>(                       // ff2[1] +res only
        abuf, wb + 368640 + 65536, f2b + 128, nullptr, nullptr, bh, nullptr, 512);

    pool_head_kernel<<<8, 1024, 0, stream>>>(bh, hlnw, hlnb, h1w, h1b, h2w, h2b, out);
}

// Round 8
// 343.057 us; speedup vs baseline: 1.4689x; 1.0009x over previous
//
#include <hip/hip_runtime.h>
#include <hip/hip_bf16.h>
#include <math.h>

#define L_SEQ 2048
#define D_MODEL 128
#define N_ROWS 16384  // B*L = 8*2048
#define LOG2E 1.4426950408889634f

typedef __attribute__((ext_vector_type(8))) short bf16x8;
typedef __attribute__((ext_vector_type(4))) short short4v;
typedef __attribute__((ext_vector_type(4))) float f32x4;

__device__ __forceinline__ short f2bf(float x)  // RNE
{
    __hip_bfloat16 b = __float2bfloat16(x);
    return *reinterpret_cast<short*>(&b);
}
__device__ __forceinline__ short f2bf_fast(float x)  // round-half-up, x >= 0
{
    unsigned u = __builtin_bit_cast(unsigned, x);
    return (short)((u + 0x8000u) >> 16);
}
__device__ __forceinline__ unsigned cvt_pk_bf16(float lo, float hi)  // 2xbf16 in 1 instr
{
    unsigned r;
    asm("v_cvt_pk_bf16_f32 %0, %1, %2" : "=v"(r) : "v"(lo), "v"(hi));
    return r;
}
__device__ __forceinline__ float bf2f(short s)
{
    unsigned u = ((unsigned)(unsigned short)s) << 16;
    return __builtin_bit_cast(float, u);
}
__device__ __forceinline__ short f2h(float x)   // v_cvt_f16_f32
{
    _Float16 h = (_Float16)x;
    return (short)__builtin_bit_cast(unsigned short, h);
}
__device__ __forceinline__ float h2f(short s)   // v_cvt_f32_f16
{
    _Float16 h = __builtin_bit_cast(_Float16, (unsigned short)s);
    return (float)h;
}

// ---------------------------------------------------------------------------
// One-shot fp32 -> bf16 conversion of x and all weight matrices.
// ---------------------------------------------------------------------------
__global__ __launch_bounds__(256) void convert_kernel(
    const float* __restrict__ x,    const float* __restrict__ inw,
    const float* __restrict__ ssmi, const float* __restrict__ ssmo,
    const float* __restrict__ qkvw, const float* __restrict__ aow,
    const float* __restrict__ f1w,  const float* __restrict__ f2w,
    short* __restrict__ xb, short* __restrict__ wb)
{
    int it = blockIdx.x * 256 + threadIdx.x;
    const float* src; short* dst; int off;
    if      (it < 131072) { src = x;    dst = xb;          off = it; }
    else if (it < 132096) { src = inw;  dst = wb;          off = it - 131072; }
    else if (it < 140288) { src = ssmi; dst = wb + 8192;   off = it - 132096; }
    else if (it < 144384) { src = ssmo; dst = wb + 73728;  off = it - 140288; }
    else if (it < 156672) { src = qkvw; dst = wb + 106496; off = it - 144384; }
    else if (it < 160768) { src = aow;  dst = wb + 204800; off = it - 156672; }
    else if (it < 177152) { src = f1w;  dst = wb + 237568; off = it - 160768; }
    else                  { src = f2w;  dst = wb + 368640; off = it - 177152; }
    off <<= 3;
    float4 v0 = *(const float4*)(src + off);
    float4 v1 = *(const float4*)(src + off + 4);
    bf16x8 p = {f2bf(v0.x), f2bf(v0.y), f2bf(v0.z), f2bf(v0.w),
                f2bf(v1.x), f2bf(v1.y), f2bf(v1.z), f2bf(v1.w)};
    *(bf16x8*)(dst + off) = p;
}

// ---------------------------------------------------------------------------
// Fused E=128 GEMM + residual + LayerNorm (R16 occupancy rework, validated R5).
// 32-row x 128-col blocks, grid 512 -> 2 blocks/CU. 4 waves = rh x ch; LN via
// one-pass sum/sumsq partials + 256B LDS cross-wave combine.
// FUSE: 0 = PE+LN, 1 = RES+LN, 2 = RES only (last ff2).
// ---------------------------------------------------------------------------
template <int FUSE>
__global__ __launch_bounds__(256) void gemm_ln(const short* __restrict__ A,
                                               const short* __restrict__ W,
                                               const float* __restrict__ bias,
                                               const float* __restrict__ lnw,
                                               const float* __restrict__ lnb,
                                               float* __restrict__ bh,
                                               short* __restrict__ lnout,
                                               int K)
{
    __shared__ __align__(16) short As[32][72];
    __shared__ __align__(16) short Bs[128][72];
    __shared__ float2 red[2][32];

    const int tid  = threadIdx.x;
    const int wave = tid >> 6;
    const int lane = tid & 63;
    const int m    = lane & 15;
    const int quad = lane >> 4;
    const int rh   = wave & 1;     // row half (16 rows)
    const int ch   = wave >> 1;    // col half (64 cols)
    const int n0   = blockIdx.x * 32;

    const int arow = tid >> 3, acol = (tid & 7) << 3;
    const int brow = tid >> 1, bcol = (tid & 1) << 5;

    const short* Ap = A + (size_t)(n0 + arow) * K + acol;
    const short* Wp = W + (size_t)brow * K + bcol;

    f32x4 acc[4];
#pragma unroll
    for (int i = 0; i < 4; ++i) acc[i] = (f32x4){0.f, 0.f, 0.f, 0.f};

    bf16x8 a0 = *(const bf16x8*)Ap;
    bf16x8 b0 = *(const bf16x8*)Wp;
    bf16x8 b1 = *(const bf16x8*)(Wp + 8);
    bf16x8 b2 = *(const bf16x8*)(Wp + 16);
    bf16x8 b3 = *(const bf16x8*)(Wp + 24);

    for (int k0 = 0; k0 < K; k0 += 64) {
        *(bf16x8*)&As[arow][acol]      = a0;
        *(bf16x8*)&Bs[brow][bcol]      = b0;
        *(bf16x8*)&Bs[brow][bcol + 8]  = b1;
        *(bf16x8*)&Bs[brow][bcol + 16] = b2;
        *(bf16x8*)&Bs[brow][bcol + 24] = b3;
        __syncthreads();
        if (k0 + 64 < K) {
            a0 = *(const bf16x8*)(Ap + k0 + 64);
            b0 = *(const bf16x8*)(Wp + k0 + 64);
            b1 = *(const bf16x8*)(Wp + k0 + 72);
            b2 = *(const bf16x8*)(Wp + k0 + 80);
            b3 = *(const bf16x8*)(Wp + k0 + 88);
        }
#pragma unroll
        for (int ks = 0; ks < 2; ++ks) {
            bf16x8 af = *(const bf16x8*)&As[(rh << 4) + m][(ks << 5) + (quad << 3)];
#pragma unroll
            for (int nt = 0; nt < 4; ++nt) {
                bf16x8 bfr = *(const bf16x8*)&Bs[(ch << 6) + (nt << 4) + m][(ks << 5) + (quad << 3)];
                acc[nt] = __builtin_amdgcn_mfma_f32_16x16x32_bf16(af, bfr, acc[nt], 0, 0, 0);
            }
        }
        __syncthreads();
    }

    // ---- epilogue: bias (+PE | +res), write fp32 bh, keep v in registers ----
#pragma unroll
    for (int nt = 0; nt < 4; ++nt) {
        int col = (ch << 6) + (nt << 4) + m;
        float bv = bias[col];
        float fr = 0.f;
        if (FUSE == 0)
            fr = __expf((float)(col & ~1) * (-0.07195578415606394f)); // -ln(1e4)/128
#pragma unroll
        for (int r = 0; r < 4; ++r) {
            int row = n0 + (rh << 4) + (quad << 2) + r;
            float t = acc[nt][r] + bv;
            if (FUSE == 0) {
                float ang = (float)(row & (L_SEQ - 1)) * fr;
                t += (col & 1) ? cosf(ang) : sinf(ang);
            } else {
                t += bh[(size_t)row * 128 + col];
            }
            acc[nt][r] = t;
            bh[(size_t)row * 128 + col] = t;
        }
    }

    if (FUSE < 2) {
        // ---- LN: one-pass sum/sumsq; 64-col partials cross-wave via LDS ----
        float wv[4], bvn[4];
#pragma unroll
        for (int nt = 0; nt < 4; ++nt) {
            wv[nt]  = lnw[(ch << 6) + (nt << 4) + m];
            bvn[nt] = lnb[(ch << 6) + (nt << 4) + m];
        }
        float s1[4], s2[4];
#pragma unroll
        for (int r = 0; r < 4; ++r) {
            float s = 0.f, q = 0.f;
#pragma unroll
            for (int nt = 0; nt < 4; ++nt) {
                float t = acc[nt][r];
                s += t;
                q = fmaf(t, t, q);
            }
            s += __shfl_xor(s, 1);  q += __shfl_xor(q, 1);
            s += __shfl_xor(s, 2);  q += __shfl_xor(q, 2);
            s += __shfl_xor(s, 4);  q += __shfl_xor(q, 4);
            s += __shfl_xor(s, 8);  q += __shfl_xor(q, 8);
            s1[r] = s; s2[r] = q;
            if (m == 0) red[ch][(rh << 4) + (quad << 2) + r] = make_float2(s, q);
        }
        __syncthreads();
#pragma unroll
        for (int r = 0; r < 4; ++r) {
            float2 o = red[ch ^ 1][(rh << 4) + (quad << 2) + r];
            float ts = s1[r] + o.x;
            float tq = s2[r] + o.y;
            float mean = ts * (1.f / 128.f);
            float var  = tq * (1.f / 128.f) - mean * mean;
            float inv  = rsqrtf(var + 1e-5f);
            int row = n0 + (rh << 4) + (quad << 2) + r;
#pragma unroll
            for (int nt = 0; nt < 4; ++nt) {
                int col = (ch << 6) + (nt << 4) + m;
                lnout[(size_t)row * 128 + col] =
                    f2bf((acc[nt][r] - mean) * inv * wv[nt] + bvn[nt]);
            }
        }
    }
}

// ---------------------------------------------------------------------------
// bf16-native MFMA GEMM v2 (R18): single-shot K=128 staging.
// R7 accounting: ~220us is spread over the GEMM family; this kernel's old
// structure ran a 2-iteration double-buffered loop with 4 barrier drains for
// K=128 — the pipeline never filled. All call sites have K=128, so stage the
// WHOLE 64x128 A-tile and W-tile (32KB LDS) once, ONE barrier, then 16
// uninterrupted MFMAs (4 k-steps). Identical FP accumulation order
// (k = 0,32,64,96). LDS 18.4->34.8KB caps 4 blocks/CU (4 waves/SIMD, fine).
// Epilogues unchanged: BF_RELU (ff1), QKV, SCAN_T.
// ---------------------------------------------------------------------------
enum { EPI_BF_RELU = 0, EPI_QKV = 1, EPI_SCAN_T = 2 };

template <int EPI>
__global__ __launch_bounds__(256) void gemm_bf(const short* __restrict__ A,
                                               const short* __restrict__ W,
                                               const float* __restrict__ bias,
                                               short* __restrict__ outb,  // QKV: qs (ks = +2097152); SCAN_T: pt
                                               short* __restrict__ outv,  // QKV: vt
                                               int K, int E)
{
    __shared__ __align__(16) short As[64][136];   // 272B rows: 16B-aligned, pair-stride 34
    __shared__ __align__(16) short Bs[64][136];

    const int tid  = threadIdx.x;
    const int wave = tid >> 6;
    const int lane = tid & 63;
    const int m    = lane & 15;
    const int quad = lane >> 4;

    const int n0 = blockIdx.y * 64;
    const int e0 = blockIdx.x * 64;

    const int srow = tid >> 2;
    const int scol = (tid & 3) << 5;   // 32-short (64B) chunks: 4 per 128-K row

    const short* Ap = A + (size_t)(n0 + srow) * K + scol;
    const short* Wp = W + (size_t)(e0 + srow) * K + scol;

    // ---- single-shot staging: whole K=128 tile, one barrier ----
    bf16x8 a0 = *(const bf16x8*)(Ap);
    bf16x8 a1 = *(const bf16x8*)(Ap + 8);
    bf16x8 a2 = *(const bf16x8*)(Ap + 16);
    bf16x8 a3 = *(const bf16x8*)(Ap + 24);
    bf16x8 w0 = *(const bf16x8*)(Wp);
    bf16x8 w1 = *(const bf16x8*)(Wp + 8);
    bf16x8 w2 = *(const bf16x8*)(Wp + 16);
    bf16x8 w3 = *(const bf16x8*)(Wp + 24);
    *(bf16x8*)&As[srow][scol]      = a0;
    *(bf16x8*)&As[srow][scol + 8]  = a1;
    *(bf16x8*)&As[srow][scol + 16] = a2;
    *(bf16x8*)&As[srow][scol + 24] = a3;
    *(bf16x8*)&Bs[srow][scol]      = w0;
    *(bf16x8*)&Bs[srow][scol + 8]  = w1;
    *(bf16x8*)&Bs[srow][scol + 16] = w2;
    *(bf16x8*)&Bs[srow][scol + 24] = w3;
    __syncthreads();

    f32x4 acc[4];
#pragma unroll
    for (int i = 0; i < 4; ++i) acc[i] = (f32x4){0.f, 0.f, 0.f, 0.f};

#pragma unroll
    for (int ks = 0; ks < 4; ++ks) {
        bf16x8 af = *(const bf16x8*)&As[(wave << 4) + m][(ks << 5) + (quad << 3)];
#pragma unroll
        for (int nt = 0; nt < 4; ++nt) {
            bf16x8 bfr = *(const bf16x8*)&Bs[(nt << 4) + m][(ks << 5) + (quad << 3)];
            acc[nt] = __builtin_amdgcn_mfma_f32_16x16x32_bf16(af, bfr, acc[nt], 0, 0, 0);
        }
    }

    if (EPI == EPI_QKV) {
        const float QSC = 0.17677669529663687f * LOG2E;  // 1/sqrt(32) * log2e
        if (e0 < 256) {
            short* dst = (e0 < 128) ? outb : (outb + 2097152);
            int cbase = (e0 < 128) ? e0 : (e0 - 128);
#pragma unroll
            for (int nt = 0; nt < 4; ++nt) {
                int col = cbase + (nt << 4) + m;
                float bv = bias[e0 + (nt << 4) + m];
#pragma unroll
                for (int r = 0; r < 4; ++r) {
                    int row = n0 + (wave << 4) + (quad << 2) + r;
                    float v = acc[nt][r] + bv;
                    if (e0 < 128) v *= QSC;
                    dst[(size_t)row * 128 + col] = f2bf(v);
                }
            }
        } else {
            int bb_ = n0 >> 11;
            int l0  = (n0 & (L_SEQ - 1)) + (wave << 4) + (quad << 2);
#pragma unroll
            for (int nt = 0; nt < 4; ++nt) {
                int c  = (e0 - 256) + (nt << 4) + m;
                int hh = c >> 5, dd = c & 31;
                float bv = bias[e0 + (nt << 4) + m];
                short4v pk;
#pragma unroll
                for (int r = 0; r < 4; ++r) pk[r] = f2bf(acc[nt][r] + bv);
                *(short4v*)&outv[(size_t)((bb_ * 4 + hh) * 32 + dd) * L_SEQ + l0] = pk;
            }
        }
    } else if (EPI == EPI_SCAN_T) {
        // transposed write pt[b][e][l] (fp16): u2 for e<128, sigmoid(g) for e>=128
        int bb_ = n0 >> 11;
        int l0  = (n0 & (L_SEQ - 1)) + (wave << 4) + (quad << 2);
#pragma unroll
        for (int nt = 0; nt < 4; ++nt) {
            int col = e0 + (nt << 4) + m;
            float bv = bias[col];
            short4v pk;
            if (e0 < 128) {
#pragma unroll
                for (int r = 0; r < 4; ++r)
                    pk[r] = f2h((acc[nt][r] + bv) * (2.f * LOG2E));
            } else {
#pragma unroll
                for (int r = 0; r < 4; ++r) {
                    float gr = acc[nt][r] + bv;
                    float g = __builtin_amdgcn_rcpf(
                        1.f + __builtin_amdgcn_exp2f(-gr * LOG2E));
                    pk[r] = f2h(g);
                }
            }
            *(short4v*)&outb[(((size_t)(bb_ * 256 + col)) << 11) + l0] = pk;
        }
    } else {  // EPI_BF_RELU
#pragma unroll
        for (int nt = 0; nt < 4; ++nt) {
            int col = e0 + (nt << 4) + m;
            float bv = bias[col];
#pragma unroll
            for (int r = 0; r < 4; ++r) {
                int row = n0 + (wave << 4) + (quad << 2) + r;
                float v = fmaxf(acc[nt][r] + bv, 0.f);
                outb[(size_t)row * E + col] = f2bf(v);
            }
        }
    }
}

// ---------------------------------------------------------------------------
// SSM gated scan — R13 chunked-parallel version (validated R1: 68 -> ~10 us).
// Recurrence is contractive; 16 chunks of 128 steps each with 128-step
// burn-in from h=0. Sequential depth 2048 -> 256.
// ---------------------------------------------------------------------------
#define SCAN_WARM 128   // burn-in steps (contraction margin)

__device__ __forceinline__ void scan8(float& h, bf16x8 u8, bf16x8 g8,
                                      float a2, short* __restrict__ ob, int l0)
{
#pragma unroll
    for (int i = 0; i < 8; ++i) {
        float u2 = h2f(u8[i]);
        float g  = h2f(g8[i]);
        float omg = 1.f - g;
        float m2  = -2.f * omg;
        float c0 = fmaf(g, h, omg);                          // parallel to exp path
        float e2 = __builtin_amdgcn_exp2f(fmaf(a2, h, u2));  // exp(2x)
        float r  = __builtin_amdgcn_rcpf(1.f + e2);
        h = fmaf(m2, r, c0);
        ob[(l0 + i) * D_MODEL] = f2bf(h);
    }
}

__device__ __forceinline__ void scan8_ns(float& h, bf16x8 u8, bf16x8 g8,
                                         float a2)
{
#pragma unroll
    for (int i = 0; i < 8; ++i) {
        float u2 = h2f(u8[i]);
        float g  = h2f(g8[i]);
        float omg = 1.f - g;
        float m2  = -2.f * omg;
        float c0 = fmaf(g, h, omg);
        float e2 = __builtin_amdgcn_exp2f(fmaf(a2, h, u2));
        float r  = __builtin_amdgcn_rcpf(1.f + e2);
        h = fmaf(m2, r, c0);
    }
}

__global__ __launch_bounds__(64) void scan_kernel(const short* __restrict__ pt,
                                                  const float* __restrict__ A,
                                                  short* __restrict__ hs)
{
    int blk = blockIdx.x;             // 256 blocks = 16 (b,dhalf) x 16 chunks
    int c   = blk & 15;               // chunk index: writes l in [c*128, c*128+128)
    int bd  = blk >> 4;
    int b   = bd >> 1;
    int d   = ((bd & 1) << 6) + threadIdx.x;
    float a2 = 2.f * A[d] * LOG2E;
    const short* up = pt + (((size_t)(b * 256 + d)) << 11);
    const short* gp = up + (((size_t)128) << 11);
    short* ob = hs + ((size_t)(b << 11)) * D_MODEL + d;

    const int lw = c << 7;            // first stored step
    float h = 0.f;

    bf16x8 uA0, uA1, gA0, gA1;

    if (c > 0) {
        // ---- burn-in: SCAN_WARM steps ending at lw, no stores ----
        int l0 = lw - SCAN_WARM;
        uA0 = *(const bf16x8*)(up + l0);
        uA1 = *(const bf16x8*)(up + l0 + 8);
        gA0 = *(const bf16x8*)(gp + l0);
        gA1 = *(const bf16x8*)(gp + l0 + 8);
        for (int l = l0; l < lw; l += 32) {
            bf16x8 uB0 = *(const bf16x8*)(up + l + 16);
            bf16x8 uB1 = *(const bf16x8*)(up + l + 24);
            bf16x8 gB0 = *(const bf16x8*)(gp + l + 16);
            bf16x8 gB1 = *(const bf16x8*)(gp + l + 24);
            scan8_ns(h, uA0, gA0, a2);
            scan8_ns(h, uA1, gA1, a2);
            uA0 = *(const bf16x8*)(up + l + 32);
            uA1 = *(const bf16x8*)(up + l + 40);
            gA0 = *(const bf16x8*)(gp + l + 32);
            gA1 = *(const bf16x8*)(gp + l + 40);
            scan8_ns(h, uB0, gB0, a2);
            scan8_ns(h, uB1, gB1, a2);
        }
    } else {
        uA0 = *(const bf16x8*)(up);
        uA1 = *(const bf16x8*)(up + 8);
        gA0 = *(const bf16x8*)(gp);
        gA1 = *(const bf16x8*)(gp + 8);
    }

    // ---- live phase: 128 steps with stores ----
    for (int l = lw; l < lw + 128; l += 32) {
        bf16x8 uB0 = *(const bf16x8*)(up + l + 16);
        bf16x8 uB1 = *(const bf16x8*)(up + l + 24);
        bf16x8 gB0 = *(const bf16x8*)(gp + l + 16);
        bf16x8 gB1 = *(const bf16x8*)(gp + l + 24);
        scan8(h, uA0, gA0, a2, ob, l);
        scan8(h, uA1, gA1, a2, ob, l + 8);
        if (l + 32 < lw + 128) {      // guard: l+32 would be OOB at chunk end
            uA0 = *(const bf16x8*)(up + l + 32);
            uA1 = *(const bf16x8*)(up + l + 40);
            gA0 = *(const bf16x8*)(gp + l + 32);
            gA1 = *(const bf16x8*)(gp + l + 40);
        }
        scan8(h, uB0, gB0, a2, ob, l + 16);
        scan8(h, uB1, gB1, a2, ob, l + 24);
    }
}

// ---------------------------------------------------------------------------
// Flash attention v7 (R17, validated R7): 2 q-tiles per wave, 128 q-rows per
// block, grid 512, XCD swizzle. LDS traffic per work -36% vs v6; TLP 2/SIMD.
// ---------------------------------------------------------------------------
__global__ __launch_bounds__(256) void attn_kernel(const short* __restrict__ Qs,
                                                   const short* __restrict__ Ks,
                                                   const short* __restrict__ Vtg,
                                                   short* __restrict__ outb)
{
    __shared__ __align__(16) short Klds[2][64][40];
    __shared__ __align__(16) short Vlds[2][32][72];
    __shared__ __align__(16) short Plds[4][32][68];   // [wave][qt*16+m][k] 34-dw rows

    const int tid  = threadIdx.x;
    const int wave = tid >> 6;
    const int lane = tid & 63;
    const int m    = lane & 15;
    const int quad = lane >> 4;

    // XCD-aware swizzle for grid 512: XCD x gets logical [x*64, x*64+64)
    // = all 64 blocks of batch element x (1MB KV in its L2).
    const int raw = blockIdx.x;
    const int bid = (raw & 7) * 64 + (raw >> 3);
    const int b  = bid >> 6;
    const int h  = (bid >> 4) & 3;
    const int q0 = (bid & 15) << 7;       // 128 q-rows per block

    const size_t qrow = (size_t)((b << 11) + q0 + (wave << 5) + m);
    bf16x8 qfA = *(const bf16x8*)&Qs[qrow * 128 + (h << 5) + (quad << 3)];
    bf16x8 qfB = *(const bf16x8*)&Qs[(qrow + 16) * 128 + (h << 5) + (quad << 3)];

    f32x4 O00 = {0.f,0.f,0.f,0.f}, O01 = {0.f,0.f,0.f,0.f};   // qt0: dt0, dt1
    f32x4 O10 = {0.f,0.f,0.f,0.f}, O11 = {0.f,0.f,0.f,0.f};   // qt1: dt0, dt1
    float rs0 = 0.f, rs1 = 0.f;

    const int krow = tid >> 2, dg = (tid & 3) << 3;
    const int vrow = tid >> 3, kg = (tid & 7) << 3;
    const short* kbase = Ks + ((size_t)(b << 11) + krow) * 128 + (h << 5) + dg;
    const short* vbase = Vtg + ((size_t)((b << 2) + h) * 32 + vrow) * L_SEQ + kg;

    // stage chunk 0
    bf16x8 kreg = *(const bf16x8*)kbase;
    bf16x8 vreg = *(const bf16x8*)vbase;
    *(bf16x8*)&Klds[0][krow][dg] = kreg;
    *(bf16x8*)&Vlds[0][vrow][kg] = vreg;
    __syncthreads();

    for (int kc = 0; kc < 32; ++kc) {
        const int cur = kc & 1;
        if (kc < 31) {  // prefetch next chunk into registers (coalesced bulk)
            kreg = *(const bf16x8*)(kbase + (size_t)((kc + 1) << 6) * 128);
            vreg = *(const bf16x8*)(vbase + ((kc + 1) << 6));
        }

        // ---- swapped QK^T: each kf read feeds both q-tiles ----
#pragma unroll
        for (int kt = 0; kt < 4; ++kt) {
            bf16x8 kf = *(const bf16x8*)&Klds[cur][(kt << 4) + m][quad << 3];
            f32x4 S0 = __builtin_amdgcn_mfma_f32_16x16x32_bf16(
                kf, qfA, (f32x4){0.f, 0.f, 0.f, 0.f}, 0, 0, 0);
            f32x4 S1 = __builtin_amdgcn_mfma_f32_16x16x32_bf16(
                kf, qfB, (f32x4){0.f, 0.f, 0.f, 0.f}, 0, 0, 0);
            float a0 = __builtin_amdgcn_exp2f(S0[0]);
            float a1 = __builtin_amdgcn_exp2f(S0[1]);
            float a2 = __builtin_amdgcn_exp2f(S0[2]);
            float a3 = __builtin_amdgcn_exp2f(S0[3]);
            rs0 += a0 + a1 + a2 + a3;
            uint2 pkA;
            pkA.x = cvt_pk_bf16(a0, a1);
            pkA.y = cvt_pk_bf16(a2, a3);
            *(uint2*)&Plds[wave][m][(kt << 4) + (quad << 2)] = pkA;
            float b0 = __builtin_amdgcn_exp2f(S1[0]);
            float b1 = __builtin_amdgcn_exp2f(S1[1]);
            float b2 = __builtin_amdgcn_exp2f(S1[2]);
            float b3 = __builtin_amdgcn_exp2f(S1[3]);
            rs1 += b0 + b1 + b2 + b3;
            uint2 pkB;
            pkB.x = cvt_pk_bf16(b0, b1);
            pkB.y = cvt_pk_bf16(b2, b3);
            *(uint2*)&Plds[wave][16 + m][(kt << 4) + (quad << 2)] = pkB;
        }

        // ---- PV: each vf read feeds both q-tiles ----
#pragma unroll
        for (int kt2 = 0; kt2 < 2; ++kt2) {
            short4v aLo = *(const short4v*)&Plds[wave][m][(kt2 << 5) + (quad << 3)];
            short4v aHi = *(const short4v*)&Plds[wave][m][(kt2 << 5) + (quad << 3) + 4];
            bf16x8 pfA = {aLo[0], aLo[1], aLo[2], aLo[3],
                          aHi[0], aHi[1], aHi[2], aHi[3]};
            short4v bLo = *(const short4v*)&Plds[wave][16 + m][(kt2 << 5) + (quad << 3)];
            short4v bHi = *(const short4v*)&Plds[wave][16 + m][(kt2 << 5) + (quad << 3) + 4];
            bf16x8 pfB = {bLo[0], bLo[1], bLo[2], bLo[3],
                          bHi[0], bHi[1], bHi[2], bHi[3]};
            bf16x8 vf0 = *(const bf16x8*)&Vlds[cur][m][(kt2 << 5) + (quad << 3)];
            bf16x8 vf1 = *(const bf16x8*)&Vlds[cur][16 + m][(kt2 << 5) + (quad << 3)];
            O00 = __builtin_amdgcn_mfma_f32_16x16x32_bf16(pfA, vf0, O00, 0, 0, 0);
            O01 = __builtin_amdgcn_mfma_f32_16x16x32_bf16(pfA, vf1, O01, 0, 0, 0);
            O10 = __builtin_amdgcn_mfma_f32_16x16x32_bf16(pfB, vf0, O10, 0, 0, 0);
            O11 = __builtin_amdgcn_mfma_f32_16x16x32_bf16(pfB, vf1, O11, 0, 0, 0);
        }

        // ---- write next K/V buffer; single barrier per chunk ----
        if (kc < 31) {
            *(bf16x8*)&Klds[cur ^ 1][krow][dg] = kreg;
            *(bf16x8*)&Vlds[cur ^ 1][vrow][kg] = vreg;
        }
        __syncthreads();
    }

    // rs per lane = sum over its quad-slice of k for q = m; finish across quads
    rs0 += __shfl_xor(rs0, 16);
    rs0 += __shfl_xor(rs0, 32);
    rs1 += __shfl_xor(rs1, 16);
    rs1 += __shfl_xor(rs1, 32);

#pragma unroll
    for (int r = 0; r < 4; ++r) {
        float svA = __shfl(rs0, (quad << 2) + r);   // rs(q=quad*4+r) lives at lane q
        float svB = __shfl(rs1, (quad << 2) + r);
        float invA = 1.f / svA;
        float invB = 1.f / svB;
        int rowA = (b << 11) + q0 + (wave << 5) + (quad << 2) + r;
        short* opA = outb + (size_t)rowA * D_MODEL + (h << 5) + m;
        opA[0]  = f2bf(O00[r] * invA);
        opA[16] = f2bf(O01[r] * invA);
        short* opB = opA + (size_t)16 * D_MODEL;
        opB[0]  = f2bf(O10[r] * invB);
        opB[16] = f2bf(O11[r] * invB);
    }
}

// ---------------------------------------------------------------------------
// Fused pool + head (R12): one 1024-thread block per batch element.
// ---------------------------------------------------------------------------
__global__ __launch_bounds__(1024) void pool_head_kernel(
    const float* __restrict__ h,
    const float* __restrict__ hlnw, const float* __restrict__ hlnb,
    const float* __restrict__ h1w, const float* __restrict__ h1b,
    const float* __restrict__ h2w, const float* __restrict__ h2b,
    float* __restrict__ out)
{
    __shared__ float part[8][128];
    __shared__ float sd[128];
    __shared__ float sq[128];

    int b   = blockIdx.x;
    int t   = threadIdx.x;
    int d   = t & 127;
    int seg = t >> 7;    // 0..7
    const float* hb = h + (size_t)b * L_SEQ * D_MODEL;

    // ---- phase 1: pool ----
    float acc = 0.f;
    int l0 = seg << 8;
    for (int l = l0; l < l0 + 256; l += 4) {
        acc += hb[(l + 0) * D_MODEL + d] + hb[(l + 1) * D_MODEL + d]
             + hb[(l + 2) * D_MODEL + d] + hb[(l + 3) * D_MODEL + d];
    }
    part[seg][d] = acc;
    __syncthreads();

    // ---- phase 2: head (threads 0..127 compute; all hit barriers) ----
    float v = 0.f;
    if (t < 128) {
        float s = 0.f;
#pragma unroll
        for (int i = 0; i < 8; ++i) s += part[i][t];
        v = 0.5f * hb[(L_SEQ - 1) * D_MODEL + t] + 0.5f * (s * (1.f / (float)L_SEQ));
        sd[t] = v;
    }
    __syncthreads();
    for (int s = 64; s > 0; s >>= 1) {
        if (t < s) sd[t] += sd[t + s];
        __syncthreads();
    }
    float mu = sd[0] * (1.f / 128.f);
    __syncthreads();
    float dv = v - mu;
    if (t < 128) sd[t] = dv * dv;
    __syncthreads();
    for (int s = 64; s > 0; s >>= 1) {
        if (t < s) sd[t] += sd[t + s];
        __syncthreads();
    }
    float var = sd[0] * (1.f / 128.f);
    __syncthreads();
    if (t < 128) sq[t] = dv * rsqrtf(var + 1e-5f) * hlnw[t] + hlnb[t];
    __syncthreads();
    if (t < 128) {
        float dot = h1b[t];
        for (int d2 = 0; d2 < 128; ++d2) dot = fmaf(sq[d2], h1w[t * 128 + d2], dot);
        float ge = 0.5f * dot * (1.f + erff(dot * 0.7071067811865475f));
        sd[t] = ge * h2w[t];
    }
    __syncthreads();
    for (int s = 64; s > 0; s >>= 1) {
        if (t < s) sd[t] += sd[t + s];
        __syncthreads();
    }
    if (t == 0) out[b] = sd[0] + h2b[0];
}

// ---------------------------------------------------------------------------
extern "C" void kernel_launch(void* const* d_in, const int* in_sizes, int n_in,
                              void* d_out, int out_size, void* d_ws, size_t ws_size,
                              hipStream_t stream)
{
    (void)in_sizes; (void)n_in; (void)out_size; (void)ws_size;
    const float* x      = (const float*)d_in[0];
    const float* in_w   = (const float*)d_in[1];
    const float* in_b   = (const float*)d_in[2];
    const float* ssm_nw = (const float*)d_in[3];
    const float* ssm_nb = (const float*)d_in[4];
    const float* ssm_A  = (const float*)d_in[5];
    const float* ssm_iw = (const float*)d_in[6];
    const float* ssm_ib = (const float*)d_in[7];
    const float* ssm_ow = (const float*)d_in[8];
    const float* ssm_ob = (const float*)d_in[9];
    const float* ln1w   = (const float*)d_in[10];
    const float* ln1b   = (const float*)d_in[11];
    const float* ln2w   = (const float*)d_in[12];
    const float* ln2b   = (const float*)d_in[13];
    const float* qkvw   = (const float*)d_in[14];
    const float* qkvb   = (const float*)d_in[15];
    const float* aow    = (const float*)d_in[16];
    const float* aob    = (const float*)d_in[17];
    const float* f1w    = (const float*)d_in[18];
    const float* f1b    = (const float*)d_in[19];
    const float* f2w    = (const float*)d_in[20];
    const float* f2b    = (const float*)d_in[21];
    const float* hlnw   = (const float*)d_in[22];
    const float* hlnb   = (const float*)d_in[23];
    const float* h1w    = (const float*)d_in[24];
    const float* h1b    = (const float*)d_in[25];
    const float* h2w    = (const float*)d_in[26];
    const float* h2b    = (const float*)d_in[27];
    float* out = (float*)d_out;

    char* wsb = (char*)d_ws;
    float* bh     = (float*)(wsb);               // [N,128] fp32 residual stream (8 MB)
    short* abuf   = (short*)(wsb + 8388608);     // [N,512] bf16 wide scratch / scan pt (16 MB)
    short* bbuf   = (short*)(wsb + 25165824);    // [N,128] bf16 ln/hs/attn-out (4 MB)
    short* qs     = (short*)(wsb + 29360128);    // [N,128] bf16 Q prescaled; ks = +2097152
    short* vt     = (short*)(wsb + 37748736);    // [B,4,32,2048] bf16 V^T (4 MB)
    short* xb     = (short*)(wsb + 41943040);    // [N,64] bf16 input (2 MB)
    short* wb     = (short*)(wsb + 44040192);    // bf16 weights (~1 MB)
    short* ks     = qs + 2097152;

    dim3 blk(256);

    convert_kernel<<<756, blk, 0, stream>>>(x, in_w, ssm_iw, ssm_ow, qkvw, aow, f1w, f2w, xb, wb);

    // input projection + PE + LN(ssm_norm0): writes bh (fp32) and bbuf (bf16 LN)
    gemm_ln<0><<<512, blk, 0, stream>>>(
        xb, wb, in_b, ssm_nw, ssm_nb, bh, bbuf, 64);

    // SSM block 0
    gemm_bf<EPI_SCAN_T><<<dim3(4, 256), blk, 0, stream>>>(
        bbuf, wb + 8192, ssm_ib, abuf, nullptr, 128, 256);
    scan_kernel<<<256, 64, 0, stream>>>(abuf, ssm_A, bbuf);
    gemm_ln<1><<<512, blk, 0, stream>>>(                       // +res, LN(ssm_norm1)
        bbuf, wb + 73728, ssm_ob, ssm_nw + 128, ssm_nb + 128, bh, bbuf, 128);

    // SSM block 1
    gemm_bf<EPI_SCAN_T><<<dim3(4, 256), blk, 0, stream>>>(
        bbuf, wb + 8192 + 32768, ssm_ib + 256, abuf, nullptr, 128, 256);
    scan_kernel<<<256, 64, 0, stream>>>(abuf, ssm_A + 128, bbuf);
    gemm_ln<1><<<512, blk, 0, stream>>>(                       // +res, LN(ln1[0])
        bbuf, wb + 73728 + 16384, ssm_ob + 128, ln1w, ln1b, bh, bbuf, 128);

    // Encoder layer 0
    gemm_bf<EPI_QKV><<<dim3(6, 256), blk, 0, stream>>>(
        bbuf, wb + 106496, qkvb, qs, vt, 128, 384);
    attn_kernel<<<512, blk, 0, stream>>>(qs, ks, vt, bbuf);
    gemm_ln<1><<<512, blk, 0, stream>>>(                       // +res, LN(ln2[0])
        bbuf, wb + 204800, aob, ln2w, ln2b, bh, bbuf, 128);
    gemm_bf<EPI_BF_RELU><<<dim3(8, 256), blk, 0, stream>>>(
        bbuf, wb + 237568, f1b, abuf, nullptr, 128, 512);
    gemm_ln<1><<<512, blk, 0, stream>>>(                       // ff2[0] +res, LN(ln1[1])
        abuf, wb + 368640, f2b, ln1w + 128, ln1b + 128, bh, bbuf, 512);

    // Encoder layer 1
    gemm_bf<EPI_QKV><<<dim3(6, 256), blk, 0, stream>>>(
        bbuf, wb + 106496 + 49152, qkvb + 384, qs, vt, 128, 384);
    attn_kernel<<<512, blk, 0, stream>>>(qs, ks, vt, bbuf);
    gemm_ln<1><<<512, blk, 0, stream>>>(                       // +res, LN(ln2[1])
        bbuf, wb + 204800 + 16384, aob + 128, ln2w + 128, ln2b + 128, bh, bbuf, 128);
    gemm_bf<EPI_BF_RELU><<<dim3(8, 256), blk, 0, stream>>>(
        bbuf, wb + 237568 + 65536, f1b + 512, abuf, nullptr, 128, 512);
    gemm_ln<2><<<512, blk, 0, stream>>>(                       // ff2[1] +res only
        abuf, wb + 368640 + 65536, f2b + 128, nullptr, nullptr, bh, nullptr, 512);

    pool_head_kernel<<<8, 1024, 0, stream>>>(bh, hlnw, hlnb, h1w, h1b, h2w, h2b, out);
}

// Round 9
// 343.056 us; speedup vs baseline: 1.4689x; 1.0000x over previous
//
#include <hip/hip_runtime.h>
#include <hip/hip_bf16.h>
#include <math.h>

#define L_SEQ 2048
#define D_MODEL 128
#define N_ROWS 16384  // B*L = 8*2048
#define LOG2E 1.4426950408889634f

typedef __attribute__((ext_vector_type(8))) short bf16x8;
typedef __attribute__((ext_vector_type(4))) short short4v;
typedef __attribute__((ext_vector_type(4))) float f32x4;

__device__ __forceinline__ short f2bf(float x)  // RNE
{
    __hip_bfloat16 b = __float2bfloat16(x);
    return *reinterpret_cast<short*>(&b);
}
__device__ __forceinline__ short f2bf_fast(float x)  // round-half-up, x >= 0
{
    unsigned u = __builtin_bit_cast(unsigned, x);
    return (short)((u + 0x8000u) >> 16);
}
__device__ __forceinline__ unsigned cvt_pk_bf16(float lo, float hi)  // 2xbf16 in 1 instr
{
    unsigned r;
    asm("v_cvt_pk_bf16_f32 %0, %1, %2" : "=v"(r) : "v"(lo), "v"(hi));
    return r;
}
__device__ __forceinline__ float bf2f(short s)
{
    unsigned u = ((unsigned)(unsigned short)s) << 16;
    return __builtin_bit_cast(float, u);
}
__device__ __forceinline__ short f2h(float x)   // v_cvt_f16_f32
{
    _Float16 h = (_Float16)x;
    return (short)__builtin_bit_cast(unsigned short, h);
}
__device__ __forceinline__ float h2f(short s)   // v_cvt_f32_f16
{
    _Float16 h = __builtin_bit_cast(_Float16, (unsigned short)s);
    return (float)h;
}

// ---------------------------------------------------------------------------
// One-shot fp32 -> bf16 conversion of x and all weight matrices.
// ---------------------------------------------------------------------------
__global__ __launch_bounds__(256) void convert_kernel(
    const float* __restrict__ x,    const float* __restrict__ inw,
    const float* __restrict__ ssmi, const float* __restrict__ ssmo,
    const float* __restrict__ qkvw, const float* __restrict__ aow,
    const float* __restrict__ f1w,  const float* __restrict__ f2w,
    short* __restrict__ xb, short* __restrict__ wb)
{
    int it = blockIdx.x * 256 + threadIdx.x;
    const float* src; short* dst; int off;
    if      (it < 131072) { src = x;    dst = xb;          off = it; }
    else if (it < 132096) { src = inw;  dst = wb;          off = it - 131072; }
    else if (it < 140288) { src = ssmi; dst = wb + 8192;   off = it - 132096; }
    else if (it < 144384) { src = ssmo; dst = wb + 73728;  off = it - 140288; }
    else if (it < 156672) { src = qkvw; dst = wb + 106496; off = it - 144384; }
    else if (it < 160768) { src = aow;  dst = wb + 204800; off = it - 156672; }
    else if (it < 177152) { src = f1w;  dst = wb + 237568; off = it - 160768; }
    else                  { src = f2w;  dst = wb + 368640; off = it - 177152; }
    off <<= 3;
    float4 v0 = *(const float4*)(src + off);
    float4 v1 = *(const float4*)(src + off + 4);
    bf16x8 p = {f2bf(v0.x), f2bf(v0.y), f2bf(v0.z), f2bf(v0.w),
                f2bf(v1.x), f2bf(v1.y), f2bf(v1.z), f2bf(v1.w)};
    *(bf16x8*)(dst + off) = p;
}

// ---------------------------------------------------------------------------
// Fused E=128 GEMM + residual + LayerNorm (R16 occupancy rework, validated R5).
// 32-row x 128-col blocks, grid 512 -> 2 blocks/CU. 4 waves = rh x ch; LN via
// one-pass sum/sumsq partials + 256B LDS cross-wave combine.
// FUSE: 0 = PE+LN, 1 = RES+LN, 2 = RES only (last ff2).
// ---------------------------------------------------------------------------
template <int FUSE>
__global__ __launch_bounds__(256) void gemm_ln(const short* __restrict__ A,
                                               const short* __restrict__ W,
                                               const float* __restrict__ bias,
                                               const float* __restrict__ lnw,
                                               const float* __restrict__ lnb,
                                               float* __restrict__ bh,
                                               short* __restrict__ lnout,
                                               int K)
{
    __shared__ __align__(16) short As[32][72];
    __shared__ __align__(16) short Bs[128][72];
    __shared__ float2 red[2][32];

    const int tid  = threadIdx.x;
    const int wave = tid >> 6;
    const int lane = tid & 63;
    const int m    = lane & 15;
    const int quad = lane >> 4;
    const int rh   = wave & 1;     // row half (16 rows)
    const int ch   = wave >> 1;    // col half (64 cols)
    const int n0   = blockIdx.x * 32;

    const int arow = tid >> 3, acol = (tid & 7) << 3;
    const int brow = tid >> 1, bcol = (tid & 1) << 5;

    const short* Ap = A + (size_t)(n0 + arow) * K + acol;
    const short* Wp = W + (size_t)brow * K + bcol;

    f32x4 acc[4];
#pragma unroll
    for (int i = 0; i < 4; ++i) acc[i] = (f32x4){0.f, 0.f, 0.f, 0.f};

    bf16x8 a0 = *(const bf16x8*)Ap;
    bf16x8 b0 = *(const bf16x8*)Wp;
    bf16x8 b1 = *(const bf16x8*)(Wp + 8);
    bf16x8 b2 = *(const bf16x8*)(Wp + 16);
    bf16x8 b3 = *(const bf16x8*)(Wp + 24);

    for (int k0 = 0; k0 < K; k0 += 64) {
        *(bf16x8*)&As[arow][acol]      = a0;
        *(bf16x8*)&Bs[brow][bcol]      = b0;
        *(bf16x8*)&Bs[brow][bcol + 8]  = b1;
        *(bf16x8*)&Bs[brow][bcol + 16] = b2;
        *(bf16x8*)&Bs[brow][bcol + 24] = b3;
        __syncthreads();
        if (k0 + 64 < K) {
            a0 = *(const bf16x8*)(Ap + k0 + 64);
            b0 = *(const bf16x8*)(Wp + k0 + 64);
            b1 = *(const bf16x8*)(Wp + k0 + 72);
            b2 = *(const bf16x8*)(Wp + k0 + 80);
            b3 = *(const bf16x8*)(Wp + k0 + 88);
        }
#pragma unroll
        for (int ks = 0; ks < 2; ++ks) {
            bf16x8 af = *(const bf16x8*)&As[(rh << 4) + m][(ks << 5) + (quad << 3)];
#pragma unroll
            for (int nt = 0; nt < 4; ++nt) {
                bf16x8 bfr = *(const bf16x8*)&Bs[(ch << 6) + (nt << 4) + m][(ks << 5) + (quad << 3)];
                acc[nt] = __builtin_amdgcn_mfma_f32_16x16x32_bf16(af, bfr, acc[nt], 0, 0, 0);
            }
        }
        __syncthreads();
    }

    // ---- epilogue: bias (+PE | +res), write fp32 bh, keep v in registers ----
#pragma unroll
    for (int nt = 0; nt < 4; ++nt) {
        int col = (ch << 6) + (nt << 4) + m;
        float bv = bias[col];
        float fr = 0.f;
        if (FUSE == 0)
            fr = __expf((float)(col & ~1) * (-0.07195578415606394f)); // -ln(1e4)/128
#pragma unroll
        for (int r = 0; r < 4; ++r) {
            int row = n0 + (rh << 4) + (quad << 2) + r;
            float t = acc[nt][r] + bv;
            if (FUSE == 0) {
                float ang = (float)(row & (L_SEQ - 1)) * fr;
                t += (col & 1) ? cosf(ang) : sinf(ang);
            } else {
                t += bh[(size_t)row * 128 + col];
            }
            acc[nt][r] = t;
            bh[(size_t)row * 128 + col] = t;
        }
    }

    if (FUSE < 2) {
        // ---- LN: one-pass sum/sumsq; 64-col partials cross-wave via LDS ----
        float wv[4], bvn[4];
#pragma unroll
        for (int nt = 0; nt < 4; ++nt) {
            wv[nt]  = lnw[(ch << 6) + (nt << 4) + m];
            bvn[nt] = lnb[(ch << 6) + (nt << 4) + m];
        }
        float s1[4], s2[4];
#pragma unroll
        for (int r = 0; r < 4; ++r) {
            float s = 0.f, q = 0.f;
#pragma unroll
            for (int nt = 0; nt < 4; ++nt) {
                float t = acc[nt][r];
                s += t;
                q = fmaf(t, t, q);
            }
            s += __shfl_xor(s, 1);  q += __shfl_xor(q, 1);
            s += __shfl_xor(s, 2);  q += __shfl_xor(q, 2);
            s += __shfl_xor(s, 4);  q += __shfl_xor(q, 4);
            s += __shfl_xor(s, 8);  q += __shfl_xor(q, 8);
            s1[r] = s; s2[r] = q;
            if (m == 0) red[ch][(rh << 4) + (quad << 2) + r] = make_float2(s, q);
        }
        __syncthreads();
#pragma unroll
        for (int r = 0; r < 4; ++r) {
            float2 o = red[ch ^ 1][(rh << 4) + (quad << 2) + r];
            float ts = s1[r] + o.x;
            float tq = s2[r] + o.y;
            float mean = ts * (1.f / 128.f);
            float var  = tq * (1.f / 128.f) - mean * mean;
            float inv  = rsqrtf(var + 1e-5f);
            int row = n0 + (rh << 4) + (quad << 2) + r;
#pragma unroll
            for (int nt = 0; nt < 4; ++nt) {
                int col = (ch << 6) + (nt << 4) + m;
                lnout[(size_t)row * 128 + col] =
                    f2bf((acc[nt][r] - mean) * inv * wv[nt] + bvn[nt]);
            }
        }
    }
}

// ---------------------------------------------------------------------------
// bf16-native MFMA GEMM v2 (R18): single-shot K=128 staging (neutral R8, kept).
// Epilogues: BF_RELU (ff1), QKV, SCAN_T.
// ---------------------------------------------------------------------------
enum { EPI_BF_RELU = 0, EPI_QKV = 1, EPI_SCAN_T = 2 };

template <int EPI>
__global__ __launch_bounds__(256) void gemm_bf(const short* __restrict__ A,
                                               const short* __restrict__ W,
                                               const float* __restrict__ bias,
                                               short* __restrict__ outb,  // QKV: qs (ks = +2097152); SCAN_T: pt
                                               short* __restrict__ outv,  // QKV: vt
                                               int K, int E)
{
    __shared__ __align__(16) short As[64][136];   // 272B rows: 16B-aligned
    __shared__ __align__(16) short Bs[64][136];

    const int tid  = threadIdx.x;
    const int wave = tid >> 6;
    const int lane = tid & 63;
    const int m    = lane & 15;
    const int quad = lane >> 4;

    const int n0 = blockIdx.y * 64;
    const int e0 = blockIdx.x * 64;

    const int srow = tid >> 2;
    const int scol = (tid & 3) << 5;   // 32-short (64B) chunks: 4 per 128-K row

    const short* Ap = A + (size_t)(n0 + srow) * K + scol;
    const short* Wp = W + (size_t)(e0 + srow) * K + scol;

    // ---- single-shot staging: whole K=128 tile, one barrier ----
    bf16x8 a0 = *(const bf16x8*)(Ap);
    bf16x8 a1 = *(const bf16x8*)(Ap + 8);
    bf16x8 a2 = *(const bf16x8*)(Ap + 16);
    bf16x8 a3 = *(const bf16x8*)(Ap + 24);
    bf16x8 w0 = *(const bf16x8*)(Wp);
    bf16x8 w1 = *(const bf16x8*)(Wp + 8);
    bf16x8 w2 = *(const bf16x8*)(Wp + 16);
    bf16x8 w3 = *(const bf16x8*)(Wp + 24);
    *(bf16x8*)&As[srow][scol]      = a0;
    *(bf16x8*)&As[srow][scol + 8]  = a1;
    *(bf16x8*)&As[srow][scol + 16] = a2;
    *(bf16x8*)&As[srow][scol + 24] = a3;
    *(bf16x8*)&Bs[srow][scol]      = w0;
    *(bf16x8*)&Bs[srow][scol + 8]  = w1;
    *(bf16x8*)&Bs[srow][scol + 16] = w2;
    *(bf16x8*)&Bs[srow][scol + 24] = w3;
    __syncthreads();

    f32x4 acc[4];
#pragma unroll
    for (int i = 0; i < 4; ++i) acc[i] = (f32x4){0.f, 0.f, 0.f, 0.f};

#pragma unroll
    for (int ks = 0; ks < 4; ++ks) {
        bf16x8 af = *(const bf16x8*)&As[(wave << 4) + m][(ks << 5) + (quad << 3)];
#pragma unroll
        for (int nt = 0; nt < 4; ++nt) {
            bf16x8 bfr = *(const bf16x8*)&Bs[(nt << 4) + m][(ks << 5) + (quad << 3)];
            acc[nt] = __builtin_amdgcn_mfma_f32_16x16x32_bf16(af, bfr, acc[nt], 0, 0, 0);
        }
    }

    if (EPI == EPI_QKV) {
        const float QSC = 0.17677669529663687f * LOG2E;  // 1/sqrt(32) * log2e
        if (e0 < 256) {
            short* dst = (e0 < 128) ? outb : (outb + 2097152);
            int cbase = (e0 < 128) ? e0 : (e0 - 128);
#pragma unroll
            for (int nt = 0; nt < 4; ++nt) {
                int col = cbase + (nt << 4) + m;
                float bv = bias[e0 + (nt << 4) + m];
#pragma unroll
                for (int r = 0; r < 4; ++r) {
                    int row = n0 + (wave << 4) + (quad << 2) + r;
                    float v = acc[nt][r] + bv;
                    if (e0 < 128) v *= QSC;
                    dst[(size_t)row * 128 + col] = f2bf(v);
                }
            }
        } else {
            int bb_ = n0 >> 11;
            int l0  = (n0 & (L_SEQ - 1)) + (wave << 4) + (quad << 2);
#pragma unroll
            for (int nt = 0; nt < 4; ++nt) {
                int c  = (e0 - 256) + (nt << 4) + m;
                int hh = c >> 5, dd = c & 31;
                float bv = bias[e0 + (nt << 4) + m];
                short4v pk;
#pragma unroll
                for (int r = 0; r < 4; ++r) pk[r] = f2bf(acc[nt][r] + bv);
                *(short4v*)&outv[(size_t)((bb_ * 4 + hh) * 32 + dd) * L_SEQ + l0] = pk;
            }
        }
    } else if (EPI == EPI_SCAN_T) {
        // transposed write pt[b][e][l] (fp16): u2 for e<128, sigmoid(g) for e>=128
        int bb_ = n0 >> 11;
        int l0  = (n0 & (L_SEQ - 1)) + (wave << 4) + (quad << 2);
#pragma unroll
        for (int nt = 0; nt < 4; ++nt) {
            int col = e0 + (nt << 4) + m;
            float bv = bias[col];
            short4v pk;
            if (e0 < 128) {
#pragma unroll
                for (int r = 0; r < 4; ++r)
                    pk[r] = f2h((acc[nt][r] + bv) * (2.f * LOG2E));
            } else {
#pragma unroll
                for (int r = 0; r < 4; ++r) {
                    float gr = acc[nt][r] + bv;
                    float g = __builtin_amdgcn_rcpf(
                        1.f + __builtin_amdgcn_exp2f(-gr * LOG2E));
                    pk[r] = f2h(g);
                }
            }
            *(short4v*)&outb[(((size_t)(bb_ * 256 + col)) << 11) + l0] = pk;
        }
    } else {  // EPI_BF_RELU
#pragma unroll
        for (int nt = 0; nt < 4; ++nt) {
            int col = e0 + (nt << 4) + m;
            float bv = bias[col];
#pragma unroll
            for (int r = 0; r < 4; ++r) {
                int row = n0 + (wave << 4) + (quad << 2) + r;
                float v = fmaxf(acc[nt][r] + bv, 0.f);
                outb[(size_t)row * E + col] = f2bf(v);
            }
        }
    }
}

// ---------------------------------------------------------------------------
// SSM gated scan — R13 chunked-parallel version (validated R1: 68 -> ~10 us).
// ---------------------------------------------------------------------------
#define SCAN_WARM 128   // burn-in steps (contraction margin)

__device__ __forceinline__ void scan8(float& h, bf16x8 u8, bf16x8 g8,
                                      float a2, short* __restrict__ ob, int l0)
{
#pragma unroll
    for (int i = 0; i < 8; ++i) {
        float u2 = h2f(u8[i]);
        float g  = h2f(g8[i]);
        float omg = 1.f - g;
        float m2  = -2.f * omg;
        float c0 = fmaf(g, h, omg);                          // parallel to exp path
        float e2 = __builtin_amdgcn_exp2f(fmaf(a2, h, u2));  // exp(2x)
        float r  = __builtin_amdgcn_rcpf(1.f + e2);
        h = fmaf(m2, r, c0);
        ob[(l0 + i) * D_MODEL] = f2bf(h);
    }
}

__device__ __forceinline__ void scan8_ns(float& h, bf16x8 u8, bf16x8 g8,
                                         float a2)
{
#pragma unroll
    for (int i = 0; i < 8; ++i) {
        float u2 = h2f(u8[i]);
        float g  = h2f(g8[i]);
        float omg = 1.f - g;
        float m2  = -2.f * omg;
        float c0 = fmaf(g, h, omg);
        float e2 = __builtin_amdgcn_exp2f(fmaf(a2, h, u2));
        float r  = __builtin_amdgcn_rcpf(1.f + e2);
        h = fmaf(m2, r, c0);
    }
}

__global__ __launch_bounds__(64) void scan_kernel(const short* __restrict__ pt,
                                                  const float* __restrict__ A,
                                                  short* __restrict__ hs)
{
    int blk = blockIdx.x;             // 256 blocks = 16 (b,dhalf) x 16 chunks
    int c   = blk & 15;               // chunk index: writes l in [c*128, c*128+128)
    int bd  = blk >> 4;
    int b   = bd >> 1;
    int d   = ((bd & 1) << 6) + threadIdx.x;
    float a2 = 2.f * A[d] * LOG2E;
    const short* up = pt + (((size_t)(b * 256 + d)) << 11);
    const short* gp = up + (((size_t)128) << 11);
    short* ob = hs + ((size_t)(b << 11)) * D_MODEL + d;

    const int lw = c << 7;            // first stored step
    float h = 0.f;

    bf16x8 uA0, uA1, gA0, gA1;

    if (c > 0) {
        // ---- burn-in: SCAN_WARM steps ending at lw, no stores ----
        int l0 = lw - SCAN_WARM;
        uA0 = *(const bf16x8*)(up + l0);
        uA1 = *(const bf16x8*)(up + l0 + 8);
        gA0 = *(const bf16x8*)(gp + l0);
        gA1 = *(const bf16x8*)(gp + l0 + 8);
        for (int l = l0; l < lw; l += 32) {
            bf16x8 uB0 = *(const bf16x8*)(up + l + 16);
            bf16x8 uB1 = *(const bf16x8*)(up + l + 24);
            bf16x8 gB0 = *(const bf16x8*)(gp + l + 16);
            bf16x8 gB1 = *(const bf16x8*)(gp + l + 24);
            scan8_ns(h, uA0, gA0, a2);
            scan8_ns(h, uA1, gA1, a2);
            uA0 = *(const bf16x8*)(up + l + 32);
            uA1 = *(const bf16x8*)(up + l + 40);
            gA0 = *(const bf16x8*)(gp + l + 32);
            gA1 = *(const bf16x8*)(gp + l + 40);
            scan8_ns(h, uB0, gB0, a2);
            scan8_ns(h, uB1, gB1, a2);
        }
    } else {
        uA0 = *(const bf16x8*)(up);
        uA1 = *(const bf16x8*)(up + 8);
        gA0 = *(const bf16x8*)(gp);
        gA1 = *(const bf16x8*)(gp + 8);
    }

    // ---- live phase: 128 steps with stores ----
    for (int l = lw; l < lw + 128; l += 32) {
        bf16x8 uB0 = *(const bf16x8*)(up + l + 16);
        bf16x8 uB1 = *(const bf16x8*)(up + l + 24);
        bf16x8 gB0 = *(const bf16x8*)(gp + l + 16);
        bf16x8 gB1 = *(const bf16x8*)(gp + l + 24);
        scan8(h, uA0, gA0, a2, ob, l);
        scan8(h, uA1, gA1, a2, ob, l + 8);
        if (l + 32 < lw + 128) {      // guard: l+32 would be OOB at chunk end
            uA0 = *(const bf16x8*)(up + l + 32);
            uA1 = *(const bf16x8*)(up + l + 40);
            gA0 = *(const bf16x8*)(gp + l + 32);
            gA1 = *(const bf16x8*)(gp + l + 40);
        }
        scan8(h, uB0, gB0, a2, ob, l + 16);
        scan8(h, uB1, gB1, a2, ob, l + 24);
    }
}

// ---------------------------------------------------------------------------
// Flash attention v8 (R19): split-KV. v7 was TLP-starved (2 blocks/CU,
// MfmaUtil 14 + VALU 43 -> 43% idle); v6 had 4 blocks/CU but 2x LDS traffic.
// Zero-shift softmax is ADDITIVE over KV chunks (no max-rescale coupling):
// split KV into 2 halves of 16 chunks. Grid 1024 -> 4 blocks/CU, 4 waves/SIMD
// (v6 TLP) at v7's per-work LDS traffic. Blocks write un-normalized fp32
// O-partials + per-(head,row) rs partials; attn_reduce sums + normalizes.
// XCD swizzle: one batch element (128 logical blocks) per XCD.
// ---------------------------------------------------------------------------
__global__ __launch_bounds__(256) void attn_kernel(const short* __restrict__ Qs,
                                                   const short* __restrict__ Ks,
                                                   const short* __restrict__ Vtg,
                                                   float* __restrict__ pO,
                                                   float* __restrict__ prs)
{
    __shared__ __align__(16) short Klds[2][64][40];
    __shared__ __align__(16) short Vlds[2][32][72];
    __shared__ __align__(16) short Plds[4][32][68];   // [wave][qt*16+m][k] 34-dw rows

    const int tid  = threadIdx.x;
    const int wave = tid >> 6;
    const int lane = tid & 63;
    const int m    = lane & 15;
    const int quad = lane >> 4;

    // XCD-aware swizzle for grid 1024: XCD x gets logical [x*128, x*128+128)
    // = all heads/q0/halves of batch element x (1MB KV in its L2).
    const int raw = blockIdx.x;
    const int bid = (raw & 7) * 128 + (raw >> 3);
    const int b    = bid >> 7;
    const int h    = (bid >> 5) & 3;
    const int qh   = bid & 31;
    const int q0   = (qh >> 1) << 7;      // 128 q-rows per block
    const int half = qh & 1;              // KV half: rows [half*1024, half*1024+1024)
    const int kv0  = half << 10;

    const size_t qrow = (size_t)((b << 11) + q0 + (wave << 5) + m);
    bf16x8 qfA = *(const bf16x8*)&Qs[qrow * 128 + (h << 5) + (quad << 3)];
    bf16x8 qfB = *(const bf16x8*)&Qs[(qrow + 16) * 128 + (h << 5) + (quad << 3)];

    f32x4 O00 = {0.f,0.f,0.f,0.f}, O01 = {0.f,0.f,0.f,0.f};   // qt0: dt0, dt1
    f32x4 O10 = {0.f,0.f,0.f,0.f}, O11 = {0.f,0.f,0.f,0.f};   // qt1: dt0, dt1
    float rs0 = 0.f, rs1 = 0.f;

    const int krow = tid >> 2, dg = (tid & 3) << 3;
    const int vrow = tid >> 3, kg = (tid & 7) << 3;
    const short* kbase = Ks + ((size_t)((b << 11) + kv0) + krow) * 128 + (h << 5) + dg;
    const short* vbase = Vtg + ((size_t)((b << 2) + h) * 32 + vrow) * L_SEQ + kv0 + kg;

    // stage chunk 0
    bf16x8 kreg = *(const bf16x8*)kbase;
    bf16x8 vreg = *(const bf16x8*)vbase;
    *(bf16x8*)&Klds[0][krow][dg] = kreg;
    *(bf16x8*)&Vlds[0][vrow][kg] = vreg;
    __syncthreads();

    for (int kc = 0; kc < 16; ++kc) {
        const int cur = kc & 1;
        if (kc < 15) {  // prefetch next chunk into registers (coalesced bulk)
            kreg = *(const bf16x8*)(kbase + (size_t)((kc + 1) << 6) * 128);
            vreg = *(const bf16x8*)(vbase + ((kc + 1) << 6));
        }

        // ---- swapped QK^T: each kf read feeds both q-tiles ----
#pragma unroll
        for (int kt = 0; kt < 4; ++kt) {
            bf16x8 kf = *(const bf16x8*)&Klds[cur][(kt << 4) + m][quad << 3];
            f32x4 S0 = __builtin_amdgcn_mfma_f32_16x16x32_bf16(
                kf, qfA, (f32x4){0.f, 0.f, 0.f, 0.f}, 0, 0, 0);
            f32x4 S1 = __builtin_amdgcn_mfma_f32_16x16x32_bf16(
                kf, qfB, (f32x4){0.f, 0.f, 0.f, 0.f}, 0, 0, 0);
            float a0 = __builtin_amdgcn_exp2f(S0[0]);
            float a1 = __builtin_amdgcn_exp2f(S0[1]);
            float a2 = __builtin_amdgcn_exp2f(S0[2]);
            float a3 = __builtin_amdgcn_exp2f(S0[3]);
            rs0 += a0 + a1 + a2 + a3;
            uint2 pkA;
            pkA.x = cvt_pk_bf16(a0, a1);
            pkA.y = cvt_pk_bf16(a2, a3);
            *(uint2*)&Plds[wave][m][(kt << 4) + (quad << 2)] = pkA;
            float b0 = __builtin_amdgcn_exp2f(S1[0]);
            float b1 = __builtin_amdgcn_exp2f(S1[1]);
            float b2 = __builtin_amdgcn_exp2f(S1[2]);
            float b3 = __builtin_amdgcn_exp2f(S1[3]);
            rs1 += b0 + b1 + b2 + b3;
            uint2 pkB;
            pkB.x = cvt_pk_bf16(b0, b1);
            pkB.y = cvt_pk_bf16(b2, b3);
            *(uint2*)&Plds[wave][16 + m][(kt << 4) + (quad << 2)] = pkB;
        }

        // ---- PV: each vf read feeds both q-tiles ----
#pragma unroll
        for (int kt2 = 0; kt2 < 2; ++kt2) {
            short4v aLo = *(const short4v*)&Plds[wave][m][(kt2 << 5) + (quad << 3)];
            short4v aHi = *(const short4v*)&Plds[wave][m][(kt2 << 5) + (quad << 3) + 4];
            bf16x8 pfA = {aLo[0], aLo[1], aLo[2], aLo[3],
                          aHi[0], aHi[1], aHi[2], aHi[3]};
            short4v bLo = *(const short4v*)&Plds[wave][16 + m][(kt2 << 5) + (quad << 3)];
            short4v bHi = *(const short4v*)&Plds[wave][16 + m][(kt2 << 5) + (quad << 3) + 4];
            bf16x8 pfB = {bLo[0], bLo[1], bLo[2], bLo[3],
                          bHi[0], bHi[1], bHi[2], bHi[3]};
            bf16x8 vf0 = *(const bf16x8*)&Vlds[cur][m][(kt2 << 5) + (quad << 3)];
            bf16x8 vf1 = *(const bf16x8*)&Vlds[cur][16 + m][(kt2 << 5) + (quad << 3)];
            O00 = __builtin_amdgcn_mfma_f32_16x16x32_bf16(pfA, vf0, O00, 0, 0, 0);
            O01 = __builtin_amdgcn_mfma_f32_16x16x32_bf16(pfA, vf1, O01, 0, 0, 0);
            O10 = __builtin_amdgcn_mfma_f32_16x16x32_bf16(pfB, vf0, O10, 0, 0, 0);
            O11 = __builtin_amdgcn_mfma_f32_16x16x32_bf16(pfB, vf1, O11, 0, 0, 0);
        }

        // ---- write next K/V buffer; single barrier per chunk ----
        if (kc < 15) {
            *(bf16x8*)&Klds[cur ^ 1][krow][dg] = kreg;
            *(bf16x8*)&Vlds[cur ^ 1][vrow][kg] = vreg;
        }
        __syncthreads();
    }

    // rs per lane (q=m): finish across quads; write per-(half,head,row) partial
    rs0 += __shfl_xor(rs0, 16);
    rs0 += __shfl_xor(rs0, 32);
    rs1 += __shfl_xor(rs1, 16);
    rs1 += __shfl_xor(rs1, 32);

    const int rowbase = (b << 11) + q0 + (wave << 5);
    if (quad == 0) {   // lanes 0..15 hold rs for q = m
        prs[(size_t)((half << 2) + h) * N_ROWS + rowbase + m]      = rs0;
        prs[(size_t)((half << 2) + h) * N_ROWS + rowbase + 16 + m] = rs1;
    }

    // un-normalized O partials (fp32): pO[half][row][h*32 + d]
    float* pb = pO + (size_t)(half * N_ROWS) * 128;
#pragma unroll
    for (int r = 0; r < 4; ++r) {
        int rowA = rowbase + (quad << 2) + r;
        float* opA = pb + (size_t)rowA * 128 + (h << 5) + m;
        opA[0]  = O00[r];
        opA[16] = O01[r];
        float* opB = opA + (size_t)16 * 128;
        opB[0]  = O10[r];
        opB[16] = O11[r];
    }
}

// ---------------------------------------------------------------------------
// attn_reduce (R19): out = (pO[0]+pO[1]) / (rs[0]+rs[1]), bf16.
// 16384 rows x 128 cols; each thread does 8 contiguous cols of one row.
// ---------------------------------------------------------------------------
__global__ __launch_bounds__(256) void attn_reduce(const float* __restrict__ pO,
                                                   const float* __restrict__ prs,
                                                   short* __restrict__ outb)
{
    int idx = blockIdx.x * 256 + threadIdx.x;   // 16384*16 units
    int row = idx >> 4;
    int cg  = (idx & 15) << 3;                  // col base, 8 cols
    int h   = cg >> 5;
    float rs = prs[(size_t)h * N_ROWS + row] + prs[(size_t)(4 + h) * N_ROWS + row];
    float inv = 1.f / rs;
    const float* p0 = pO + (size_t)row * 128 + cg;
    const float* p1 = p0 + (size_t)N_ROWS * 128;
    float4 a0 = *(const float4*)p0;
    float4 a1 = *(const float4*)(p0 + 4);
    float4 b0 = *(const float4*)p1;
    float4 b1 = *(const float4*)(p1 + 4);
    bf16x8 o = {f2bf((a0.x + b0.x) * inv), f2bf((a0.y + b0.y) * inv),
                f2bf((a0.z + b0.z) * inv), f2bf((a0.w + b0.w) * inv),
                f2bf((a1.x + b1.x) * inv), f2bf((a1.y + b1.y) * inv),
                f2bf((a1.z + b1.z) * inv), f2bf((a1.w + b1.w) * inv)};
    *(bf16x8*)&outb[(size_t)row * 128 + cg] = o;
}

// ---------------------------------------------------------------------------
// Fused pool + head (R12): one 1024-thread block per batch element.
// ---------------------------------------------------------------------------
__global__ __launch_bounds__(1024) void pool_head_kernel(
    const float* __restrict__ h,
    const float* __restrict__ hlnw, const float* __restrict__ hlnb,
    const float* __restrict__ h1w, const float* __restrict__ h1b,
    const float* __restrict__ h2w, const float* __restrict__ h2b,
    float* __restrict__ out)
{
    __shared__ float part[8][128];
    __shared__ float sd[128];
    __shared__ float sq[128];

    int b   = blockIdx.x;
    int t   = threadIdx.x;
    int d   = t & 127;
    int seg = t >> 7;    // 0..7
    const float* hb = h + (size_t)b * L_SEQ * D_MODEL;

    // ---- phase 1: pool ----
    float acc = 0.f;
    int l0 = seg << 8;
    for (int l = l0; l < l0 + 256; l += 4) {
        acc += hb[(l + 0) * D_MODEL + d] + hb[(l + 1) * D_MODEL + d]
             + hb[(l + 2) * D_MODEL + d] + hb[(l + 3) * D_MODEL + d];
    }
    part[seg][d] = acc;
    __syncthreads();

    // ---- phase 2: head (threads 0..127 compute; all hit barriers) ----
    float v = 0.f;
    if (t < 128) {
        float s = 0.f;
#pragma unroll
        for (int i = 0; i < 8; ++i) s += part[i][t];
        v = 0.5f * hb[(L_SEQ - 1) * D_MODEL + t] + 0.5f * (s * (1.f / (float)L_SEQ));
        sd[t] = v;
    }
    __syncthreads();
    for (int s = 64; s > 0; s >>= 1) {
        if (t < s) sd[t] += sd[t + s];
        __syncthreads();
    }
    float mu = sd[0] * (1.f / 128.f);
    __syncthreads();
    float dv = v - mu;
    if (t < 128) sd[t] = dv * dv;
    __syncthreads();
    for (int s = 64; s > 0; s >>= 1) {
        if (t < s) sd[t] += sd[t + s];
        __syncthreads();
    }
    float var = sd[0] * (1.f / 128.f);
    __syncthreads();
    if (t < 128) sq[t] = dv * rsqrtf(var + 1e-5f) * hlnw[t] + hlnb[t];
    __syncthreads();
    if (t < 128) {
        float dot = h1b[t];
        for (int d2 = 0; d2 < 128; ++d2) dot = fmaf(sq[d2], h1w[t * 128 + d2], dot);
        float ge = 0.5f * dot * (1.f + erff(dot * 0.7071067811865475f));
        sd[t] = ge * h2w[t];
    }
    __syncthreads();
    for (int s = 64; s > 0; s >>= 1) {
        if (t < s) sd[t] += sd[t + s];
        __syncthreads();
    }
    if (t == 0) out[b] = sd[0] + h2b[0];
}

// ---------------------------------------------------------------------------
extern "C" void kernel_launch(void* const* d_in, const int* in_sizes, int n_in,
                              void* d_out, int out_size, void* d_ws, size_t ws_size,
                              hipStream_t stream)
{
    (void)in_sizes; (void)n_in; (void)out_size; (void)ws_size;
    const float* x      = (const float*)d_in[0];
    const float* in_w   = (const float*)d_in[1];
    const float* in_b   = (const float*)d_in[2];
    const float* ssm_nw = (const float*)d_in[3];
    const float* ssm_nb = (const float*)d_in[4];
    const float* ssm_A  = (const float*)d_in[5];
    const float* ssm_iw = (const float*)d_in[6];
    const float* ssm_ib = (const float*)d_in[7];
    const float* ssm_ow = (const float*)d_in[8];
    const float* ssm_ob = (const float*)d_in[9];
    const float* ln1w   = (const float*)d_in[10];
    const float* ln1b   = (const float*)d_in[11];
    const float* ln2w   = (const float*)d_in[12];
    const float* ln2b   = (const float*)d_in[13];
    const float* qkvw   = (const float*)d_in[14];
    const float* qkvb   = (const float*)d_in[15];
    const float* aow    = (const float*)d_in[16];
    const float* aob    = (const float*)d_in[17];
    const float* f1w    = (const float*)d_in[18];
    const float* f1b    = (const float*)d_in[19];
    const float* f2w    = (const float*)d_in[20];
    const float* f2b    = (const float*)d_in[21];
    const float* hlnw   = (const float*)d_in[22];
    const float* hlnb   = (const float*)d_in[23];
    const float* h1w    = (const float*)d_in[24];
    const float* h1b    = (const float*)d_in[25];
    const float* h2w    = (const float*)d_in[26];
    const float* h2b    = (const float*)d_in[27];
    float* out = (float*)d_out;

    char* wsb = (char*)d_ws;
    float* bh     = (float*)(wsb);               // [N,128] fp32 residual stream (8 MB)
    short* abuf   = (short*)(wsb + 8388608);     // [N,512] bf16 wide scratch / scan pt (16 MB)
    short* bbuf   = (short*)(wsb + 25165824);    // [N,128] bf16 ln/hs/attn-out (4 MB)
    short* qs     = (short*)(wsb + 29360128);    // [N,128] bf16 Q prescaled; ks = +2097152
    short* vt     = (short*)(wsb + 37748736);    // [B,4,32,2048] bf16 V^T (4 MB)
    short* xb     = (short*)(wsb + 41943040);    // [N,64] bf16 input (2 MB)
    short* wb     = (short*)(wsb + 44040192);    // bf16 weights (~1 MB)
    float* pO     = (float*)(wsb + 46137344);    // [2][N,128] fp32 attn O partials (16 MB)
    float* prs    = (float*)(wsb + 62914560);    // [2][4][N] fp32 attn rs partials (512 KB)
    short* ks     = qs + 2097152;

    dim3 blk(256);

    convert_kernel<<<756, blk, 0, stream>>>(x, in_w, ssm_iw, ssm_ow, qkvw, aow, f1w, f2w, xb, wb);

    // input projection + PE + LN(ssm_norm0): writes bh (fp32) and bbuf (bf16 LN)
    gemm_ln<0><<<512, blk, 0, stream>>>(
        xb, wb, in_b, ssm_nw, ssm_nb, bh, bbuf, 64);

    // SSM block 0
    gemm_bf<EPI_SCAN_T><<<dim3(4, 256), blk, 0, stream>>>(
        bbuf, wb + 8192, ssm_ib, abuf, nullptr, 128, 256);
    scan_kernel<<<256, 64, 0, stream>>>(abuf, ssm_A, bbuf);
    gemm_ln<1><<<512, blk, 0, stream>>>(                       // +res, LN(ssm_norm1)
        bbuf, wb + 73728, ssm_ob, ssm_nw + 128, ssm_nb + 128, bh, bbuf, 128);

    // SSM block 1
    gemm_bf<EPI_SCAN_T><<<dim3(4, 256), blk, 0, stream>>>(
        bbuf, wb + 8192 + 32768, ssm_ib + 256, abuf, nullptr, 128, 256);
    scan_kernel<<<256, 64, 0, stream>>>(abuf, ssm_A + 128, bbuf);
    gemm_ln<1><<<512, blk, 0, stream>>>(                       // +res, LN(ln1[0])
        bbuf, wb + 73728 + 16384, ssm_ob + 128, ln1w, ln1b, bh, bbuf, 128);

    // Encoder layer 0
    gemm_bf<EPI_QKV><<<dim3(6, 256), blk, 0, stream>>>(
        bbuf, wb + 106496, qkvb, qs, vt, 128, 384);
    attn_kernel<<<1024, blk, 0, stream>>>(qs, ks, vt, pO, prs);
    attn_reduce<<<1024, blk, 0, stream>>>(pO, prs, bbuf);
    gemm_ln<1><<<512, blk, 0, stream>>>(                       // +res, LN(ln2[0])
        bbuf, wb + 204800, aob, ln2w, ln2b, bh, bbuf, 128);
    gemm_bf<EPI_BF_RELU><<<dim3(8, 256), blk, 0, stream>>>(
        bbuf, wb + 237568, f1b, abuf, nullptr, 128, 512);
    gemm_ln<1><<<512, blk, 0, stream>>>(                       // ff2[0] +res, LN(ln1[1])
        abuf, wb + 368640, f2b, ln1w + 128, ln1b + 128, bh, bbuf, 512);

    // Encoder layer 1
    gemm_bf<EPI_QKV><<<dim3(6, 256), blk, 0, stream>>>(
        bbuf, wb + 106496 + 49152, qkvb + 384, qs, vt, 128, 384);
    attn_kernel<<<1024, blk, 0, stream>>>(qs, ks, vt, pO, prs);
    attn_reduce<<<1024, blk, 0, stream>>>(pO, prs, bbuf);
    gemm_ln<1><<<512, blk, 0, stream>>>(                       // +res, LN(ln2[1])
        bbuf, wb + 204800 + 16384, aob + 128, ln2w + 128, ln2b + 128, bh, bbuf, 128);
    gemm_bf<EPI_BF_RELU><<<dim3(8, 256), blk, 0, stream>>>(
        bbuf, wb + 237568 + 65536, f1b + 512, abuf, nullptr, 128, 512);
    gemm_ln<2><<<512, blk, 0, stream>>>(                       // ff2[1] +res only
        abuf, wb + 368640 + 65536, f2b + 128, nullptr, nullptr, bh, nullptr, 512);

    pool_head_kernel<<<8, 1024, 0, stream>>>(bh, hlnw, hlnb, h1w, h1b, h2w, h2b, out);
}

// Round 11
// 336.848 us; speedup vs baseline: 1.4959x; 1.0184x over previous
//
#include <hip/hip_runtime.h>
#include <hip/hip_bf16.h>
#include <math.h>

#define L_SEQ 2048
#define D_MODEL 128
#define N_ROWS 16384  // B*L = 8*2048
#define LOG2E 1.4426950408889634f

typedef __attribute__((ext_vector_type(8))) short bf16x8;
typedef __attribute__((ext_vector_type(4))) short short4v;
typedef __attribute__((ext_vector_type(4))) float f32x4;
typedef __attribute__((ext_vector_type(4))) unsigned uint4v;

__device__ __forceinline__ short f2bf(float x)  // RNE
{
    __hip_bfloat16 b = __float2bfloat16(x);
    return *reinterpret_cast<short*>(&b);
}
__device__ __forceinline__ short f2bf_fast(float x)  // round-half-up, x >= 0
{
    unsigned u = __builtin_bit_cast(unsigned, x);
    return (short)((u + 0x8000u) >> 16);
}
__device__ __forceinline__ unsigned cvt_pk_bf16(float lo, float hi)  // 2xbf16 in 1 instr
{
    unsigned r;
    asm("v_cvt_pk_bf16_f32 %0, %1, %2" : "=v"(r) : "v"(lo), "v"(hi));
    return r;
}
__device__ __forceinline__ float bf2f(short s)
{
    unsigned u = ((unsigned)(unsigned short)s) << 16;
    return __builtin_bit_cast(float, u);
}
__device__ __forceinline__ short f2h(float x)   // v_cvt_f16_f32
{
    _Float16 h = (_Float16)x;
    return (short)__builtin_bit_cast(unsigned short, h);
}
__device__ __forceinline__ float h2f(short s)   // v_cvt_f32_f16
{
    _Float16 h = __builtin_bit_cast(_Float16, (unsigned short)s);
    return (float)h;
}

// ---------------------------------------------------------------------------
// One-shot fp32 -> bf16 conversion of x and all weight matrices.
// ---------------------------------------------------------------------------
__global__ __launch_bounds__(256) void convert_kernel(
    const float* __restrict__ x,    const float* __restrict__ inw,
    const float* __restrict__ ssmi, const float* __restrict__ ssmo,
    const float* __restrict__ qkvw, const float* __restrict__ aow,
    const float* __restrict__ f1w,  const float* __restrict__ f2w,
    short* __restrict__ xb, short* __restrict__ wb)
{
    int it = blockIdx.x * 256 + threadIdx.x;
    const float* src; short* dst; int off;
    if      (it < 131072) { src = x;    dst = xb;          off = it; }
    else if (it < 132096) { src = inw;  dst = wb;          off = it - 131072; }
    else if (it < 140288) { src = ssmi; dst = wb + 8192;   off = it - 132096; }
    else if (it < 144384) { src = ssmo; dst = wb + 73728;  off = it - 140288; }
    else if (it < 156672) { src = qkvw; dst = wb + 106496; off = it - 144384; }
    else if (it < 160768) { src = aow;  dst = wb + 204800; off = it - 156672; }
    else if (it < 177152) { src = f1w;  dst = wb + 237568; off = it - 160768; }
    else                  { src = f2w;  dst = wb + 368640; off = it - 177152; }
    off <<= 3;
    float4 v0 = *(const float4*)(src + off);
    float4 v1 = *(const float4*)(src + off + 4);
    bf16x8 p = {f2bf(v0.x), f2bf(v0.y), f2bf(v0.z), f2bf(v0.w),
                f2bf(v1.x), f2bf(v1.y), f2bf(v1.z), f2bf(v1.w)};
    *(bf16x8*)(dst + off) = p;
}

// ---------------------------------------------------------------------------
// Fused E=128 GEMM + residual + LayerNorm (R16 rework, validated R5).
// 32-row x 128-col blocks, grid 512. 4 waves = rh x ch; LN via one-pass
// sum/sumsq partials + 256B LDS cross-wave combine.
// FUSE: 0 = PE+LN, 1 = RES+LN, 2 = RES only.
// RED (R20): A-operand = split-KV attn partials — staging loads fp32
// pO halves, sums, normalizes by (rs0+rs1), packs bf16 in-register.
// Replaces the attn_reduce dispatch (2 fewer launches, -8MB HBM/layer).
// ---------------------------------------------------------------------------
template <int FUSE, int RED>
__global__ __launch_bounds__(256) void gemm_ln(const short* __restrict__ A,
                                               const short* __restrict__ W,
                                               const float* __restrict__ bias,
                                               const float* __restrict__ lnw,
                                               const float* __restrict__ lnb,
                                               float* __restrict__ bh,
                                               short* __restrict__ lnout,
                                               int K,
                                               const float* __restrict__ pO,
                                               const float* __restrict__ prs)
{
    __shared__ __align__(16) short As[32][72];
    __shared__ __align__(16) short Bs[128][72];
    __shared__ float2 red[2][32];

    const int tid  = threadIdx.x;
    const int wave = tid >> 6;
    const int lane = tid & 63;
    const int m    = lane & 15;
    const int quad = lane >> 4;
    const int rh   = wave & 1;     // row half (16 rows)
    const int ch   = wave >> 1;    // col half (64 cols)
    const int n0   = blockIdx.x * 32;

    const int arow = tid >> 3, acol = (tid & 7) << 3;
    const int brow = tid >> 1, bcol = (tid & 1) << 5;

    const short* Ap = A + (size_t)(n0 + arow) * K + acol;
    const short* Wp = W + (size_t)brow * K + bcol;

    f32x4 acc[4];
#pragma unroll
    for (int i = 0; i < 4; ++i) acc[i] = (f32x4){0.f, 0.f, 0.f, 0.f};

    bf16x8 a0;
    float4 ra0, ra1, rb0, rb1;
    float inva = 0.f;
    if (RED) {
        int row = n0 + arow;
        int hh  = acol >> 5;
        float rsv = prs[(size_t)hh * N_ROWS + row] + prs[(size_t)(4 + hh) * N_ROWS + row];
        inva = 1.f / rsv;
        const float* p0 = pO + (size_t)row * 128 + acol;
        const float* p1 = p0 + (size_t)N_ROWS * 128;
        ra0 = *(const float4*)p0;
        ra1 = *(const float4*)(p0 + 4);
        rb0 = *(const float4*)p1;
        rb1 = *(const float4*)(p1 + 4);
    } else {
        a0 = *(const bf16x8*)Ap;
    }
    bf16x8 b0 = *(const bf16x8*)Wp;
    bf16x8 b1 = *(const bf16x8*)(Wp + 8);
    bf16x8 b2 = *(const bf16x8*)(Wp + 16);
    bf16x8 b3 = *(const bf16x8*)(Wp + 24);

    for (int k0 = 0; k0 < K; k0 += 64) {
        if (RED) {
            uint4v pk;
            pk.x = cvt_pk_bf16((ra0.x + rb0.x) * inva, (ra0.y + rb0.y) * inva);
            pk.y = cvt_pk_bf16((ra0.z + rb0.z) * inva, (ra0.w + rb0.w) * inva);
            pk.z = cvt_pk_bf16((ra1.x + rb1.x) * inva, (ra1.y + rb1.y) * inva);
            pk.w = cvt_pk_bf16((ra1.z + rb1.z) * inva, (ra1.w + rb1.w) * inva);
            *(bf16x8*)&As[arow][acol] = __builtin_bit_cast(bf16x8, pk);
        } else {
            *(bf16x8*)&As[arow][acol] = a0;
        }
        *(bf16x8*)&Bs[brow][bcol]      = b0;
        *(bf16x8*)&Bs[brow][bcol + 8]  = b1;
        *(bf16x8*)&Bs[brow][bcol + 16] = b2;
        *(bf16x8*)&Bs[brow][bcol + 24] = b3;
        __syncthreads();
        if (k0 + 64 < K) {
            if (RED) {
                int row = n0 + arow;
                int col = k0 + 64 + acol;
                int hh  = col >> 5;
                float rsv = prs[(size_t)hh * N_ROWS + row] + prs[(size_t)(4 + hh) * N_ROWS + row];
                inva = 1.f / rsv;
                const float* p0 = pO + (size_t)row * 128 + col;
                const float* p1 = p0 + (size_t)N_ROWS * 128;
                ra0 = *(const float4*)p0;
                ra1 = *(const float4*)(p0 + 4);
                rb0 = *(const float4*)p1;
                rb1 = *(const float4*)(p1 + 4);
            } else {
                a0 = *(const bf16x8*)(Ap + k0 + 64);
            }
            b0 = *(const bf16x8*)(Wp + k0 + 64);
            b1 = *(const bf16x8*)(Wp + k0 + 72);
            b2 = *(const bf16x8*)(Wp + k0 + 80);
            b3 = *(const bf16x8*)(Wp + k0 + 88);
        }
#pragma unroll
        for (int ks = 0; ks < 2; ++ks) {
            bf16x8 af = *(const bf16x8*)&As[(rh << 4) + m][(ks << 5) + (quad << 3)];
#pragma unroll
            for (int nt = 0; nt < 4; ++nt) {
                bf16x8 bfr = *(const bf16x8*)&Bs[(ch << 6) + (nt << 4) + m][(ks << 5) + (quad << 3)];
                acc[nt] = __builtin_amdgcn_mfma_f32_16x16x32_bf16(af, bfr, acc[nt], 0, 0, 0);
            }
        }
        __syncthreads();
    }

    // ---- epilogue: bias (+PE | +res), write fp32 bh, keep v in registers ----
#pragma unroll
    for (int nt = 0; nt < 4; ++nt) {
        int col = (ch << 6) + (nt << 4) + m;
        float bv = bias[col];
        float fr = 0.f;
        if (FUSE == 0)
            fr = __expf((float)(col & ~1) * (-0.07195578415606394f)); // -ln(1e4)/128
#pragma unroll
        for (int r = 0; r < 4; ++r) {
            int row = n0 + (rh << 4) + (quad << 2) + r;
            float t = acc[nt][r] + bv;
            if (FUSE == 0) {
                float ang = (float)(row & (L_SEQ - 1)) * fr;
                t += (col & 1) ? cosf(ang) : sinf(ang);
            } else {
                t += bh[(size_t)row * 128 + col];
            }
            acc[nt][r] = t;
            bh[(size_t)row * 128 + col] = t;
        }
    }

    if (FUSE < 2) {
        // ---- LN: one-pass sum/sumsq; 64-col partials cross-wave via LDS ----
        float wv[4], bvn[4];
#pragma unroll
        for (int nt = 0; nt < 4; ++nt) {
            wv[nt]  = lnw[(ch << 6) + (nt << 4) + m];
            bvn[nt] = lnb[(ch << 6) + (nt << 4) + m];
        }
        float s1[4], s2[4];
#pragma unroll
        for (int r = 0; r < 4; ++r) {
            float s = 0.f, q = 0.f;
#pragma unroll
            for (int nt = 0; nt < 4; ++nt) {
                float t = acc[nt][r];
                s += t;
                q = fmaf(t, t, q);
            }
            s += __shfl_xor(s, 1);  q += __shfl_xor(q, 1);
            s += __shfl_xor(s, 2);  q += __shfl_xor(q, 2);
            s += __shfl_xor(s, 4);  q += __shfl_xor(q, 4);
            s += __shfl_xor(s, 8);  q += __shfl_xor(q, 8);
            s1[r] = s; s2[r] = q;
            if (m == 0) red[ch][(rh << 4) + (quad << 2) + r] = make_float2(s, q);
        }
        __syncthreads();
#pragma unroll
        for (int r = 0; r < 4; ++r) {
            float2 o = red[ch ^ 1][(rh << 4) + (quad << 2) + r];
            float ts = s1[r] + o.x;
            float tq = s2[r] + o.y;
            float mean = ts * (1.f / 128.f);
            float var  = tq * (1.f / 128.f) - mean * mean;
            float inv  = rsqrtf(var + 1e-5f);
            int row = n0 + (rh << 4) + (quad << 2) + r;
#pragma unroll
            for (int nt = 0; nt < 4; ++nt) {
                int col = (ch << 6) + (nt << 4) + m;
                lnout[(size_t)row * 128 + col] =
                    f2bf((acc[nt][r] - mean) * inv * wv[nt] + bvn[nt]);
            }
        }
    }
}

// ---------------------------------------------------------------------------
// bf16-native MFMA GEMM v2 (R18): single-shot K=128 staging (neutral R8, kept).
// Epilogues: BF_RELU (ff1), QKV, SCAN_T.
// ---------------------------------------------------------------------------
enum { EPI_BF_RELU = 0, EPI_QKV = 1, EPI_SCAN_T = 2 };

template <int EPI>
__global__ __launch_bounds__(256) void gemm_bf(const short* __restrict__ A,
                                               const short* __restrict__ W,
                                               const float* __restrict__ bias,
                                               short* __restrict__ outb,  // QKV: qs (ks = +2097152); SCAN_T: pt
                                               short* __restrict__ outv,  // QKV: vt
                                               int K, int E)
{
    __shared__ __align__(16) short As[64][136];   // 272B rows: 16B-aligned
    __shared__ __align__(16) short Bs[64][136];

    const int tid  = threadIdx.x;
    const int wave = tid >> 6;
    const int lane = tid & 63;
    const int m    = lane & 15;
    const int quad = lane >> 4;

    const int n0 = blockIdx.y * 64;
    const int e0 = blockIdx.x * 64;

    const int srow = tid >> 2;
    const int scol = (tid & 3) << 5;   // 32-short (64B) chunks: 4 per 128-K row

    const short* Ap = A + (size_t)(n0 + srow) * K + scol;
    const short* Wp = W + (size_t)(e0 + srow) * K + scol;

    // ---- single-shot staging: whole K=128 tile, one barrier ----
    bf16x8 a0 = *(const bf16x8*)(Ap);
    bf16x8 a1 = *(const bf16x8*)(Ap + 8);
    bf16x8 a2 = *(const bf16x8*)(Ap + 16);
    bf16x8 a3 = *(const bf16x8*)(Ap + 24);
    bf16x8 w0 = *(const bf16x8*)(Wp);
    bf16x8 w1 = *(const bf16x8*)(Wp + 8);
    bf16x8 w2 = *(const bf16x8*)(Wp + 16);
    bf16x8 w3 = *(const bf16x8*)(Wp + 24);
    *(bf16x8*)&As[srow][scol]      = a0;
    *(bf16x8*)&As[srow][scol + 8]  = a1;
    *(bf16x8*)&As[srow][scol + 16] = a2;
    *(bf16x8*)&As[srow][scol + 24] = a3;
    *(bf16x8*)&Bs[srow][scol]      = w0;
    *(bf16x8*)&Bs[srow][scol + 8]  = w1;
    *(bf16x8*)&Bs[srow][scol + 16] = w2;
    *(bf16x8*)&Bs[srow][scol + 24] = w3;
    __syncthreads();

    f32x4 acc[4];
#pragma unroll
    for (int i = 0; i < 4; ++i) acc[i] = (f32x4){0.f, 0.f, 0.f, 0.f};

#pragma unroll
    for (int ks = 0; ks < 4; ++ks) {
        bf16x8 af = *(const bf16x8*)&As[(wave << 4) + m][(ks << 5) + (quad << 3)];
#pragma unroll
        for (int nt = 0; nt < 4; ++nt) {
            bf16x8 bfr = *(const bf16x8*)&Bs[(nt << 4) + m][(ks << 5) + (quad << 3)];
            acc[nt] = __builtin_amdgcn_mfma_f32_16x16x32_bf16(af, bfr, acc[nt], 0, 0, 0);
        }
    }

    if (EPI == EPI_QKV) {
        const float QSC = 0.17677669529663687f * LOG2E;  // 1/sqrt(32) * log2e
        if (e0 < 256) {
            short* dst = (e0 < 128) ? outb : (outb + 2097152);
            int cbase = (e0 < 128) ? e0 : (e0 - 128);
#pragma unroll
            for (int nt = 0; nt < 4; ++nt) {
                int col = cbase + (nt << 4) + m;
                float bv = bias[e0 + (nt << 4) + m];
#pragma unroll
                for (int r = 0; r < 4; ++r) {
                    int row = n0 + (wave << 4) + (quad << 2) + r;
                    float v = acc[nt][r] + bv;
                    if (e0 < 128) v *= QSC;
                    dst[(size_t)row * 128 + col] = f2bf(v);
                }
            }
        } else {
            int bb_ = n0 >> 11;
            int l0  = (n0 & (L_SEQ - 1)) + (wave << 4) + (quad << 2);
#pragma unroll
            for (int nt = 0; nt < 4; ++nt) {
                int c  = (e0 - 256) + (nt << 4) + m;
                int hh = c >> 5, dd = c & 31;
                float bv = bias[e0 + (nt << 4) + m];
                short4v pk;
#pragma unroll
                for (int r = 0; r < 4; ++r) pk[r] = f2bf(acc[nt][r] + bv);
                *(short4v*)&outv[(size_t)((bb_ * 4 + hh) * 32 + dd) * L_SEQ + l0] = pk;
            }
        }
    } else if (EPI == EPI_SCAN_T) {
        // transposed write pt[b][e][l] (fp16): u2 for e<128, sigmoid(g) for e>=128
        int bb_ = n0 >> 11;
        int l0  = (n0 & (L_SEQ - 1)) + (wave << 4) + (quad << 2);
#pragma unroll
        for (int nt = 0; nt < 4; ++nt) {
            int col = e0 + (nt << 4) + m;
            float bv = bias[col];
            short4v pk;
            if (e0 < 128) {
#pragma unroll
                for (int r = 0; r < 4; ++r)
                    pk[r] = f2h((acc[nt][r] + bv) * (2.f * LOG2E));
            } else {
#pragma unroll
                for (int r = 0; r < 4; ++r) {
                    float gr = acc[nt][r] + bv;
                    float g = __builtin_amdgcn_rcpf(
                        1.f + __builtin_amdgcn_exp2f(-gr * LOG2E));
                    pk[r] = f2h(g);
                }
            }
            *(short4v*)&outb[(((size_t)(bb_ * 256 + col)) << 11) + l0] = pk;
        }
    } else {  // EPI_BF_RELU
#pragma unroll
        for (int nt = 0; nt < 4; ++nt) {
            int col = e0 + (nt << 4) + m;
            float bv = bias[col];
#pragma unroll
            for (int r = 0; r < 4; ++r) {
                int row = n0 + (wave << 4) + (quad << 2) + r;
                float v = fmaxf(acc[nt][r] + bv, 0.f);
                outb[(size_t)row * E + col] = f2bf(v);
            }
        }
    }
}

// ---------------------------------------------------------------------------
// SSM gated scan — R13 chunked-parallel version (validated R1: 68 -> ~10 us).
// ---------------------------------------------------------------------------
#define SCAN_WARM 128   // burn-in steps (contraction margin)

__device__ __forceinline__ void scan8(float& h, bf16x8 u8, bf16x8 g8,
                                      float a2, short* __restrict__ ob, int l0)
{
#pragma unroll
    for (int i = 0; i < 8; ++i) {
        float u2 = h2f(u8[i]);
        float g  = h2f(g8[i]);
        float omg = 1.f - g;
        float m2  = -2.f * omg;
        float c0 = fmaf(g, h, omg);                          // parallel to exp path
        float e2 = __builtin_amdgcn_exp2f(fmaf(a2, h, u2));  // exp(2x)
        float r  = __builtin_amdgcn_rcpf(1.f + e2);
        h = fmaf(m2, r, c0);
        ob[(l0 + i) * D_MODEL] = f2bf(h);
    }
}

__device__ __forceinline__ void scan8_ns(float& h, bf16x8 u8, bf16x8 g8,
                                         float a2)
{
#pragma unroll
    for (int i = 0; i < 8; ++i) {
        float u2 = h2f(u8[i]);
        float g  = h2f(g8[i]);
        float omg = 1.f - g;
        float m2  = -2.f * omg;
        float c0 = fmaf(g, h, omg);
        float e2 = __builtin_amdgcn_exp2f(fmaf(a2, h, u2));
        float r  = __builtin_amdgcn_rcpf(1.f + e2);
        h = fmaf(m2, r, c0);
    }
}

__global__ __launch_bounds__(64) void scan_kernel(const short* __restrict__ pt,
                                                  const float* __restrict__ A,
                                                  short* __restrict__ hs)
{
    int blk = blockIdx.x;             // 256 blocks = 16 (b,dhalf) x 16 chunks
    int c   = blk & 15;               // chunk index: writes l in [c*128, c*128+128)
    int bd  = blk >> 4;
    int b   = bd >> 1;
    int d   = ((bd & 1) << 6) + threadIdx.x;
    float a2 = 2.f * A[d] * LOG2E;
    const short* up = pt + (((size_t)(b * 256 + d)) << 11);
    const short* gp = up + (((size_t)128) << 11);
    short* ob = hs + ((size_t)(b << 11)) * D_MODEL + d;

    const int lw = c << 7;            // first stored step
    float h = 0.f;

    bf16x8 uA0, uA1, gA0, gA1;

    if (c > 0) {
        // ---- burn-in: SCAN_WARM steps ending at lw, no stores ----
        int l0 = lw - SCAN_WARM;
        uA0 = *(const bf16x8*)(up + l0);
        uA1 = *(const bf16x8*)(up + l0 + 8);
        gA0 = *(const bf16x8*)(gp + l0);
        gA1 = *(const bf16x8*)(gp + l0 + 8);
        for (int l = l0; l < lw; l += 32) {
            bf16x8 uB0 = *(const bf16x8*)(up + l + 16);
            bf16x8 uB1 = *(const bf16x8*)(up + l + 24);
            bf16x8 gB0 = *(const bf16x8*)(gp + l + 16);
            bf16x8 gB1 = *(const bf16x8*)(gp + l + 24);
            scan8_ns(h, uA0, gA0, a2);
            scan8_ns(h, uA1, gA1, a2);
            uA0 = *(const bf16x8*)(up + l + 32);
            uA1 = *(const bf16x8*)(up + l + 40);
            gA0 = *(const bf16x8*)(gp + l + 32);
            gA1 = *(const bf16x8*)(gp + l + 40);
            scan8_ns(h, uB0, gB0, a2);
            scan8_ns(h, uB1, gB1, a2);
        }
    } else {
        uA0 = *(const bf16x8*)(up);
        uA1 = *(const bf16x8*)(up + 8);
        gA0 = *(const bf16x8*)(gp);
        gA1 = *(const bf16x8*)(gp + 8);
    }

    // ---- live phase: 128 steps with stores ----
    for (int l = lw; l < lw + 128; l += 32) {
        bf16x8 uB0 = *(const bf16x8*)(up + l + 16);
        bf16x8 uB1 = *(const bf16x8*)(up + l + 24);
        bf16x8 gB0 = *(const bf16x8*)(gp + l + 16);
        bf16x8 gB1 = *(const bf16x8*)(gp + l + 24);
        scan8(h, uA0, gA0, a2, ob, l);
        scan8(h, uA1, gA1, a2, ob, l + 8);
        if (l + 32 < lw + 128) {      // guard: l+32 would be OOB at chunk end
            uA0 = *(const bf16x8*)(up + l + 32);
            uA1 = *(const bf16x8*)(up + l + 40);
            gA0 = *(const bf16x8*)(gp + l + 32);
            gA1 = *(const bf16x8*)(gp + l + 40);
        }
        scan8(h, uB0, gB0, a2, ob, l + 16);
        scan8(h, uB1, gB1, a2, ob, l + 24);
    }
}

// ---------------------------------------------------------------------------
// Flash attention v8 (R19): split-KV, un-normalized fp32 partials + rs.
// Normalization fused into the downstream gemm_ln (RED path, R20).
// ---------------------------------------------------------------------------
__global__ __launch_bounds__(256) void attn_kernel(const short* __restrict__ Qs,
                                                   const short* __restrict__ Ks,
                                                   const short* __restrict__ Vtg,
                                                   float* __restrict__ pO,
                                                   float* __restrict__ prs)
{
    __shared__ __align__(16) short Klds[2][64][40];
    __shared__ __align__(16) short Vlds[2][32][72];
    __shared__ __align__(16) short Plds[4][32][68];   // [wave][qt*16+m][k] 34-dw rows

    const int tid  = threadIdx.x;
    const int wave = tid >> 6;
    const int lane = tid & 63;
    const int m    = lane & 15;
    const int quad = lane >> 4;

    // XCD-aware swizzle for grid 1024: XCD x gets logical [x*128, x*128+128)
    const int raw = blockIdx.x;
    const int bid = (raw & 7) * 128 + (raw >> 3);
    const int b    = bid >> 7;
    const int h    = (bid >> 5) & 3;
    const int qh   = bid & 31;
    const int q0   = (qh >> 1) << 7;      // 128 q-rows per block
    const int half = qh & 1;              // KV half: rows [half*1024, half*1024+1024)
    const int kv0  = half << 10;

    const size_t qrow = (size_t)((b << 11) + q0 + (wave << 5) + m);
    bf16x8 qfA = *(const bf16x8*)&Qs[qrow * 128 + (h << 5) + (quad << 3)];
    bf16x8 qfB = *(const bf16x8*)&Qs[(qrow + 16) * 128 + (h << 5) + (quad << 3)];

    f32x4 O00 = {0.f,0.f,0.f,0.f}, O01 = {0.f,0.f,0.f,0.f};   // qt0: dt0, dt1
    f32x4 O10 = {0.f,0.f,0.f,0.f}, O11 = {0.f,0.f,0.f,0.f};   // qt1: dt0, dt1
    float rs0 = 0.f, rs1 = 0.f;

    const int krow = tid >> 2, dg = (tid & 3) << 3;
    const int vrow = tid >> 3, kg = (tid & 7) << 3;
    const short* kbase = Ks + ((size_t)((b << 11) + kv0) + krow) * 128 + (h << 5) + dg;
    const short* vbase = Vtg + ((size_t)((b << 2) + h) * 32 + vrow) * L_SEQ + kv0 + kg;

    // stage chunk 0
    bf16x8 kreg = *(const bf16x8*)kbase;
    bf16x8 vreg = *(const bf16x8*)vbase;
    *(bf16x8*)&Klds[0][krow][dg] = kreg;
    *(bf16x8*)&Vlds[0][vrow][kg] = vreg;
    __syncthreads();

    for (int kc = 0; kc < 16; ++kc) {
        const int cur = kc & 1;
        if (kc < 15) {  // prefetch next chunk into registers (coalesced bulk)
            kreg = *(const bf16x8*)(kbase + (size_t)((kc + 1) << 6) * 128);
            vreg = *(const bf16x8*)(vbase + ((kc + 1) << 6));
        }

        // ---- swapped QK^T: each kf read feeds both q-tiles ----
#pragma unroll
        for (int kt = 0; kt < 4; ++kt) {
            bf16x8 kf = *(const bf16x8*)&Klds[cur][(kt << 4) + m][quad << 3];
            f32x4 S0 = __builtin_amdgcn_mfma_f32_16x16x32_bf16(
                kf, qfA, (f32x4){0.f, 0.f, 0.f, 0.f}, 0, 0, 0);
            f32x4 S1 = __builtin_amdgcn_mfma_f32_16x16x32_bf16(
                kf, qfB, (f32x4){0.f, 0.f, 0.f, 0.f}, 0, 0, 0);
            float a0 = __builtin_amdgcn_exp2f(S0[0]);
            float a1 = __builtin_amdgcn_exp2f(S0[1]);
            float a2 = __builtin_amdgcn_exp2f(S0[2]);
            float a3 = __builtin_amdgcn_exp2f(S0[3]);
            rs0 += a0 + a1 + a2 + a3;
            uint2 pkA;
            pkA.x = cvt_pk_bf16(a0, a1);
            pkA.y = cvt_pk_bf16(a2, a3);
            *(uint2*)&Plds[wave][m][(kt << 4) + (quad << 2)] = pkA;
            float b0 = __builtin_amdgcn_exp2f(S1[0]);
            float b1 = __builtin_amdgcn_exp2f(S1[1]);
            float b2 = __builtin_amdgcn_exp2f(S1[2]);
            float b3 = __builtin_amdgcn_exp2f(S1[3]);
            rs1 += b0 + b1 + b2 + b3;
            uint2 pkB;
            pkB.x = cvt_pk_bf16(b0, b1);
            pkB.y = cvt_pk_bf16(b2, b3);
            *(uint2*)&Plds[wave][16 + m][(kt << 4) + (quad << 2)] = pkB;
        }

        // ---- PV: each vf read feeds both q-tiles ----
#pragma unroll
        for (int kt2 = 0; kt2 < 2; ++kt2) {
            short4v aLo = *(const short4v*)&Plds[wave][m][(kt2 << 5) + (quad << 3)];
            short4v aHi = *(const short4v*)&Plds[wave][m][(kt2 << 5) + (quad << 3) + 4];
            bf16x8 pfA = {aLo[0], aLo[1], aLo[2], aLo[3],
                          aHi[0], aHi[1], aHi[2], aHi[3]};
            short4v bLo = *(const short4v*)&Plds[wave][16 + m][(kt2 << 5) + (quad << 3)];
            short4v bHi = *(const short4v*)&Plds[wave][16 + m][(kt2 << 5) + (quad << 3) + 4];
            bf16x8 pfB = {bLo[0], bLo[1], bLo[2], bLo[3],
                          bHi[0], bHi[1], bHi[2], bHi[3]};
            bf16x8 vf0 = *(const bf16x8*)&Vlds[cur][m][(kt2 << 5) + (quad << 3)];
            bf16x8 vf1 = *(const bf16x8*)&Vlds[cur][16 + m][(kt2 << 5) + (quad << 3)];
            O00 = __builtin_amdgcn_mfma_f32_16x16x32_bf16(pfA, vf0, O00, 0, 0, 0);
            O01 = __builtin_amdgcn_mfma_f32_16x16x32_bf16(pfA, vf1, O01, 0, 0, 0);
            O10 = __builtin_amdgcn_mfma_f32_16x16x32_bf16(pfB, vf0, O10, 0, 0, 0);
            O11 = __builtin_amdgcn_mfma_f32_16x16x32_bf16(pfB, vf1, O11, 0, 0, 0);
        }

        // ---- write next K/V buffer; single barrier per chunk ----
        if (kc < 15) {
            *(bf16x8*)&Klds[cur ^ 1][krow][dg] = kreg;
            *(bf16x8*)&Vlds[cur ^ 1][vrow][kg] = vreg;
        }
        __syncthreads();
    }

    // rs per lane (q=m): finish across quads; write per-(half,head,row) partial
    rs0 += __shfl_xor(rs0, 16);
    rs0 += __shfl_xor(rs0, 32);
    rs1 += __shfl_xor(rs1, 16);
    rs1 += __shfl_xor(rs1, 32);

    const int rowbase = (b << 11) + q0 + (wave << 5);
    if (quad == 0) {   // lanes 0..15 hold rs for q = m
        prs[(size_t)((half << 2) + h) * N_ROWS + rowbase + m]      = rs0;
        prs[(size_t)((half << 2) + h) * N_ROWS + rowbase + 16 + m] = rs1;
    }

    // un-normalized O partials (fp32): pO[half][row][h*32 + d]
    float* pb = pO + (size_t)(half * N_ROWS) * 128;
#pragma unroll
    for (int r = 0; r < 4; ++r) {
        int rowA = rowbase + (quad << 2) + r;
        float* opA = pb + (size_t)rowA * 128 + (h << 5) + m;
        opA[0]  = O00[r];
        opA[16] = O01[r];
        float* opB = opA + (size_t)16 * 128;
        opB[0]  = O10[r];
        opB[16] = O11[r];
    }
}

// ---------------------------------------------------------------------------
// Fused pool + head (R12): one 1024-thread block per batch element.
// ---------------------------------------------------------------------------
__global__ __launch_bounds__(1024) void pool_head_kernel(
    const float* __restrict__ h,
    const float* __restrict__ hlnw, const float* __restrict__ hlnb,
    const float* __restrict__ h1w, const float* __restrict__ h1b,
    const float* __restrict__ h2w, const float* __restrict__ h2b,
    float* __restrict__ out)
{
    __shared__ float part[8][128];
    __shared__ float sd[128];
    __shared__ float sq[128];

    int b   = blockIdx.x;
    int t   = threadIdx.x;
    int d   = t & 127;
    int seg = t >> 7;    // 0..7
    const float* hb = h + (size_t)b * L_SEQ * D_MODEL;

    // ---- phase 1: pool ----
    float acc = 0.f;
    int l0 = seg << 8;
    for (int l = l0; l < l0 + 256; l += 4) {
        acc += hb[(l + 0) * D_MODEL + d] + hb[(l + 1) * D_MODEL + d]
             + hb[(l + 2) * D_MODEL + d] + hb[(l + 3) * D_MODEL + d];
    }
    part[seg][d] = acc;
    __syncthreads();

    // ---- phase 2: head (threads 0..127 compute; all hit barriers) ----
    float v = 0.f;
    if (t < 128) {
        float s = 0.f;
#pragma unroll
        for (int i = 0; i < 8; ++i) s += part[i][t];
        v = 0.5f * hb[(L_SEQ - 1) * D_MODEL + t] + 0.5f * (s * (1.f / (float)L_SEQ));
        sd[t] = v;
    }
    __syncthreads();
    for (int s = 64; s > 0; s >>= 1) {
        if (t < s) sd[t] += sd[t + s];
        __syncthreads();
    }
    float mu = sd[0] * (1.f / 128.f);
    __syncthreads();
    float dv = v - mu;
    if (t < 128) sd[t] = dv * dv;
    __syncthreads();
    for (int s = 64; s > 0; s >>= 1) {
        if (t < s) sd[t] += sd[t + s];
        __syncthreads();
    }
    float var = sd[0] * (1.f / 128.f);
    __syncthreads();
    if (t < 128) sq[t] = dv * rsqrtf(var + 1e-5f) * hlnw[t] + hlnb[t];
    __syncthreads();
    if (t < 128) {
        float dot = h1b[t];
        for (int d2 = 0; d2 < 128; ++d2) dot = fmaf(sq[d2], h1w[t * 128 + d2], dot);
        float ge = 0.5f * dot * (1.f + erff(dot * 0.7071067811865475f));
        sd[t] = ge * h2w[t];
    }
    __syncthreads();
    for (int s = 64; s > 0; s >>= 1) {
        if (t < s) sd[t] += sd[t + s];
        __syncthreads();
    }
    if (t == 0) out[b] = sd[0] + h2b[0];
}

// ---------------------------------------------------------------------------
extern "C" void kernel_launch(void* const* d_in, const int* in_sizes, int n_in,
                              void* d_out, int out_size, void* d_ws, size_t ws_size,
                              hipStream_t stream)
{
    (void)in_sizes; (void)n_in; (void)out_size; (void)ws_size;
    const float* x      = (const float*)d_in[0];
    const float* in_w   = (const float*)d_in[1];
    const float* in_b   = (const float*)d_in[2];
    const float* ssm_nw = (const float*)d_in[3];
    const float* ssm_nb = (const float*)d_in[4];
    const float* ssm_A  = (const float*)d_in[5];
    const float* ssm_iw = (const float*)d_in[6];
    const float* ssm_ib = (const float*)d_in[7];
    const float* ssm_ow = (const float*)d_in[8];
    const float* ssm_ob = (const float*)d_in[9];
    const float* ln1w   = (const float*)d_in[10];
    const float* ln1b   = (const float*)d_in[11];
    const float* ln2w   = (const float*)d_in[12];
    const float* ln2b   = (const float*)d_in[13];
    const float* qkvw   = (const float*)d_in[14];
    const float* qkvb   = (const float*)d_in[15];
    const float* aow    = (const float*)d_in[16];
    const float* aob    = (const float*)d_in[17];
    const float* f1w    = (const float*)d_in[18];
    const float* f1b    = (const float*)d_in[19];
    const float* f2w    = (const float*)d_in[20];
    const float* f2b    = (const float*)d_in[21];
    const float* hlnw   = (const float*)d_in[22];
    const float* hlnb   = (const float*)d_in[23];
    const float* h1w    = (const float*)d_in[24];
    const float* h1b    = (const float*)d_in[25];
    const float* h2w    = (const float*)d_in[26];
    const float* h2b    = (const float*)d_in[27];
    float* out = (float*)d_out;

    char* wsb = (char*)d_ws;
    float* bh     = (float*)(wsb);               // [N,128] fp32 residual stream (8 MB)
    short* abuf   = (short*)(wsb + 8388608);     // [N,512] bf16 wide scratch / scan pt (16 MB)
    short* bbuf   = (short*)(wsb + 25165824);    // [N,128] bf16 ln/hs/attn-out (4 MB)
    short* qs     = (short*)(wsb + 29360128);    // [N,128] bf16 Q prescaled; ks = +2097152
    short* vt     = (short*)(wsb + 37748736);    // [B,4,32,2048] bf16 V^T (4 MB)
    short* xb     = (short*)(wsb + 41943040);    // [N,64] bf16 input (2 MB)
    short* wb     = (short*)(wsb + 44040192);    // bf16 weights (~1 MB)
    float* pO     = (float*)(wsb + 46137344);    // [2][N,128] fp32 attn O partials (16 MB)
    float* prs    = (float*)(wsb + 62914560);    // [2][4][N] fp32 attn rs partials (512 KB)
    short* ks     = qs + 2097152;

    dim3 blk(256);

    convert_kernel<<<756, blk, 0, stream>>>(x, in_w, ssm_iw, ssm_ow, qkvw, aow, f1w, f2w, xb, wb);

    // input projection + PE + LN(ssm_norm0): writes bh (fp32) and bbuf (bf16 LN)
    gemm_ln<0, 0><<<512, blk, 0, stream>>>(
        xb, wb, in_b, ssm_nw, ssm_nb, bh, bbuf, 64, nullptr, nullptr);

    // SSM block 0
    gemm_bf<EPI_SCAN_T><<<dim3(4, 256), blk, 0, stream>>>(
        bbuf, wb + 8192, ssm_ib, abuf, nullptr, 128, 256);
    scan_kernel<<<256, 64, 0, stream>>>(abuf, ssm_A, bbuf);
    gemm_ln<1, 0><<<512, blk, 0, stream>>>(                    // +res, LN(ssm_norm1)
        bbuf, wb + 73728, ssm_ob, ssm_nw + 128, ssm_nb + 128, bh, bbuf, 128, nullptr, nullptr);

    // SSM block 1
    gemm_bf<EPI_SCAN_T><<<dim3(4, 256), blk, 0, stream>>>(
        bbuf, wb + 8192 + 32768, ssm_ib + 256, abuf, nullptr, 128, 256);
    scan_kernel<<<256, 64, 0, stream>>>(abuf, ssm_A + 128, bbuf);
    gemm_ln<1, 0><<<512, blk, 0, stream>>>(                    // +res, LN(ln1[0])
        bbuf, wb + 73728 + 16384, ssm_ob + 128, ln1w, ln1b, bh, bbuf, 128, nullptr, nullptr);

    // Encoder layer 0
    gemm_bf<EPI_QKV><<<dim3(6, 256), blk, 0, stream>>>(
        bbuf, wb + 106496, qkvb, qs, vt, 128, 384);
    attn_kernel<<<1024, blk, 0, stream>>>(qs, ks, vt, pO, prs);
    gemm_ln<1, 1><<<512, blk, 0, stream>>>(                    // reduce+norm fused: +res, LN(ln2[0])
        bbuf, wb + 204800, aob, ln2w, ln2b, bh, bbuf, 128, pO, prs);
    gemm_bf<EPI_BF_RELU><<<dim3(8, 256), blk, 0, stream>>>(
        bbuf, wb + 237568, f1b, abuf, nullptr, 128, 512);
    gemm_ln<1, 0><<<512, blk, 0, stream>>>(                    // ff2[0] +res, LN(ln1[1])
        abuf, wb + 368640, f2b, ln1w + 128, ln1b + 128, bh, bbuf, 512, nullptr, nullptr);

    // Encoder layer 1
    gemm_bf<EPI_QKV><<<dim3(6, 256), blk, 0, stream>>>(
        bbuf, wb + 106496 + 49152, qkvb + 384, qs, vt, 128, 384);
    attn_kernel<<<1024, blk, 0, stream>>>(qs, ks, vt, pO, prs);
    gemm_ln<1, 1><<<512, blk, 0, stream>>>(                    // reduce+norm fused: +res, LN(ln2[1])
        bbuf, wb + 204800 + 16384, aob + 128, ln2w + 128, ln2b + 128, bh, bbuf, 128, pO, prs);
    gemm_bf<EPI_BF_RELU><<<dim3(8, 256), blk, 0, stream>>>(
        bbuf, wb + 237568 + 65536, f1b + 512, abuf, nullptr, 128, 512);
    gemm_ln<2, 0><<<512, blk, 0, stream>>>(                    // ff2[1] +res only
        abuf, wb + 368640 + 65536, f2b + 128, nullptr, nullptr, bh, nullptr, 512, nullptr, nullptr);

    pool_head_kernel<<<8, 1024, 0, stream>>>(bh, hlnw, hlnb, h1w, h1b, h2w, h2b, out);
}